// Round 1
// baseline (1473.415 us; speedup 1.0000x reference)
//
#include <hip/hip_runtime.h>
#include <math.h>

#define PASTN 64
#define FUTN 16
#define NN 80

// ---------------- setup: A (causal softmax of relu(M M^T)), theta, scale ----------------
__global__ __launch_bounds__(256) void k_setup(const float* __restrict__ M, const float* __restrict__ kerW,
                                               const float* __restrict__ smoothing,
                                               float* __restrict__ A_ws, float* __restrict__ A_out,
                                               float* __restrict__ theta, float* __restrict__ scale)
{
    __shared__ float Ms[80 * 26];
    __shared__ float Ar[80 * 80];
    const int t = threadIdx.x;
    for (int i = t; i < 80 * 26; i += 256) Ms[i] = M[i];
    __syncthreads();
    for (int idx = t; idx < 6400; idx += 256) {
        int i = idx / 80, j = idx - 80 * i;
        float acc = 0.f;
#pragma unroll
        for (int k = 0; k < 26; ++k) acc = fmaf(Ms[i * 26 + k], Ms[j * 26 + k], acc);
        Ar[idx] = fmaxf(acc, 0.f);
    }
    __syncthreads();
    if (t < 80) {
        float mx = -1e30f;
        for (int j = 0; j <= t; ++j) mx = fmaxf(mx, Ar[t * 80 + j]);
        float s = 0.f;
        for (int j = 0; j <= t; ++j) s += expf(Ar[t * 80 + j] - mx);
        float inv = 1.f / s;
        for (int j = 0; j < 80; ++j) {
            float v = (j <= t) ? expf(Ar[t * 80 + j] - mx) * inv : 0.f;
            A_ws[t * 80 + j] = v;
            A_out[t * 80 + j] = v;
        }
    }
    for (int idx = t; idx < 34 * 34; idx += 256) {
        int i = idx / 34, j = idx - 34 * i;
        float acc = 0.f;
        for (int k = 0; k < 128; ++k) acc = fmaf(kerW[i * 128 + k], kerW[j * 128 + k], acc);
        theta[idx] = acc;
    }
    if (t == 0) {
        float s0 = smoothing[0];
        float sig = 1.f / (1.f + expf(-s0));
        scale[0] = -0.5f / (sig * 0.01f);
    }
}

// ---------------- degree count / dinv ----------------
__global__ void k_deg(const int* __restrict__ dst, float* __restrict__ deg, int E)
{
    int e = blockIdx.x * blockDim.x + threadIdx.x;
    if (e < E) atomicAdd(&deg[dst[e]], 1.0f);
}

__global__ void k_dinv(float* __restrict__ d, int n)
{
    int i = blockIdx.x * blockDim.x + threadIdx.x;
    if (i < n) d[i] = 1.f / sqrtf(1.f + d[i]);
}

// ---------------- pre MLP: 35 -> 128 -> 128 -> 34 (+passthrough num col) ----------------
#define PR 16
__global__ __launch_bounds__(128) void k_pre(const int* __restrict__ cat, const float* __restrict__ num,
                                             const float* __restrict__ emb0, const float* __restrict__ emb1,
                                             const float* __restrict__ emb2,
                                             const float* __restrict__ W1, const float* __restrict__ b1,
                                             const float* __restrict__ W2, const float* __restrict__ b2,
                                             const float* __restrict__ W3, const float* __restrict__ b3,
                                             float* __restrict__ X, int nrows)
{
    __shared__ float oT[35 * PR];    // [i][r]
    __shared__ float h1T[128 * PR];  // [k][r]
    __shared__ float h2T[128 * PR];
    __shared__ float W3s[128 * 34];
    const int t = threadIdx.x;
    const int base = blockIdx.x * PR;

    for (int i = t; i < 128 * 34; i += 128) W3s[i] = W3[i];
    for (int idx = t; idx < 35 * PR; idx += 128) {
        int r = idx / 35, i = idx - 35 * r;
        int row = base + r;
        float v;
        if (i < 16) v = emb0[cat[row * 3 + 0] * 16 + i];
        else if (i < 24) v = emb1[cat[row * 3 + 1] * 8 + (i - 16)];
        else if (i < 32) v = emb2[cat[row * 3 + 2] * 8 + (i - 24)];
        else v = num[row * 3 + (i - 32)];
        oT[i * PR + r] = v;
    }
    __syncthreads();

    float acc[PR];
    // layer 1
    {
        float bb = b1[t];
#pragma unroll
        for (int r = 0; r < PR; ++r) acc[r] = bb;
        for (int i = 0; i < 35; ++i) {
            float wv = W1[i * 128 + t];
            const float4* op = (const float4*)(oT + i * PR);
#pragma unroll
            for (int q = 0; q < PR / 4; ++q) {
                float4 o4 = op[q];
                acc[4 * q + 0] = fmaf(wv, o4.x, acc[4 * q + 0]);
                acc[4 * q + 1] = fmaf(wv, o4.y, acc[4 * q + 1]);
                acc[4 * q + 2] = fmaf(wv, o4.z, acc[4 * q + 2]);
                acc[4 * q + 3] = fmaf(wv, o4.w, acc[4 * q + 3]);
            }
        }
#pragma unroll
        for (int q = 0; q < PR / 4; ++q) {
            float4 v;
            v.x = fmaxf(acc[4 * q + 0], 0.f);
            v.y = fmaxf(acc[4 * q + 1], 0.f);
            v.z = fmaxf(acc[4 * q + 2], 0.f);
            v.w = fmaxf(acc[4 * q + 3], 0.f);
            *(float4*)(h1T + t * PR + 4 * q) = v;
        }
    }
    __syncthreads();
    // layer 2
    {
        float bb = b2[t];
#pragma unroll
        for (int r = 0; r < PR; ++r) acc[r] = bb;
        for (int k = 0; k < 128; ++k) {
            float wv = W2[k * 128 + t];
            const float4* hp = (const float4*)(h1T + k * PR);
#pragma unroll
            for (int q = 0; q < PR / 4; ++q) {
                float4 h4 = hp[q];
                acc[4 * q + 0] = fmaf(wv, h4.x, acc[4 * q + 0]);
                acc[4 * q + 1] = fmaf(wv, h4.y, acc[4 * q + 1]);
                acc[4 * q + 2] = fmaf(wv, h4.z, acc[4 * q + 2]);
                acc[4 * q + 3] = fmaf(wv, h4.w, acc[4 * q + 3]);
            }
        }
#pragma unroll
        for (int q = 0; q < PR / 4; ++q) {
            float4 v;
            v.x = fmaxf(acc[4 * q + 0], 0.f);
            v.y = fmaxf(acc[4 * q + 1], 0.f);
            v.z = fmaxf(acc[4 * q + 2], 0.f);
            v.w = fmaxf(acc[4 * q + 3], 0.f);
            *(float4*)(h2T + t * PR + 4 * q) = v;
        }
    }
    __syncthreads();
    // layer 3: 34*PR outputs
    for (int idx = t; idx < 34 * PR; idx += 128) {
        int j = idx / PR, r = idx - PR * j;
        float a3 = b3[j];
        for (int k = 0; k < 128; ++k) a3 = fmaf(h2T[k * PR + r], W3s[k * 34 + j], a3);
        X[(size_t)(base + r) * 35 + j] = a3;
    }
    if (t < PR) X[(size_t)(base + t) * 35 + 34] = num[(base + t) * 3 + 2];
}

// ---------------- dense gemm (row-major W: DIN x DOUT), optional bias/relu ----------------
template <int DIN, int DOUT, bool BIAS, bool RELU>
__global__ void k_gemm(const float* __restrict__ Xin, int ldin, const float* __restrict__ W,
                       const float* __restrict__ b, float* __restrict__ Out, int n)
{
    __shared__ float Ws[DIN * DOUT];
    for (int i = threadIdx.x; i < DIN * DOUT; i += blockDim.x) Ws[i] = W[i];
    __syncthreads();
    int idx = blockIdx.x * blockDim.x + threadIdx.x;
    if (idx >= n * DOUT) return;
    int row = idx / DOUT, j = idx - row * DOUT;
    const float* xr = Xin + (size_t)row * ldin;
    float acc = BIAS ? b[j] : 0.f;
#pragma unroll
    for (int i = 0; i < DIN; ++i) acc = fmaf(xr[i], Ws[i * DOUT + j], acc);
    if (RELU) acc = fmaxf(acc, 0.f);
    Out[idx] = acc;
}

// ---------------- edge scatter: Agg[dst] += H[src] * dinv[src]*dinv[dst] ----------------
template <int D>
__global__ void k_scatter(const int* __restrict__ src, const int* __restrict__ dst,
                          const float* __restrict__ dinv, const float* __restrict__ H,
                          float* __restrict__ Agg, int E)
{
    int tid = blockIdx.x * blockDim.x + threadIdx.x;
    if (tid >= E * D) return;
    int e = tid / D, i = tid - e * D;
    int s = src[e], d = dst[e];
    float c = dinv[s] * dinv[d];
    atomicAdd(&Agg[(size_t)d * D + i], H[(size_t)s * D + i] * c);
}

template <int D>
__global__ void k_selfadd(const float* __restrict__ Xin, const float* __restrict__ dinv,
                          float* __restrict__ Agg, int n)
{
    int idx = blockIdx.x * blockDim.x + threadIdx.x;
    if (idx >= n * D) return;
    int row = idx / D;
    float di = dinv[row];
    Agg[idx] += Xin[idx] * di * di;
}

template <int D, bool RELU>
__global__ void k_combine(const float* __restrict__ H, const float* __restrict__ dinv,
                          const float* __restrict__ b, const float* __restrict__ Agg,
                          float* __restrict__ dest, int n)
{
    int idx = blockIdx.x * blockDim.x + threadIdx.x;
    if (idx >= n * D) return;
    int row = idx / D, j = idx - row * D;
    float di = dinv[row];
    float v = Agg[idx] + H[idx] * di * di + b[j];
    if (RELU) v = fmaxf(v, 0.f);
    dest[idx] = v;
}

// ---------------- alpha / yh: per-batch kernel regression ----------------
__global__ __launch_bounds__(64) void k_alpha(const float* __restrict__ X1,  // n1 x 34
                                              const float* __restrict__ X,   // n1 x 35
                                              float* __restrict__ X2,        // n2 x 35, writes col 34
                                              const float* __restrict__ theta,
                                              const float* __restrict__ A,
                                              const float* __restrict__ scale)
{
    const int b = blockIdx.x;
    const int p = threadIdx.x;  // 0..63
    __shared__ float th[34 * 34];
    __shared__ float xf[16 * 34];
    __shared__ float uf[16];
    for (int i = p; i < 34 * 34; i += 64) th[i] = theta[i];
    for (int i = p; i < 16 * 34; i += 64) {
        int q = i / 34, o = i - 34 * q;
        xf[i] = X2[(size_t)(b * 16 + q) * 35 + o];
    }
    __syncthreads();
    float xp[34], U[34];
    const float* xr = X1 + (size_t)(b * 64 + p) * 34;
#pragma unroll
    for (int o = 0; o < 34; ++o) xp[o] = xr[o];
#pragma unroll
    for (int o = 0; o < 34; ++o) {
        float a = 0.f;
#pragma unroll
        for (int O = 0; O < 34; ++O) a = fmaf(th[o * 34 + O], xp[O], a);
        U[o] = a;
    }
    float up = 0.f;
#pragma unroll
    for (int o = 0; o < 34; ++o) up = fmaf(xp[o], U[o], up);
    if (p < 16) {
        float acc = 0.f;
        for (int o = 0; o < 34; ++o) {
            float a = 0.f;
#pragma unroll
            for (int O = 0; O < 34; ++O) a = fmaf(th[o * 34 + O], xf[p * 34 + O], a);
            acc = fmaf(xf[p * 34 + o], a, acc);
        }
        uf[p] = acc;
    }
    float y = X[(size_t)(b * 64 + p) * 35 + 34];
    float sc = scale[0];
    __syncthreads();
    for (int q = 0; q < 16; ++q) {
        float g = 0.f;
#pragma unroll
        for (int o = 0; o < 34; ++o) g = fmaf(xf[q * 34 + o], U[o], g);
        float a = sc * (up + uf[q] - 2.f * g);
        if (A[(PASTN + q) * NN + p] == 0.f) a = -INFINITY;
        float mx = a;
#pragma unroll
        for (int off = 32; off > 0; off >>= 1) mx = fmaxf(mx, __shfl_xor(mx, off));
        float e = expf(a - mx);
        float s = e;
#pragma unroll
        for (int off = 32; off > 0; off >>= 1) s += __shfl_xor(s, off);
        float wgt = e / s;
        float c = wgt * y;
#pragma unroll
        for (int off = 32; off > 0; off >>= 1) c += __shfl_xor(c, off);
        if (p == 0) X2[(size_t)(b * 16 + q) * 35 + 34] = c;
    }
}

// ---------------- pairwise distances ----------------
__global__ __launch_bounds__(256) void k_cd(const float* __restrict__ X, const float* __restrict__ X2,
                                            float* __restrict__ cd)
{
    const int b = blockIdx.x;
    const int t = threadIdx.x;
    __shared__ float xa[80 * 36];
    __shared__ float sq[80];
    for (int idx = t; idx < 80 * 35; idx += 256) {
        int nrow = idx / 35, k = idx - 35 * nrow;
        float v = (nrow < 64) ? X[(size_t)(b * 64 + nrow) * 35 + k]
                              : X2[(size_t)(b * 16 + (nrow - 64)) * 35 + k];
        xa[nrow * 36 + k] = v;
    }
    __syncthreads();
    if (t < 80) {
        float acc = 0.f;
#pragma unroll
        for (int k = 0; k < 35; ++k) {
            float v = xa[t * 36 + k];
            acc = fmaf(v, v, acc);
        }
        sq[t] = acc;
    }
    __syncthreads();
    for (int idx = t; idx < 6400; idx += 256) {
        int n_ = idx / 80, m = idx - 80 * n_;
        float dot = 0.f;
#pragma unroll
        for (int k = 0; k < 35; ++k) dot = fmaf(xa[n_ * 36 + k], xa[m * 36 + k], dot);
        float d2 = sq[n_] + sq[m] - 2.f * dot;
        cd[(size_t)b * 6400 + idx] = sqrtf(fmaxf(d2, 0.f));
    }
}

extern "C" void kernel_launch(void* const* d_in, const int* in_sizes, int n_in,
                              void* d_out, int out_size, void* d_ws, size_t ws_size,
                              hipStream_t stream)
{
    const int* x1_cat = (const int*)d_in[0];
    const float* x1_num = (const float*)d_in[1];
    const int* x2_cat = (const int*)d_in[2];
    const float* x2_num = (const float*)d_in[3];
    const int* e1 = (const int*)d_in[4];
    const int* e2 = (const int*)d_in[5];
    const float* emb0 = (const float*)d_in[6];
    const float* emb1 = (const float*)d_in[7];
    const float* emb2 = (const float*)d_in[8];
    const float* pW1 = (const float*)d_in[9];
    const float* pb1 = (const float*)d_in[10];
    const float* pW2 = (const float*)d_in[11];
    const float* pb2 = (const float*)d_in[12];
    const float* pW3 = (const float*)d_in[13];
    const float* pb3 = (const float*)d_in[14];
    const float* g1W1 = (const float*)d_in[15];
    const float* g1b1 = (const float*)d_in[16];
    const float* g1W2 = (const float*)d_in[17];
    const float* g1b2 = (const float*)d_in[18];
    const float* g2W1 = (const float*)d_in[19];
    const float* g2b1 = (const float*)d_in[20];
    const float* g2W2 = (const float*)d_in[21];
    const float* g2b2 = (const float*)d_in[22];
    const float* kerW = (const float*)d_in[23];
    const float* smoothing = (const float*)d_in[24];
    const float* M = (const float*)d_in[25];

    const int n1 = in_sizes[0] / 3;
    const int n2 = in_sizes[2] / 3;
    const int E1 = in_sizes[4] / 2;
    const int E2 = in_sizes[5] / 2;
    const int SBc = n2 / FUTN;

    float* w = (float*)d_ws;
    size_t off = 0;
    float* scale = w + off; off += 16;
    float* theta = w + off; off += 1184;
    float* Aws = w + off; off += 6400;
    float* X = w + off; off += (size_t)n1 * 35;
    float* X2 = w + off; off += (size_t)n2 * 35;
    float* dinv1 = w + off; off += (size_t)n1;
    float* dinv2 = w + off; off += (size_t)n2;
    float* B1 = w + off; off += (size_t)n1 * 35;
    float* B2 = w + off; off += (size_t)n1 * 64;
    float* B3 = w + off; off += (size_t)n1 * 34;
    float* B4 = w + off; off += (size_t)n1 * 34;

    float* out_f = (float*)d_out;
    float* cd_f = out_f + (size_t)SBc * FUTN;
    float* A_out = cd_f + (size_t)SBc * NN * NN;

    auto cdiv = [](long long a, long long b) { return (unsigned)((a + b - 1) / b); };

    hipMemsetAsync(dinv1, 0, (size_t)n1 * 4, stream);
    hipMemsetAsync(dinv2, 0, (size_t)n2 * 4, stream);
    k_setup<<<1, 256, 0, stream>>>(M, kerW, smoothing, Aws, A_out, theta, scale);
    k_deg<<<cdiv(E1, 256), 256, 0, stream>>>(e1 + E1, dinv1, E1);
    k_deg<<<cdiv(E2, 256), 256, 0, stream>>>(e2 + E2, dinv2, E2);
    k_dinv<<<cdiv(n1, 256), 256, 0, stream>>>(dinv1, n1);
    k_dinv<<<cdiv(n2, 256), 256, 0, stream>>>(dinv2, n2);

    k_pre<<<n1 / PR, 128, 0, stream>>>(x1_cat, x1_num, emb0, emb1, emb2, pW1, pb1, pW2, pb2, pW3, pb3, X, n1);
    k_pre<<<n2 / PR, 128, 0, stream>>>(x2_cat, x2_num, emb0, emb1, emb2, pW1, pb1, pW2, pb2, pW3, pb3, X2, n2);

    // g1 layer 1: aggregate inputs (35 dims) then GEMM 35->64 (+bias, relu)
    hipMemsetAsync(B1, 0, (size_t)n1 * 35 * 4, stream);
    k_scatter<35><<<cdiv((long long)E1 * 35, 256), 256, 0, stream>>>(e1, e1 + E1, dinv1, X, B1, E1);
    k_selfadd<35><<<cdiv((long long)n1 * 35, 256), 256, 0, stream>>>(X, dinv1, B1, n1);
    k_gemm<35, 64, true, true><<<cdiv((long long)n1 * 64, 256), 256, 0, stream>>>(B1, 35, g1W1, g1b1, B2, n1);

    // g1 layer 2: GEMM 64->34 then aggregate (34 dims)
    k_gemm<64, 34, false, false><<<cdiv((long long)n1 * 34, 256), 256, 0, stream>>>(B2, 64, g1W2, nullptr, B3, n1);
    hipMemsetAsync(B4, 0, (size_t)n1 * 34 * 4, stream);
    k_scatter<34><<<cdiv((long long)E1 * 34, 256), 256, 0, stream>>>(e1, e1 + E1, dinv1, B3, B4, E1);
    k_combine<34, false><<<cdiv((long long)n1 * 34, 256), 256, 0, stream>>>(B3, dinv1, g1b2, B4, B4, n1);

    // alpha / yh -> X2 col 34
    k_alpha<<<SBc, 64, 0, stream>>>(B4, X, X2, theta, Aws, scale);

    // g2 layer 1
    hipMemsetAsync(B1, 0, (size_t)n2 * 35 * 4, stream);
    k_scatter<35><<<cdiv((long long)E2 * 35, 256), 256, 0, stream>>>(e2, e2 + E2, dinv2, X2, B1, E2);
    k_selfadd<35><<<cdiv((long long)n2 * 35, 256), 256, 0, stream>>>(X2, dinv2, B1, n2);
    k_gemm<35, 64, true, true><<<cdiv((long long)n2 * 64, 256), 256, 0, stream>>>(B1, 35, g2W1, g2b1, B2, n2);

    // g2 layer 2: GEMM 64->1 then aggregate 1 dim
    k_gemm<64, 1, false, false><<<cdiv(n2, 256), 256, 0, stream>>>(B2, 64, g2W2, nullptr, B3, n2);
    hipMemsetAsync(B4, 0, (size_t)n2 * 4, stream);
    k_scatter<1><<<cdiv(E2, 256), 256, 0, stream>>>(e2, e2 + E2, dinv2, B3, B4, E2);
    k_combine<1, false><<<cdiv(n2, 256), 256, 0, stream>>>(B3, dinv2, g2b2, B4, out_f, n2);

    // pairwise distances
    k_cd<<<SBc, 256, 0, stream>>>(X, X2, cd_f);
}

// Round 2
// 1233.770 us; speedup vs baseline: 1.1942x; 1.1942x over previous
//
#include <hip/hip_runtime.h>
#include <math.h>

#define PASTN 64
#define FUTN 16
#define NN 80

// ---------------- setup: A (causal softmax of relu(M M^T)), theta, scale ----------------
__global__ __launch_bounds__(256) void k_setup(const float* __restrict__ M, const float* __restrict__ kerW,
                                               const float* __restrict__ smoothing,
                                               float* __restrict__ A_ws, float* __restrict__ A_out,
                                               float* __restrict__ theta, float* __restrict__ scale)
{
    __shared__ float Ms[80 * 26];
    __shared__ float Ar[80 * 80];
    const int t = threadIdx.x;
    for (int i = t; i < 80 * 26; i += 256) Ms[i] = M[i];
    __syncthreads();
    for (int idx = t; idx < 6400; idx += 256) {
        int i = idx / 80, j = idx - 80 * i;
        float acc = 0.f;
#pragma unroll
        for (int k = 0; k < 26; ++k) acc = fmaf(Ms[i * 26 + k], Ms[j * 26 + k], acc);
        Ar[idx] = fmaxf(acc, 0.f);
    }
    __syncthreads();
    if (t < 80) {
        float mx = -1e30f;
        for (int j = 0; j <= t; ++j) mx = fmaxf(mx, Ar[t * 80 + j]);
        float s = 0.f;
        for (int j = 0; j <= t; ++j) s += expf(Ar[t * 80 + j] - mx);
        float inv = 1.f / s;
        for (int j = 0; j < 80; ++j) {
            float v = (j <= t) ? expf(Ar[t * 80 + j] - mx) * inv : 0.f;
            A_ws[t * 80 + j] = v;
            A_out[t * 80 + j] = v;
        }
    }
    for (int idx = t; idx < 34 * 34; idx += 256) {
        int i = idx / 34, j = idx - 34 * i;
        float acc = 0.f;
        for (int k = 0; k < 128; ++k) acc = fmaf(kerW[i * 128 + k], kerW[j * 128 + k], acc);
        theta[idx] = acc;
    }
    if (t == 0) {
        float s0 = smoothing[0];
        float sig = 1.f / (1.f + expf(-s0));
        scale[0] = -0.5f / (sig * 0.01f);
    }
}

// ---------------- degree count / dinv ----------------
__global__ void k_deg(const int* __restrict__ dst, float* __restrict__ deg, int E)
{
    int e = blockIdx.x * blockDim.x + threadIdx.x;
    if (e < E) atomicAdd(&deg[dst[e]], 1.0f);
}

__global__ void k_dinv(float* __restrict__ d, int n)
{
    int i = blockIdx.x * blockDim.x + threadIdx.x;
    if (i < n) d[i] = 1.f / sqrtf(1.f + d[i]);
}

// ---------------- pre MLP: 35 -> 128 -> 128 -> 34 (+passthrough num col) ----------------
#define PR 16
__global__ __launch_bounds__(128) void k_pre(const int* __restrict__ cat, const float* __restrict__ num,
                                             const float* __restrict__ emb0, const float* __restrict__ emb1,
                                             const float* __restrict__ emb2,
                                             const float* __restrict__ W1, const float* __restrict__ b1,
                                             const float* __restrict__ W2, const float* __restrict__ b2,
                                             const float* __restrict__ W3, const float* __restrict__ b3,
                                             float* __restrict__ X, int nrows)
{
    __shared__ float oT[35 * PR];    // [i][r]
    __shared__ float h1T[128 * PR];  // [k][r]
    __shared__ float h2T[128 * PR];
    __shared__ float W3s[128 * 34];
    const int t = threadIdx.x;
    const int base = blockIdx.x * PR;

    for (int i = t; i < 128 * 34; i += 128) W3s[i] = W3[i];
    for (int idx = t; idx < 35 * PR; idx += 128) {
        int r = idx / 35, i = idx - 35 * r;
        int row = base + r;
        float v;
        if (i < 16) v = emb0[cat[row * 3 + 0] * 16 + i];
        else if (i < 24) v = emb1[cat[row * 3 + 1] * 8 + (i - 16)];
        else if (i < 32) v = emb2[cat[row * 3 + 2] * 8 + (i - 24)];
        else v = num[row * 3 + (i - 32)];
        oT[i * PR + r] = v;
    }
    __syncthreads();

    float acc[PR];
    // layer 1
    {
        float bb = b1[t];
#pragma unroll
        for (int r = 0; r < PR; ++r) acc[r] = bb;
        for (int i = 0; i < 35; ++i) {
            float wv = W1[i * 128 + t];
            const float4* op = (const float4*)(oT + i * PR);
#pragma unroll
            for (int q = 0; q < PR / 4; ++q) {
                float4 o4 = op[q];
                acc[4 * q + 0] = fmaf(wv, o4.x, acc[4 * q + 0]);
                acc[4 * q + 1] = fmaf(wv, o4.y, acc[4 * q + 1]);
                acc[4 * q + 2] = fmaf(wv, o4.z, acc[4 * q + 2]);
                acc[4 * q + 3] = fmaf(wv, o4.w, acc[4 * q + 3]);
            }
        }
#pragma unroll
        for (int q = 0; q < PR / 4; ++q) {
            float4 v;
            v.x = fmaxf(acc[4 * q + 0], 0.f);
            v.y = fmaxf(acc[4 * q + 1], 0.f);
            v.z = fmaxf(acc[4 * q + 2], 0.f);
            v.w = fmaxf(acc[4 * q + 3], 0.f);
            *(float4*)(h1T + t * PR + 4 * q) = v;
        }
    }
    __syncthreads();
    // layer 2
    {
        float bb = b2[t];
#pragma unroll
        for (int r = 0; r < PR; ++r) acc[r] = bb;
        for (int k = 0; k < 128; ++k) {
            float wv = W2[k * 128 + t];
            const float4* hp = (const float4*)(h1T + k * PR);
#pragma unroll
            for (int q = 0; q < PR / 4; ++q) {
                float4 h4 = hp[q];
                acc[4 * q + 0] = fmaf(wv, h4.x, acc[4 * q + 0]);
                acc[4 * q + 1] = fmaf(wv, h4.y, acc[4 * q + 1]);
                acc[4 * q + 2] = fmaf(wv, h4.z, acc[4 * q + 2]);
                acc[4 * q + 3] = fmaf(wv, h4.w, acc[4 * q + 3]);
            }
        }
#pragma unroll
        for (int q = 0; q < PR / 4; ++q) {
            float4 v;
            v.x = fmaxf(acc[4 * q + 0], 0.f);
            v.y = fmaxf(acc[4 * q + 1], 0.f);
            v.z = fmaxf(acc[4 * q + 2], 0.f);
            v.w = fmaxf(acc[4 * q + 3], 0.f);
            *(float4*)(h2T + t * PR + 4 * q) = v;
        }
    }
    __syncthreads();
    // layer 3: 34*PR outputs
    for (int idx = t; idx < 34 * PR; idx += 128) {
        int j = idx / PR, r = idx - PR * j;
        float a3 = b3[j];
        for (int k = 0; k < 128; ++k) a3 = fmaf(h2T[k * PR + r], W3s[k * 34 + j], a3);
        X[(size_t)(base + r) * 35 + j] = a3;
    }
    if (t < PR) X[(size_t)(base + t) * 35 + 34] = num[(base + t) * 3 + 2];
}

// ---------------- plain dense gemm (row-major W: DIN x DOUT) ----------------
template <int DIN, int DOUT, bool BIAS, bool RELU>
__global__ void k_gemm(const float* __restrict__ Xin, int ldin, const float* __restrict__ W,
                       const float* __restrict__ b, float* __restrict__ Out, int n)
{
    __shared__ float Ws[DIN * DOUT];
    for (int i = threadIdx.x; i < DIN * DOUT; i += blockDim.x) Ws[i] = W[i];
    __syncthreads();
    int idx = blockIdx.x * blockDim.x + threadIdx.x;
    if (idx >= n * DOUT) return;
    int row = idx / DOUT, j = idx - row * DOUT;
    const float* xr = Xin + (size_t)row * ldin;
    float acc = BIAS ? b[j] : 0.f;
#pragma unroll
    for (int i = 0; i < DIN; ++i) acc = fmaf(xr[i], Ws[i * DOUT + j], acc);
    if (RELU) acc = fmaxf(acc, 0.f);
    Out[idx] = acc;
}

// ---- GCN layer-1 gemm with fused self-loop + dinv scaling:
// Out[row,j] = relu( di*( sum_i (Agg[row,i] + X[row,i]*di) * W[i,j] ) + b[j] )
template <int DIN, int DOUT>
__global__ void k_gemm_gcn1(const float* __restrict__ Agg, const float* __restrict__ Xself, int ldx,
                            const float* __restrict__ dinv, const float* __restrict__ W,
                            const float* __restrict__ b, float* __restrict__ Out, int n)
{
    __shared__ float Ws[DIN * DOUT];
    for (int i = threadIdx.x; i < DIN * DOUT; i += blockDim.x) Ws[i] = W[i];
    __syncthreads();
    int idx = blockIdx.x * blockDim.x + threadIdx.x;
    if (idx >= n * DOUT) return;
    int row = idx / DOUT, j = idx - row * DOUT;
    float di = dinv[row];
    const float* ar = Agg + (size_t)row * DIN;
    const float* xr = Xself + (size_t)row * ldx;
    float acc = 0.f;
#pragma unroll
    for (int i = 0; i < DIN; ++i) acc = fmaf(fmaf(xr[i], di, ar[i]), Ws[i * DOUT + j], acc);
    Out[idx] = fmaxf(fmaf(di, acc, b[j]), 0.f);
}

// ---------------- edge scatter: Agg[dst] += H[src] * dinv[src]  (dst scaling deferred) ----------------
template <int D>
__global__ void k_scatter(const int* __restrict__ src, const int* __restrict__ dst,
                          const float* __restrict__ dinv, const float* __restrict__ H,
                          float* __restrict__ Agg, int E)
{
    int tid = blockIdx.x * blockDim.x + threadIdx.x;
    if (tid >= E * D) return;
    int e = tid / D, i = tid - e * D;
    int s = src[e], d = dst[e];
    atomicAdd(&Agg[(size_t)d * D + i], H[(size_t)s * D + i] * dinv[s]);
}

// combine: dest = di*(Agg + H*di) + b   (no relu)
template <int D>
__global__ void k_combine(const float* __restrict__ H, const float* __restrict__ dinv,
                          const float* __restrict__ b, const float* __restrict__ Agg,
                          float* __restrict__ dest, int n)
{
    int idx = blockIdx.x * blockDim.x + threadIdx.x;
    if (idx >= n * D) return;
    int row = idx / D, j = idx - row * D;
    float di = dinv[row];
    dest[idx] = fmaf(di, fmaf(H[idx], di, Agg[idx]), b[j]);
}

// ---------------- alpha / yh: per-batch kernel regression ----------------
// Uses theta symmetry: g[q][p] = xf[q]^T theta xp[p] = Uf[q] . xp[p], Uf = theta @ xf.
// uf[q] term is constant along softmax axis p -> cancels; omitted.
__global__ __launch_bounds__(256) void k_alpha(const float* __restrict__ X1,  // n1 x 34 (g1 out)
                                               const float* __restrict__ X,   // n1 x 35 (y col)
                                               float* __restrict__ X2,        // n2 x 35, writes col 34
                                               const float* __restrict__ theta,
                                               const float* __restrict__ A,
                                               const float* __restrict__ scale)
{
    const int b = blockIdx.x;
    const int t = threadIdx.x;
    const int p = t & 63;   // lane = past index
    const int w = t >> 6;   // wave 0..3
    __shared__ float th[34 * 34];
    __shared__ float xpS[64 * 35];  // ld 35: lane stride 3 mod 32 -> conflict-free
    __shared__ float xfS[16 * 34];
    __shared__ float UfS[16 * 34];
    __shared__ float upPart[4][64];
    __shared__ float upS[64];
    __shared__ float yS[64];

    for (int i = t; i < 34 * 34; i += 256) th[i] = theta[i];
    for (int i = t; i < 64 * 34; i += 256) {
        int r = i / 34, o = i - 34 * r;
        xpS[r * 35 + o] = X1[(size_t)(b * 64 + r) * 34 + o];
    }
    for (int i = t; i < 16 * 34; i += 256) {
        int q = i / 34, o = i - 34 * q;
        xfS[i] = X2[(size_t)(b * 16 + q) * 35 + o];
    }
    if (t < 64) yS[t] = X[(size_t)(b * 64 + t) * 35 + 34];
    __syncthreads();

    // Uf[q][o] = sum_O th[o][O] * xf[q][O]
    for (int i = t; i < 16 * 34; i += 256) {
        int q = i / 34, o = i - 34 * q;
        float a = 0.f;
#pragma unroll
        for (int O = 0; O < 34; ++O) a = fmaf(th[o * 34 + O], xfS[q * 34 + O], a);
        UfS[i] = a;
    }
    // up[p] = xp^T theta xp, split over waves (chunks of o)
    {
        const int o0 = w * 9;
        const int o1 = (o0 + 9 < 34) ? o0 + 9 : 34;
        float a = 0.f;
        for (int o = o0; o < o1; ++o) {
            float s2 = 0.f;
#pragma unroll
            for (int O = 0; O < 34; ++O) s2 = fmaf(th[o * 34 + O], xpS[p * 35 + O], s2);
            a = fmaf(xpS[p * 35 + o], s2, a);
        }
        upPart[w][p] = a;
    }
    __syncthreads();
    if (t < 64) upS[t] = upPart[0][t] + upPart[1][t] + upPart[2][t] + upPart[3][t];
    __syncthreads();

    const float sc = scale[0];
    const float up = upS[p];
    const float y = yS[p];
#pragma unroll
    for (int i = 0; i < 4; ++i) {
        const int q = w + 4 * i;
        float g = 0.f;
#pragma unroll
        for (int o = 0; o < 34; ++o) g = fmaf(UfS[q * 34 + o], xpS[p * 35 + o], g);
        float a = sc * (up - 2.f * g);
        if (A[(PASTN + q) * NN + p] == 0.f) a = -INFINITY;
        float mx = a;
#pragma unroll
        for (int off = 32; off > 0; off >>= 1) mx = fmaxf(mx, __shfl_xor(mx, off));
        float e = expf(a - mx);
        float s = e;
#pragma unroll
        for (int off = 32; off > 0; off >>= 1) s += __shfl_xor(s, off);
        float c = (e / s) * y;
#pragma unroll
        for (int off = 32; off > 0; off >>= 1) c += __shfl_xor(c, off);
        if (p == 0) X2[(size_t)(b * 16 + q) * 35 + 34] = c;
    }
}

// ---------------- pairwise distances ----------------
__global__ __launch_bounds__(256) void k_cd(const float* __restrict__ X, const float* __restrict__ X2,
                                            float* __restrict__ cd)
{
    const int b = blockIdx.x;
    const int t = threadIdx.x;
    __shared__ float xa[80 * 36];
    __shared__ float sq[80];
    for (int idx = t; idx < 80 * 35; idx += 256) {
        int nrow = idx / 35, k = idx - 35 * nrow;
        float v = (nrow < 64) ? X[(size_t)(b * 64 + nrow) * 35 + k]
                              : X2[(size_t)(b * 16 + (nrow - 64)) * 35 + k];
        xa[nrow * 36 + k] = v;
    }
    __syncthreads();
    if (t < 80) {
        float acc = 0.f;
#pragma unroll
        for (int k = 0; k < 35; ++k) {
            float v = xa[t * 36 + k];
            acc = fmaf(v, v, acc);
        }
        sq[t] = acc;
    }
    __syncthreads();
    for (int idx = t; idx < 6400; idx += 256) {
        int n_ = idx / 80, m = idx - 80 * n_;
        float dot = 0.f;
#pragma unroll
        for (int k = 0; k < 35; ++k) dot = fmaf(xa[n_ * 36 + k], xa[m * 36 + k], dot);
        float d2 = sq[n_] + sq[m] - 2.f * dot;
        cd[(size_t)b * 6400 + idx] = sqrtf(fmaxf(d2, 0.f));
    }
}

extern "C" void kernel_launch(void* const* d_in, const int* in_sizes, int n_in,
                              void* d_out, int out_size, void* d_ws, size_t ws_size,
                              hipStream_t stream)
{
    const int* x1_cat = (const int*)d_in[0];
    const float* x1_num = (const float*)d_in[1];
    const int* x2_cat = (const int*)d_in[2];
    const float* x2_num = (const float*)d_in[3];
    const int* e1 = (const int*)d_in[4];
    const int* e2 = (const int*)d_in[5];
    const float* emb0 = (const float*)d_in[6];
    const float* emb1 = (const float*)d_in[7];
    const float* emb2 = (const float*)d_in[8];
    const float* pW1 = (const float*)d_in[9];
    const float* pb1 = (const float*)d_in[10];
    const float* pW2 = (const float*)d_in[11];
    const float* pb2 = (const float*)d_in[12];
    const float* pW3 = (const float*)d_in[13];
    const float* pb3 = (const float*)d_in[14];
    const float* g1W1 = (const float*)d_in[15];
    const float* g1b1 = (const float*)d_in[16];
    const float* g1W2 = (const float*)d_in[17];
    const float* g1b2 = (const float*)d_in[18];
    const float* g2W1 = (const float*)d_in[19];
    const float* g2b1 = (const float*)d_in[20];
    const float* g2W2 = (const float*)d_in[21];
    const float* g2b2 = (const float*)d_in[22];
    const float* kerW = (const float*)d_in[23];
    const float* smoothing = (const float*)d_in[24];
    const float* M = (const float*)d_in[25];

    const int n1 = in_sizes[0] / 3;
    const int n2 = in_sizes[2] / 3;
    const int E1 = in_sizes[4] / 2;
    const int E2 = in_sizes[5] / 2;
    const int SBc = n2 / FUTN;

    float* w = (float*)d_ws;
    size_t off = 0;
    float* scale = w + off; off += 16;
    float* theta = w + off; off += 1184;
    float* Aws = w + off; off += 6400;
    float* X = w + off; off += (size_t)n1 * 35;
    float* X2 = w + off; off += (size_t)n2 * 35;
    float* dinv1 = w + off; off += (size_t)n1;
    float* dinv2 = w + off; off += (size_t)n2;
    float* B1 = w + off; off += (size_t)n1 * 35;
    float* B2 = w + off; off += (size_t)n1 * 64;
    float* B3 = w + off; off += (size_t)n1 * 34;
    float* B4 = w + off; off += (size_t)n1 * 34;

    float* out_f = (float*)d_out;
    float* cd_f = out_f + (size_t)SBc * FUTN;
    float* A_out = cd_f + (size_t)SBc * NN * NN;

    auto cdiv = [](long long a, long long b) { return (unsigned)((a + b - 1) / b); };

    hipMemsetAsync(dinv1, 0, (size_t)n1 * 4, stream);
    hipMemsetAsync(dinv2, 0, (size_t)n2 * 4, stream);
    k_setup<<<1, 256, 0, stream>>>(M, kerW, smoothing, Aws, A_out, theta, scale);
    k_deg<<<cdiv(E1, 256), 256, 0, stream>>>(e1 + E1, dinv1, E1);
    k_deg<<<cdiv(E2, 256), 256, 0, stream>>>(e2 + E2, dinv2, E2);
    k_dinv<<<cdiv(n1, 256), 256, 0, stream>>>(dinv1, n1);
    k_dinv<<<cdiv(n2, 256), 256, 0, stream>>>(dinv2, n2);

    k_pre<<<n1 / PR, 128, 0, stream>>>(x1_cat, x1_num, emb0, emb1, emb2, pW1, pb1, pW2, pb2, pW3, pb3, X, n1);
    k_pre<<<n2 / PR, 128, 0, stream>>>(x2_cat, x2_num, emb0, emb1, emb2, pW1, pb1, pW2, pb2, pW3, pb3, X2, n2);

    // g1 layer 1: aggregate inputs (35 dims, msg = x*dinv[src]) then fused gemm
    hipMemsetAsync(B1, 0, (size_t)n1 * 35 * 4, stream);
    k_scatter<35><<<cdiv((long long)E1 * 35, 256), 256, 0, stream>>>(e1, e1 + E1, dinv1, X, B1, E1);
    k_gemm_gcn1<35, 64><<<cdiv((long long)n1 * 64, 256), 256, 0, stream>>>(B1, X, 35, dinv1, g1W1, g1b1, B2, n1);

    // g1 layer 2: GEMM 64->34 then aggregate (34 dims)
    k_gemm<64, 34, false, false><<<cdiv((long long)n1 * 34, 256), 256, 0, stream>>>(B2, 64, g1W2, nullptr, B3, n1);
    hipMemsetAsync(B4, 0, (size_t)n1 * 34 * 4, stream);
    k_scatter<34><<<cdiv((long long)E1 * 34, 256), 256, 0, stream>>>(e1, e1 + E1, dinv1, B3, B4, E1);
    k_combine<34><<<cdiv((long long)n1 * 34, 256), 256, 0, stream>>>(B3, dinv1, g1b2, B4, B4, n1);

    // alpha / yh -> X2 col 34
    k_alpha<<<SBc, 256, 0, stream>>>(B4, X, X2, theta, Aws, scale);

    // g2 layer 1
    hipMemsetAsync(B1, 0, (size_t)n2 * 35 * 4, stream);
    k_scatter<35><<<cdiv((long long)E2 * 35, 256), 256, 0, stream>>>(e2, e2 + E2, dinv2, X2, B1, E2);
    k_gemm_gcn1<35, 64><<<cdiv((long long)n2 * 64, 256), 256, 0, stream>>>(B1, X2, 35, dinv2, g2W1, g2b1, B2, n2);

    // g2 layer 2: GEMM 64->1 then aggregate 1 dim
    k_gemm<64, 1, false, false><<<cdiv(n2, 256), 256, 0, stream>>>(B2, 64, g2W2, nullptr, B3, n2);
    hipMemsetAsync(B4, 0, (size_t)n2 * 4, stream);
    k_scatter<1><<<cdiv(E2, 256), 256, 0, stream>>>(e2, e2 + E2, dinv2, B3, B4, E2);
    k_combine<1><<<cdiv(n2, 256), 256, 0, stream>>>(B3, dinv2, g2b2, B4, out_f, n2);

    // pairwise distances
    k_cd<<<SBc, 256, 0, stream>>>(X, X2, cd_f);
}

// Round 3
// 1088.836 us; speedup vs baseline: 1.3532x; 1.1331x over previous
//
#include <hip/hip_runtime.h>
#include <math.h>

#define PASTN 64
#define FUTN 16
#define NN 80

// ---------------- setup: A (causal softmax of relu(M M^T)), theta, scale ----------------
__global__ __launch_bounds__(256) void k_setup(const float* __restrict__ M, const float* __restrict__ kerW,
                                               const float* __restrict__ smoothing,
                                               float* __restrict__ A_ws, float* __restrict__ A_out,
                                               float* __restrict__ theta, float* __restrict__ scale)
{
    __shared__ float Ms[80 * 26];
    __shared__ float Ar[80 * 80];
    const int t = threadIdx.x;
    for (int i = t; i < 80 * 26; i += 256) Ms[i] = M[i];
    __syncthreads();
    for (int idx = t; idx < 6400; idx += 256) {
        int i = idx / 80, j = idx - 80 * i;
        float acc = 0.f;
#pragma unroll
        for (int k = 0; k < 26; ++k) acc = fmaf(Ms[i * 26 + k], Ms[j * 26 + k], acc);
        Ar[idx] = fmaxf(acc, 0.f);
    }
    __syncthreads();
    if (t < 80) {
        float mx = -1e30f;
        for (int j = 0; j <= t; ++j) mx = fmaxf(mx, Ar[t * 80 + j]);
        float s = 0.f;
        for (int j = 0; j <= t; ++j) s += expf(Ar[t * 80 + j] - mx);
        float inv = 1.f / s;
        for (int j = 0; j < 80; ++j) {
            float v = (j <= t) ? expf(Ar[t * 80 + j] - mx) * inv : 0.f;
            A_ws[t * 80 + j] = v;
            A_out[t * 80 + j] = v;
        }
    }
    for (int idx = t; idx < 34 * 34; idx += 256) {
        int i = idx / 34, j = idx - 34 * i;
        float acc = 0.f;
        for (int k = 0; k < 128; ++k) acc = fmaf(kerW[i * 128 + k], kerW[j * 128 + k], acc);
        theta[idx] = acc;
    }
    if (t == 0) {
        float s0 = smoothing[0];
        float sig = 1.f / (1.f + expf(-s0));
        scale[0] = -0.5f / (sig * 0.01f);
    }
}

// ---------------- degree (int) / dinv ----------------
__global__ void k_deg(const int* __restrict__ dst, int* __restrict__ deg, int E)
{
    int e = blockIdx.x * blockDim.x + threadIdx.x;
    if (e < E) atomicAdd(&deg[dst[e]], 1);
}

__global__ void k_dinv(const int* __restrict__ deg, float* __restrict__ d, int n)
{
    int i = blockIdx.x * blockDim.x + threadIdx.x;
    if (i < n) d[i] = rsqrtf(1.f + (float)deg[i]);
}

// ---------------- exclusive scan (3-phase), chunk = 1024 ----------------
#define SCHUNK 1024
__global__ __launch_bounds__(256) void k_scan_reduce(const int* __restrict__ deg, int* __restrict__ bsum, int n)
{
    __shared__ int sd[256];
    const int b = blockIdx.x, t = threadIdx.x;
    const int base = b * SCHUNK;
    int s = 0;
#pragma unroll
    for (int j = 0; j < 4; ++j) {
        int i = base + t + j * 256;
        if (i < n) s += deg[i];
    }
    sd[t] = s;
    __syncthreads();
    for (int o = 128; o > 0; o >>= 1) {
        if (t < o) sd[t] += sd[t + o];
        __syncthreads();
    }
    if (t == 0) bsum[b] = sd[0];
}

__global__ __launch_bounds__(1024) void k_scan_mid(int* __restrict__ bsum, int nb)
{
    __shared__ int sd[1024];
    const int t = threadIdx.x;
    int orig = (t < nb) ? bsum[t] : 0;
    sd[t] = orig;
    __syncthreads();
    for (int o = 1; o < 1024; o <<= 1) {
        int v = (t >= o) ? sd[t - o] : 0;
        __syncthreads();
        sd[t] += v;
        __syncthreads();
    }
    if (t < nb) bsum[t] = sd[t] - orig;  // exclusive
}

__global__ __launch_bounds__(256) void k_scan_final(const int* __restrict__ deg, const int* __restrict__ bsum,
                                                    int* __restrict__ rs, int n)
{
    __shared__ int sd[256];
    const int b = blockIdx.x, t = threadIdx.x;
    const int base = b * SCHUNK + t * 4;
    int v0 = (base + 0 < n) ? deg[base + 0] : 0;
    int v1 = (base + 1 < n) ? deg[base + 1] : 0;
    int v2 = (base + 2 < n) ? deg[base + 2] : 0;
    int v3 = (base + 3 < n) ? deg[base + 3] : 0;
    int tsum = v0 + v1 + v2 + v3;
    sd[t] = tsum;
    __syncthreads();
    // exclusive scan over 256 per-thread sums (Hillis-Steele)
    int incl = tsum;
    for (int o = 1; o < 256; o <<= 1) {
        int v = (t >= o) ? sd[t - o] : 0;
        __syncthreads();
        incl += v;
        sd[t] = incl;
        __syncthreads();
    }
    int off = bsum[b] + incl - tsum;
    if (base + 0 < n) rs[base + 0] = off;
    if (base + 1 < n) rs[base + 1] = off + v0;
    if (base + 2 < n) rs[base + 2] = off + v0 + v1;
    if (base + 3 < n) rs[base + 3] = off + v0 + v1 + v2;
}

// ---------------- CSR fill (counting sort of src by dst) ----------------
__global__ void k_fill(const int* __restrict__ src, const int* __restrict__ dst,
                       int* __restrict__ cur, int* __restrict__ srcs_sorted, int E)
{
    int e = blockIdx.x * blockDim.x + threadIdx.x;
    if (e < E) {
        int pos = atomicAdd(&cur[dst[e]], 1);
        srcs_sorted[pos] = src[e];
    }
}

// ---------------- pull aggregation: one wave per dst row, lanes = dims ----------------
template <int D>
__global__ __launch_bounds__(256) void k_pull(const int* __restrict__ rs, const int* __restrict__ deg,
                                              const int* __restrict__ srcs, const float* __restrict__ dinv,
                                              const float* __restrict__ H, int ldh,
                                              float* __restrict__ Agg, int n)
{
    const int wid = (blockIdx.x * blockDim.x + threadIdx.x) >> 6;
    const int lane = threadIdx.x & 63;
    if (wid >= n) return;
    const int e0 = rs[wid];
    const int d = deg[wid];
    float acc = 0.f;
    for (int e = 0; e < d; ++e) {
        int s = srcs[e0 + e];
        float c = dinv[s];
        if (lane < D) acc = fmaf(H[(size_t)s * ldh + lane], c, acc);
    }
    if (lane < D) Agg[(size_t)wid * D + lane] = acc;
}

// D=1 pull: thread per row
__global__ void k_pull1(const int* __restrict__ rs, const int* __restrict__ deg,
                        const int* __restrict__ srcs, const float* __restrict__ dinv,
                        const float* __restrict__ H, float* __restrict__ Agg, int n)
{
    int r = blockIdx.x * blockDim.x + threadIdx.x;
    if (r >= n) return;
    int e0 = rs[r], d = deg[r];
    float acc = 0.f;
    for (int e = 0; e < d; ++e) {
        int s = srcs[e0 + e];
        acc = fmaf(H[s], dinv[s], acc);
    }
    Agg[r] = acc;
}

// ---------------- pre MLP: 35 -> 128 -> 128 -> 34 (+passthrough num col) ----------------
// PR=32 rows/block, 256 threads: col = t&127, row-half rh = t>>7.
// h1T/h2T: [k][32] with float4-chunk XOR swizzle (c ^= k&7) -> conflict-free b128 writes
// and conflict-free scalar layer-3 reads.
#define PR 32
__global__ __launch_bounds__(256) void k_pre(const int* __restrict__ cat, const float* __restrict__ num,
                                             const float* __restrict__ emb0, const float* __restrict__ emb1,
                                             const float* __restrict__ emb2,
                                             const float* __restrict__ W1, const float* __restrict__ b1,
                                             const float* __restrict__ W2, const float* __restrict__ b2,
                                             const float* __restrict__ W3, const float* __restrict__ b3,
                                             float* __restrict__ X, int nrows)
{
    __shared__ float oT[35 * PR];     // [i][r], ld 32, no swizzle (reads are wave-uniform)
    __shared__ float h1T[128 * PR];   // [k][r] swizzled
    __shared__ float h2T[128 * PR];
    const int t = threadIdx.x;
    const int col = t & 127;
    const int rh = t >> 7;  // 0/1: rows rh*16 .. rh*16+15
    const int base = blockIdx.x * PR;

    for (int idx = t; idx < 35 * PR; idx += 256) {
        int i = idx >> 5, r = idx & 31;
        int row = base + r;
        float v;
        if (i < 16) v = emb0[cat[row * 3 + 0] * 16 + i];
        else if (i < 24) v = emb1[cat[row * 3 + 1] * 8 + (i - 16)];
        else if (i < 32) v = emb2[cat[row * 3 + 2] * 8 + (i - 24)];
        else v = num[row * 3 + (i - 32)];
        oT[i * PR + r] = v;
    }
    __syncthreads();

    float acc[16];
    // layer 1: 35 -> 128
    {
        float bb = b1[col];
#pragma unroll
        for (int r = 0; r < 16; ++r) acc[r] = bb;
        for (int i = 0; i < 35; ++i) {
            float wv = W1[i * 128 + col];
            const float* op = oT + i * PR + rh * 16;
#pragma unroll
            for (int q = 0; q < 4; ++q) {
                float4 o4 = *(const float4*)(op + 4 * q);
                acc[4 * q + 0] = fmaf(wv, o4.x, acc[4 * q + 0]);
                acc[4 * q + 1] = fmaf(wv, o4.y, acc[4 * q + 1]);
                acc[4 * q + 2] = fmaf(wv, o4.z, acc[4 * q + 2]);
                acc[4 * q + 3] = fmaf(wv, o4.w, acc[4 * q + 3]);
            }
        }
#pragma unroll
        for (int q = 0; q < 4; ++q) {
            int c = rh * 4 + q;
            float4 v;
            v.x = fmaxf(acc[4 * q + 0], 0.f);
            v.y = fmaxf(acc[4 * q + 1], 0.f);
            v.z = fmaxf(acc[4 * q + 2], 0.f);
            v.w = fmaxf(acc[4 * q + 3], 0.f);
            *(float4*)(h1T + col * PR + ((c ^ (col & 7)) << 2)) = v;
        }
    }
    __syncthreads();
    // layer 2: 128 -> 128
    {
        float bb = b2[col];
#pragma unroll
        for (int r = 0; r < 16; ++r) acc[r] = bb;
        for (int k = 0; k < 128; ++k) {
            float wv = W2[k * 128 + col];
            const float* hp = h1T + k * PR;
#pragma unroll
            for (int q = 0; q < 4; ++q) {
                int c = rh * 4 + q;
                float4 h4 = *(const float4*)(hp + ((c ^ (k & 7)) << 2));
                acc[4 * q + 0] = fmaf(wv, h4.x, acc[4 * q + 0]);
                acc[4 * q + 1] = fmaf(wv, h4.y, acc[4 * q + 1]);
                acc[4 * q + 2] = fmaf(wv, h4.z, acc[4 * q + 2]);
                acc[4 * q + 3] = fmaf(wv, h4.w, acc[4 * q + 3]);
            }
        }
#pragma unroll
        for (int q = 0; q < 4; ++q) {
            int c = rh * 4 + q;
            float4 v;
            v.x = fmaxf(acc[4 * q + 0], 0.f);
            v.y = fmaxf(acc[4 * q + 1], 0.f);
            v.z = fmaxf(acc[4 * q + 2], 0.f);
            v.w = fmaxf(acc[4 * q + 3], 0.f);
            *(float4*)(h2T + col * PR + ((c ^ (col & 7)) << 2)) = v;
        }
    }
    __syncthreads();
    // layer 3: 128 -> 34 (34*32 = 1088 outputs)
    for (int idx = t; idx < 34 * PR; idx += 256) {
        int j = idx >> 5, r = idx & 31;
        int cr = r >> 2, wr = r & 3;
        float a3 = b3[j];
        for (int k = 0; k < 128; ++k) {
            float h = h2T[k * PR + ((cr ^ (k & 7)) << 2) + wr];
            a3 = fmaf(h, W3[k * 34 + j], a3);
        }
        X[(size_t)(base + r) * 35 + j] = a3;
    }
    if (t < PR) X[(size_t)(base + t) * 35 + 34] = num[(base + t) * 3 + 2];
}

// ---------------- plain dense gemm (row-major W: DIN x DOUT) ----------------
template <int DIN, int DOUT, bool BIAS, bool RELU>
__global__ void k_gemm(const float* __restrict__ Xin, int ldin, const float* __restrict__ W,
                       const float* __restrict__ b, float* __restrict__ Out, int n)
{
    __shared__ float Ws[DIN * DOUT];
    for (int i = threadIdx.x; i < DIN * DOUT; i += blockDim.x) Ws[i] = W[i];
    __syncthreads();
    int idx = blockIdx.x * blockDim.x + threadIdx.x;
    if (idx >= n * DOUT) return;
    int row = idx / DOUT, j = idx - row * DOUT;
    const float* xr = Xin + (size_t)row * ldin;
    float acc = BIAS ? b[j] : 0.f;
#pragma unroll
    for (int i = 0; i < DIN; ++i) acc = fmaf(xr[i], Ws[i * DOUT + j], acc);
    if (RELU) acc = fmaxf(acc, 0.f);
    Out[idx] = acc;
}

// ---- GCN layer-1 gemm with fused self-loop + dinv scaling:
// Out[row,j] = relu( di*( sum_i (Agg[row,i] + X[row,i]*di) * W[i,j] ) + b[j] )
template <int DIN, int DOUT>
__global__ void k_gemm_gcn1(const float* __restrict__ Agg, const float* __restrict__ Xself, int ldx,
                            const float* __restrict__ dinv, const float* __restrict__ W,
                            const float* __restrict__ b, float* __restrict__ Out, int n)
{
    __shared__ float Ws[DIN * DOUT];
    for (int i = threadIdx.x; i < DIN * DOUT; i += blockDim.x) Ws[i] = W[i];
    __syncthreads();
    int idx = blockIdx.x * blockDim.x + threadIdx.x;
    if (idx >= n * DOUT) return;
    int row = idx / DOUT, j = idx - row * DOUT;
    float di = dinv[row];
    const float* ar = Agg + (size_t)row * DIN;
    const float* xr = Xself + (size_t)row * ldx;
    float acc = 0.f;
#pragma unroll
    for (int i = 0; i < DIN; ++i) acc = fmaf(fmaf(xr[i], di, ar[i]), Ws[i * DOUT + j], acc);
    Out[idx] = fmaxf(fmaf(di, acc, b[j]), 0.f);
}

// combine: dest = di*(Agg + H*di) + b   (no relu)
template <int D>
__global__ void k_combine(const float* __restrict__ H, const float* __restrict__ dinv,
                          const float* __restrict__ b, const float* __restrict__ Agg,
                          float* __restrict__ dest, int n)
{
    int idx = blockIdx.x * blockDim.x + threadIdx.x;
    if (idx >= n * D) return;
    int row = idx / D, j = idx - row * D;
    float di = dinv[row];
    dest[idx] = fmaf(di, fmaf(H[idx], di, Agg[idx]), b[j]);
}

// ---------------- alpha / yh: per-batch kernel regression ----------------
__global__ __launch_bounds__(256) void k_alpha(const float* __restrict__ X1,  // n1 x 34 (g1 out)
                                               const float* __restrict__ X,   // n1 x 35 (y col)
                                               float* __restrict__ X2,        // n2 x 35, writes col 34
                                               const float* __restrict__ theta,
                                               const float* __restrict__ A,
                                               const float* __restrict__ scale)
{
    const int b = blockIdx.x;
    const int t = threadIdx.x;
    const int p = t & 63;
    const int w = t >> 6;
    __shared__ float th[34 * 34];
    __shared__ float xpS[64 * 35];
    __shared__ float xfS[16 * 34];
    __shared__ float UfS[16 * 34];
    __shared__ float upPart[4][64];
    __shared__ float upS[64];
    __shared__ float yS[64];

    for (int i = t; i < 34 * 34; i += 256) th[i] = theta[i];
    for (int i = t; i < 64 * 34; i += 256) {
        int r = i / 34, o = i - 34 * r;
        xpS[r * 35 + o] = X1[(size_t)(b * 64 + r) * 34 + o];
    }
    for (int i = t; i < 16 * 34; i += 256) {
        int q = i / 34, o = i - 34 * q;
        xfS[i] = X2[(size_t)(b * 16 + q) * 35 + o];
    }
    if (t < 64) yS[t] = X[(size_t)(b * 64 + t) * 35 + 34];
    __syncthreads();

    for (int i = t; i < 16 * 34; i += 256) {
        int q = i / 34, o = i - 34 * q;
        float a = 0.f;
#pragma unroll
        for (int O = 0; O < 34; ++O) a = fmaf(th[o * 34 + O], xfS[q * 34 + O], a);
        UfS[i] = a;
    }
    {
        const int o0 = w * 9;
        const int o1 = (o0 + 9 < 34) ? o0 + 9 : 34;
        float a = 0.f;
        for (int o = o0; o < o1; ++o) {
            float s2 = 0.f;
#pragma unroll
            for (int O = 0; O < 34; ++O) s2 = fmaf(th[o * 34 + O], xpS[p * 35 + O], s2);
            a = fmaf(xpS[p * 35 + o], s2, a);
        }
        upPart[w][p] = a;
    }
    __syncthreads();
    if (t < 64) upS[t] = upPart[0][t] + upPart[1][t] + upPart[2][t] + upPart[3][t];
    __syncthreads();

    const float sc = scale[0];
    const float up = upS[p];
    const float y = yS[p];
#pragma unroll
    for (int i = 0; i < 4; ++i) {
        const int q = w + 4 * i;
        float g = 0.f;
#pragma unroll
        for (int o = 0; o < 34; ++o) g = fmaf(UfS[q * 34 + o], xpS[p * 35 + o], g);
        float a = sc * (up - 2.f * g);
        if (A[(PASTN + q) * NN + p] == 0.f) a = -INFINITY;
        float mx = a;
#pragma unroll
        for (int off = 32; off > 0; off >>= 1) mx = fmaxf(mx, __shfl_xor(mx, off));
        float e = expf(a - mx);
        float s = e;
#pragma unroll
        for (int off = 32; off > 0; off >>= 1) s += __shfl_xor(s, off);
        float c = (e / s) * y;
#pragma unroll
        for (int off = 32; off > 0; off >>= 1) c += __shfl_xor(c, off);
        if (p == 0) X2[(size_t)(b * 16 + q) * 35 + 34] = c;
    }
}

// ---------------- pairwise distances ----------------
__global__ __launch_bounds__(256) void k_cd(const float* __restrict__ X, const float* __restrict__ X2,
                                            float* __restrict__ cd)
{
    const int b = blockIdx.x;
    const int t = threadIdx.x;
    __shared__ float xa[80 * 36];
    __shared__ float sq[80];
    for (int idx = t; idx < 80 * 35; idx += 256) {
        int nrow = idx / 35, k = idx - 35 * nrow;
        float v = (nrow < 64) ? X[(size_t)(b * 64 + nrow) * 35 + k]
                              : X2[(size_t)(b * 16 + (nrow - 64)) * 35 + k];
        xa[nrow * 36 + k] = v;
    }
    __syncthreads();
    if (t < 80) {
        float acc = 0.f;
#pragma unroll
        for (int k = 0; k < 35; ++k) {
            float v = xa[t * 36 + k];
            acc = fmaf(v, v, acc);
        }
        sq[t] = acc;
    }
    __syncthreads();
    for (int idx = t; idx < 6400; idx += 256) {
        int n_ = idx / 80, m = idx - 80 * n_;
        float dot = 0.f;
#pragma unroll
        for (int k = 0; k < 35; ++k) dot = fmaf(xa[n_ * 36 + k], xa[m * 36 + k], dot);
        float d2 = sq[n_] + sq[m] - 2.f * dot;
        cd[(size_t)b * 6400 + idx] = sqrtf(fmaxf(d2, 0.f));
    }
}

extern "C" void kernel_launch(void* const* d_in, const int* in_sizes, int n_in,
                              void* d_out, int out_size, void* d_ws, size_t ws_size,
                              hipStream_t stream)
{
    const int* x1_cat = (const int*)d_in[0];
    const float* x1_num = (const float*)d_in[1];
    const int* x2_cat = (const int*)d_in[2];
    const float* x2_num = (const float*)d_in[3];
    const int* e1 = (const int*)d_in[4];
    const int* e2 = (const int*)d_in[5];
    const float* emb0 = (const float*)d_in[6];
    const float* emb1 = (const float*)d_in[7];
    const float* emb2 = (const float*)d_in[8];
    const float* pW1 = (const float*)d_in[9];
    const float* pb1 = (const float*)d_in[10];
    const float* pW2 = (const float*)d_in[11];
    const float* pb2 = (const float*)d_in[12];
    const float* pW3 = (const float*)d_in[13];
    const float* pb3 = (const float*)d_in[14];
    const float* g1W1 = (const float*)d_in[15];
    const float* g1b1 = (const float*)d_in[16];
    const float* g1W2 = (const float*)d_in[17];
    const float* g1b2 = (const float*)d_in[18];
    const float* g2W1 = (const float*)d_in[19];
    const float* g2b1 = (const float*)d_in[20];
    const float* g2W2 = (const float*)d_in[21];
    const float* g2b2 = (const float*)d_in[22];
    const float* kerW = (const float*)d_in[23];
    const float* smoothing = (const float*)d_in[24];
    const float* M = (const float*)d_in[25];

    const int n1 = in_sizes[0] / 3;
    const int n2 = in_sizes[2] / 3;
    const int E1 = in_sizes[4] / 2;
    const int E2 = in_sizes[5] / 2;
    const int SBc = n2 / FUTN;

    float* w = (float*)d_ws;
    size_t off = 0;
    float* scale = w + off; off += 16;
    float* theta = w + off; off += 1184;
    float* Aws = w + off; off += 6400;
    float* X = w + off; off += (size_t)n1 * 35;
    float* X2 = w + off; off += (size_t)n2 * 35;
    float* dinv1 = w + off; off += (size_t)n1;
    float* dinv2 = w + off; off += (size_t)n2;
    float* B1 = w + off; off += (size_t)n1 * 35;
    float* B2 = w + off; off += (size_t)n1 * 64;
    float* B3 = w + off; off += (size_t)n1 * 34;
    float* B4 = w + off; off += (size_t)n1 * 34;
    int* iw = (int*)(w + off);
    size_t ioff = 0;
    int* degi1 = iw + ioff; ioff += n1;
    int* rs1 = iw + ioff; ioff += n1;
    int* cur1 = iw + ioff; ioff += n1;
    int* srcs1 = iw + ioff; ioff += E1;
    int* degi2 = iw + ioff; ioff += n2;
    int* rs2 = iw + ioff; ioff += n2;
    int* cur2 = iw + ioff; ioff += n2;
    int* srcs2 = iw + ioff; ioff += E2;
    int* bsumA = iw + ioff; ioff += 1024;
    int* bsumB = iw + ioff; ioff += 1024;

    float* out_f = (float*)d_out;
    float* cd_f = out_f + (size_t)SBc * FUTN;
    float* A_out = cd_f + (size_t)SBc * NN * NN;

    auto cdiv = [](long long a, long long b) { return (unsigned)((a + b - 1) / b); };

    // ---- degrees + CSR build ----
    hipMemsetAsync(degi1, 0, (size_t)n1 * 4, stream);
    hipMemsetAsync(degi2, 0, (size_t)n2 * 4, stream);
    k_setup<<<1, 256, 0, stream>>>(M, kerW, smoothing, Aws, A_out, theta, scale);
    k_deg<<<cdiv(E1, 256), 256, 0, stream>>>(e1 + E1, degi1, E1);
    k_deg<<<cdiv(E2, 256), 256, 0, stream>>>(e2 + E2, degi2, E2);
    k_dinv<<<cdiv(n1, 256), 256, 0, stream>>>(degi1, dinv1, n1);
    k_dinv<<<cdiv(n2, 256), 256, 0, stream>>>(degi2, dinv2, n2);

    const int nb1 = cdiv(n1, SCHUNK), nb2 = cdiv(n2, SCHUNK);
    k_scan_reduce<<<nb1, 256, 0, stream>>>(degi1, bsumA, n1);
    k_scan_mid<<<1, 1024, 0, stream>>>(bsumA, nb1);
    k_scan_final<<<nb1, 256, 0, stream>>>(degi1, bsumA, rs1, n1);
    k_scan_reduce<<<nb2, 256, 0, stream>>>(degi2, bsumB, n2);
    k_scan_mid<<<1, 1024, 0, stream>>>(bsumB, nb2);
    k_scan_final<<<nb2, 256, 0, stream>>>(degi2, bsumB, rs2, n2);

    hipMemcpyAsync(cur1, rs1, (size_t)n1 * 4, hipMemcpyDeviceToDevice, stream);
    hipMemcpyAsync(cur2, rs2, (size_t)n2 * 4, hipMemcpyDeviceToDevice, stream);
    k_fill<<<cdiv(E1, 256), 256, 0, stream>>>(e1, e1 + E1, cur1, srcs1, E1);
    k_fill<<<cdiv(E2, 256), 256, 0, stream>>>(e2, e2 + E2, cur2, srcs2, E2);

    // ---- pre MLP ----
    k_pre<<<n1 / PR, 256, 0, stream>>>(x1_cat, x1_num, emb0, emb1, emb2, pW1, pb1, pW2, pb2, pW3, pb3, X, n1);
    k_pre<<<n2 / PR, 256, 0, stream>>>(x2_cat, x2_num, emb0, emb1, emb2, pW1, pb1, pW2, pb2, pW3, pb3, X2, n2);

    // ---- g1 layer 1: pull(35) then fused gemm ----
    k_pull<35><<<cdiv(n1, 4), 256, 0, stream>>>(rs1, degi1, srcs1, dinv1, X, 35, B1, n1);
    k_gemm_gcn1<35, 64><<<cdiv((long long)n1 * 64, 256), 256, 0, stream>>>(B1, X, 35, dinv1, g1W1, g1b1, B2, n1);

    // ---- g1 layer 2: gemm 64->34 then pull(34) + combine ----
    k_gemm<64, 34, false, false><<<cdiv((long long)n1 * 34, 256), 256, 0, stream>>>(B2, 64, g1W2, nullptr, B3, n1);
    k_pull<34><<<cdiv(n1, 4), 256, 0, stream>>>(rs1, degi1, srcs1, dinv1, B3, 34, B4, n1);
    k_combine<34><<<cdiv((long long)n1 * 34, 256), 256, 0, stream>>>(B3, dinv1, g1b2, B4, B4, n1);

    // ---- alpha / yh -> X2 col 34 ----
    k_alpha<<<SBc, 256, 0, stream>>>(B4, X, X2, theta, Aws, scale);

    // ---- g2 layer 1 ----
    k_pull<35><<<cdiv(n2, 4), 256, 0, stream>>>(rs2, degi2, srcs2, dinv2, X2, 35, B1, n2);
    k_gemm_gcn1<35, 64><<<cdiv((long long)n2 * 64, 256), 256, 0, stream>>>(B1, X2, 35, dinv2, g2W1, g2b1, B2, n2);

    // ---- g2 layer 2: gemm 64->1, pull(1), combine ----
    k_gemm<64, 1, false, false><<<cdiv(n2, 256), 256, 0, stream>>>(B2, 64, g2W2, nullptr, B3, n2);
    k_pull1<<<cdiv(n2, 256), 256, 0, stream>>>(rs2, degi2, srcs2, dinv2, B3, B4, n2);
    k_combine<1><<<cdiv(n2, 256), 256, 0, stream>>>(B3, dinv2, g2b2, B4, out_f, n2);

    // ---- pairwise distances ----
    k_cd<<<SBc, 256, 0, stream>>>(X, X2, cd_f);
}

// Round 4
// 981.483 us; speedup vs baseline: 1.5012x; 1.1094x over previous
//
#include <hip/hip_runtime.h>
#include <math.h>

#define PASTN 64
#define FUTN 16
#define NN 80

// ---------------- setup: A (causal softmax of relu(M M^T)), theta, scale ----------------
__global__ __launch_bounds__(256) void k_setup(const float* __restrict__ M, const float* __restrict__ kerW,
                                               const float* __restrict__ smoothing,
                                               float* __restrict__ A_ws, float* __restrict__ A_out,
                                               float* __restrict__ theta, float* __restrict__ scale)
{
    __shared__ float Ms[80 * 26];
    __shared__ float Ar[80 * 80];
    const int t = threadIdx.x;
    for (int i = t; i < 80 * 26; i += 256) Ms[i] = M[i];
    __syncthreads();
    for (int idx = t; idx < 6400; idx += 256) {
        int i = idx / 80, j = idx - 80 * i;
        float acc = 0.f;
#pragma unroll
        for (int k = 0; k < 26; ++k) acc = fmaf(Ms[i * 26 + k], Ms[j * 26 + k], acc);
        Ar[idx] = fmaxf(acc, 0.f);
    }
    __syncthreads();
    if (t < 80) {
        float mx = -1e30f;
        for (int j = 0; j <= t; ++j) mx = fmaxf(mx, Ar[t * 80 + j]);
        float s = 0.f;
        for (int j = 0; j <= t; ++j) s += expf(Ar[t * 80 + j] - mx);
        float inv = 1.f / s;
        for (int j = 0; j < 80; ++j) {
            float v = (j <= t) ? expf(Ar[t * 80 + j] - mx) * inv : 0.f;
            A_ws[t * 80 + j] = v;
            A_out[t * 80 + j] = v;
        }
    }
    for (int idx = t; idx < 34 * 34; idx += 256) {
        int i = idx / 34, j = idx - 34 * i;
        float acc = 0.f;
        for (int k = 0; k < 128; ++k) acc = fmaf(kerW[i * 128 + k], kerW[j * 128 + k], acc);
        theta[idx] = acc;
    }
    if (t == 0) {
        float s0 = smoothing[0];
        float sig = 1.f / (1.f + expf(-s0));
        scale[0] = -0.5f / (sig * 0.01f);
    }
}

// ---------------- degree (int) / dinv ----------------
__global__ void k_deg(const int* __restrict__ dst, int* __restrict__ deg, int E)
{
    int e = blockIdx.x * blockDim.x + threadIdx.x;
    if (e < E) atomicAdd(&deg[dst[e]], 1);
}

__global__ void k_dinv(const int* __restrict__ deg, float* __restrict__ d, int n)
{
    int i = blockIdx.x * blockDim.x + threadIdx.x;
    if (i < n) d[i] = rsqrtf(1.f + (float)deg[i]);
}

// ---------------- exclusive scan (3-phase), chunk = 1024 ----------------
#define SCHUNK 1024
__global__ __launch_bounds__(256) void k_scan_reduce(const int* __restrict__ deg, int* __restrict__ bsum, int n)
{
    __shared__ int sd[256];
    const int b = blockIdx.x, t = threadIdx.x;
    const int base = b * SCHUNK;
    int s = 0;
#pragma unroll
    for (int j = 0; j < 4; ++j) {
        int i = base + t + j * 256;
        if (i < n) s += deg[i];
    }
    sd[t] = s;
    __syncthreads();
    for (int o = 128; o > 0; o >>= 1) {
        if (t < o) sd[t] += sd[t + o];
        __syncthreads();
    }
    if (t == 0) bsum[b] = sd[0];
}

__global__ __launch_bounds__(1024) void k_scan_mid(int* __restrict__ bsum, int nb)
{
    __shared__ int sd[1024];
    const int t = threadIdx.x;
    int orig = (t < nb) ? bsum[t] : 0;
    sd[t] = orig;
    __syncthreads();
    for (int o = 1; o < 1024; o <<= 1) {
        int v = (t >= o) ? sd[t - o] : 0;
        __syncthreads();
        sd[t] += v;
        __syncthreads();
    }
    if (t < nb) bsum[t] = sd[t] - orig;  // exclusive
}

__global__ __launch_bounds__(256) void k_scan_final(const int* __restrict__ deg, const int* __restrict__ bsum,
                                                    int* __restrict__ rs, int n)
{
    __shared__ int sd[256];
    const int b = blockIdx.x, t = threadIdx.x;
    const int base = b * SCHUNK + t * 4;
    int v0 = (base + 0 < n) ? deg[base + 0] : 0;
    int v1 = (base + 1 < n) ? deg[base + 1] : 0;
    int v2 = (base + 2 < n) ? deg[base + 2] : 0;
    int v3 = (base + 3 < n) ? deg[base + 3] : 0;
    int tsum = v0 + v1 + v2 + v3;
    sd[t] = tsum;
    __syncthreads();
    int incl = tsum;
    for (int o = 1; o < 256; o <<= 1) {
        int v = (t >= o) ? sd[t - o] : 0;
        __syncthreads();
        incl += v;
        sd[t] = incl;
        __syncthreads();
    }
    int off = bsum[b] + incl - tsum;
    if (base + 0 < n) rs[base + 0] = off;
    if (base + 1 < n) rs[base + 1] = off + v0;
    if (base + 2 < n) rs[base + 2] = off + v0 + v1;
    if (base + 3 < n) rs[base + 3] = off + v0 + v1 + v2;
}

// ---------------- CSR fill (counting sort of src by dst) ----------------
__global__ void k_fill(const int* __restrict__ src, const int* __restrict__ dst,
                       int* __restrict__ cur, int* __restrict__ srcs_sorted, int E)
{
    int e = blockIdx.x * blockDim.x + threadIdx.x;
    if (e < E) {
        int pos = atomicAdd(&cur[dst[e]], 1);
        srcs_sorted[pos] = src[e];
    }
}

// ---------------- fused GCN layer 1: pull(DIN) + gemm(DIN->64) + relu ----------------
// Out[row,col] = relu( di * sum_i ( X[row,i]*di + sum_s X[s,i]*dinv[s] ) * W[i,col] + b[col] )
template <int DIN>
__global__ __launch_bounds__(256) void k_gcn_a(const int* __restrict__ rs, const int* __restrict__ deg,
                                               const int* __restrict__ srcs, const float* __restrict__ dinv,
                                               const float* __restrict__ H, const float* __restrict__ W,
                                               const float* __restrict__ b, float* __restrict__ Out, int n)
{
    const int w = threadIdx.x >> 6, lane = threadIdx.x & 63;
    const int row = blockIdx.x * 4 + w;
    __shared__ float ag[4][DIN];
    __shared__ float diS[4];
    float di = dinv[row];
    if (lane == 0) diS[w] = di;
    float acc = 0.f;
    if (lane < DIN) acc = H[(size_t)row * DIN + lane] * di;
    const int e0 = rs[row];
    const int d = deg[row];
    for (int e = 0; e < d; ++e) {
        int s = srcs[e0 + e];
        float c = dinv[s];
        if (lane < DIN) acc = fmaf(H[(size_t)s * DIN + lane], c, acc);
    }
    if (lane < DIN) ag[w][lane] = acc;
    __syncthreads();
    float o = 0.f;
#pragma unroll
    for (int i = 0; i < DIN; ++i) o = fmaf(ag[w][i], W[i * 64 + lane], o);
    Out[(size_t)row * 64 + lane] = fmaxf(fmaf(diS[w], o, b[lane]), 0.f);
}

// ---------------- fused pull(D) + combine (no relu): dest = di*Agg + di^2*H[row] + b ----------------
template <int D>
__global__ __launch_bounds__(256) void k_pcomb(const int* __restrict__ rs, const int* __restrict__ deg,
                                               const int* __restrict__ srcs, const float* __restrict__ dinv,
                                               const float* __restrict__ H, const float* __restrict__ b,
                                               float* __restrict__ dest, int n)
{
    const int wid = (blockIdx.x * blockDim.x + threadIdx.x) >> 6;
    const int lane = threadIdx.x & 63;
    if (wid >= n) return;
    const float di = dinv[wid];
    float acc = 0.f;
    if (lane < D) acc = H[(size_t)wid * D + lane] * di;
    const int e0 = rs[wid];
    const int d = deg[wid];
    for (int e = 0; e < d; ++e) {
        int s = srcs[e0 + e];
        float c = dinv[s];
        if (lane < D) acc = fmaf(H[(size_t)s * D + lane], c, acc);
    }
    if (lane < D) dest[(size_t)wid * D + lane] = fmaf(di, acc, b[lane]);
}

// D=1 fused pull+combine: thread per row
__global__ void k_pcomb1(const int* __restrict__ rs, const int* __restrict__ deg,
                         const int* __restrict__ srcs, const float* __restrict__ dinv,
                         const float* __restrict__ H, const float* __restrict__ b,
                         float* __restrict__ dest, int n)
{
    int r = blockIdx.x * blockDim.x + threadIdx.x;
    if (r >= n) return;
    int e0 = rs[r], d = deg[r];
    float di = dinv[r];
    float acc = H[r] * di;
    for (int e = 0; e < d; ++e) {
        int s = srcs[e0 + e];
        acc = fmaf(H[s], dinv[s], acc);
    }
    dest[r] = fmaf(di, acc, b[0]);
}

// ---------------- pre MLP: 35 -> 128 -> 128 -> 34 (+passthrough num col) ----------------
// 256 threads, PR=32 rows. ct = t&31 (cols 4ct..4ct+3), rg = t>>5 (rows 4rg..4rg+3).
// LDS tiles [dim][32 rows] with float4-chunk XOR swizzle: element (k, r) at
// k*32 + (((r>>2) ^ (k&7))<<2) + (r&3)  -> conflict-free b128 reads.
#define PR 32
__global__ __launch_bounds__(256) void k_pre(const int* __restrict__ cat, const float* __restrict__ num,
                                             const float* __restrict__ emb0, const float* __restrict__ emb1,
                                             const float* __restrict__ emb2,
                                             const float* __restrict__ W1, const float* __restrict__ b1,
                                             const float* __restrict__ W2, const float* __restrict__ b2,
                                             const float* __restrict__ W3, const float* __restrict__ b3,
                                             float* __restrict__ X, int nrows)
{
    __shared__ float oT[35 * PR];
    __shared__ float h1T[128 * PR];
    __shared__ float h2T[128 * PR];
    const int t = threadIdx.x;
    const int ct = t & 31;
    const int rg = t >> 5;  // 0..7
    const int base = blockIdx.x * PR;

    for (int idx = t; idx < 35 * PR; idx += 256) {
        int i = idx >> 5, r = idx & 31;
        int row = base + r;
        float v;
        if (i < 16) v = emb0[cat[row * 3 + 0] * 16 + i];
        else if (i < 24) v = emb1[cat[row * 3 + 1] * 8 + (i - 16)];
        else if (i < 32) v = emb2[cat[row * 3 + 2] * 8 + (i - 24)];
        else v = num[row * 3 + (i - 32)];
        oT[i * PR + (((r >> 2) ^ (i & 7)) << 2) + (r & 3)] = v;
    }
    __syncthreads();

    float acc[4][4];
    // layer 1: 35 -> 128
    {
        float4 bb = *(const float4*)(b1 + 4 * ct);
        const float bbv[4] = {bb.x, bb.y, bb.z, bb.w};
#pragma unroll
        for (int c = 0; c < 4; ++c)
#pragma unroll
            for (int r = 0; r < 4; ++r) acc[c][r] = bbv[c];
        for (int i = 0; i < 35; ++i) {
            float4 ov = *(const float4*)(oT + i * PR + ((rg ^ (i & 7)) << 2));
            float4 wv = *(const float4*)(W1 + i * 128 + 4 * ct);
            const float o4[4] = {ov.x, ov.y, ov.z, ov.w};
            const float w4[4] = {wv.x, wv.y, wv.z, wv.w};
#pragma unroll
            for (int c = 0; c < 4; ++c)
#pragma unroll
                for (int r = 0; r < 4; ++r) acc[c][r] = fmaf(w4[c], o4[r], acc[c][r]);
        }
#pragma unroll
        for (int c = 0; c < 4; ++c) {
            int col = 4 * ct + c;
            float4 v;
            v.x = fmaxf(acc[c][0], 0.f);
            v.y = fmaxf(acc[c][1], 0.f);
            v.z = fmaxf(acc[c][2], 0.f);
            v.w = fmaxf(acc[c][3], 0.f);
            *(float4*)(h1T + col * PR + ((rg ^ (col & 7)) << 2)) = v;
        }
    }
    __syncthreads();
    // layer 2: 128 -> 128
    {
        float4 bb = *(const float4*)(b2 + 4 * ct);
        const float bbv[4] = {bb.x, bb.y, bb.z, bb.w};
#pragma unroll
        for (int c = 0; c < 4; ++c)
#pragma unroll
            for (int r = 0; r < 4; ++r) acc[c][r] = bbv[c];
#pragma unroll 4
        for (int k = 0; k < 128; ++k) {
            float4 hv = *(const float4*)(h1T + k * PR + ((rg ^ (k & 7)) << 2));
            float4 wv = *(const float4*)(W2 + k * 128 + 4 * ct);
            const float h4[4] = {hv.x, hv.y, hv.z, hv.w};
            const float w4[4] = {wv.x, wv.y, wv.z, wv.w};
#pragma unroll
            for (int c = 0; c < 4; ++c)
#pragma unroll
                for (int r = 0; r < 4; ++r) acc[c][r] = fmaf(w4[c], h4[r], acc[c][r]);
        }
#pragma unroll
        for (int c = 0; c < 4; ++c) {
            int col = 4 * ct + c;
            float4 v;
            v.x = fmaxf(acc[c][0], 0.f);
            v.y = fmaxf(acc[c][1], 0.f);
            v.z = fmaxf(acc[c][2], 0.f);
            v.w = fmaxf(acc[c][3], 0.f);
            *(float4*)(h2T + col * PR + ((rg ^ (col & 7)) << 2)) = v;
        }
    }
    __syncthreads();
    // layer 3: 128 -> 34, tasks = (j, row-group): 34*8 = 272
    for (int task = t; task < 34 * 8; task += 256) {
        int j = task >> 3, rg3 = task & 7;
        float a0 = b3[j], a1 = a0, a2 = a0, a3 = a0;
#pragma unroll 4
        for (int k = 0; k < 128; ++k) {
            float4 hv = *(const float4*)(h2T + k * PR + ((rg3 ^ (k & 7)) << 2));
            float wv = W3[k * 34 + j];
            a0 = fmaf(hv.x, wv, a0);
            a1 = fmaf(hv.y, wv, a1);
            a2 = fmaf(hv.z, wv, a2);
            a3 = fmaf(hv.w, wv, a3);
        }
        size_t rb = (size_t)(base + rg3 * 4);
        X[(rb + 0) * 35 + j] = a0;
        X[(rb + 1) * 35 + j] = a1;
        X[(rb + 2) * 35 + j] = a2;
        X[(rb + 3) * 35 + j] = a3;
    }
    if (t < PR) X[(size_t)(base + t) * 35 + 34] = num[(base + t) * 3 + 2];
}

// ---------------- plain dense gemm (row-major W: DIN x DOUT) ----------------
template <int DIN, int DOUT, bool BIAS, bool RELU>
__global__ void k_gemm(const float* __restrict__ Xin, int ldin, const float* __restrict__ W,
                       const float* __restrict__ b, float* __restrict__ Out, int n)
{
    __shared__ float Ws[DIN * DOUT];
    for (int i = threadIdx.x; i < DIN * DOUT; i += blockDim.x) Ws[i] = W[i];
    __syncthreads();
    int idx = blockIdx.x * blockDim.x + threadIdx.x;
    if (idx >= n * DOUT) return;
    int row = idx / DOUT, j = idx - row * DOUT;
    const float* xr = Xin + (size_t)row * ldin;
    float acc = BIAS ? b[j] : 0.f;
#pragma unroll
    for (int i = 0; i < DIN; ++i) acc = fmaf(xr[i], Ws[i * DOUT + j], acc);
    if (RELU) acc = fmaxf(acc, 0.f);
    Out[idx] = acc;
}

// ---------------- alpha / yh: per-batch kernel regression ----------------
__global__ __launch_bounds__(256) void k_alpha(const float* __restrict__ X1,  // n1 x 34 (g1 out)
                                               const float* __restrict__ X,   // n1 x 35 (y col)
                                               float* __restrict__ X2,        // n2 x 35, writes col 34
                                               const float* __restrict__ theta,
                                               const float* __restrict__ A,
                                               const float* __restrict__ scale)
{
    const int b = blockIdx.x;
    const int t = threadIdx.x;
    const int p = t & 63;
    const int w = t >> 6;
    __shared__ float th[34 * 34];
    __shared__ float xpS[64 * 35];
    __shared__ float xfS[16 * 34];
    __shared__ float UfS[16 * 34];
    __shared__ float upPart[4][64];
    __shared__ float upS[64];
    __shared__ float yS[64];

    for (int i = t; i < 34 * 34; i += 256) th[i] = theta[i];
    for (int i = t; i < 64 * 34; i += 256) {
        int r = i / 34, o = i - 34 * r;
        xpS[r * 35 + o] = X1[(size_t)(b * 64 + r) * 34 + o];
    }
    for (int i = t; i < 16 * 34; i += 256) {
        int q = i / 34, o = i - 34 * q;
        xfS[i] = X2[(size_t)(b * 16 + q) * 35 + o];
    }
    if (t < 64) yS[t] = X[(size_t)(b * 64 + t) * 35 + 34];
    __syncthreads();

    for (int i = t; i < 16 * 34; i += 256) {
        int q = i / 34, o = i - 34 * q;
        float a = 0.f;
#pragma unroll
        for (int O = 0; O < 34; ++O) a = fmaf(th[o * 34 + O], xfS[q * 34 + O], a);
        UfS[i] = a;
    }
    {
        const int o0 = w * 9;
        const int o1 = (o0 + 9 < 34) ? o0 + 9 : 34;
        float a = 0.f;
        for (int o = o0; o < o1; ++o) {
            float s2 = 0.f;
#pragma unroll
            for (int O = 0; O < 34; ++O) s2 = fmaf(th[o * 34 + O], xpS[p * 35 + O], s2);
            a = fmaf(xpS[p * 35 + o], s2, a);
        }
        upPart[w][p] = a;
    }
    __syncthreads();
    if (t < 64) upS[t] = upPart[0][t] + upPart[1][t] + upPart[2][t] + upPart[3][t];
    __syncthreads();

    const float sc = scale[0];
    const float up = upS[p];
    const float y = yS[p];
#pragma unroll
    for (int i = 0; i < 4; ++i) {
        const int q = w + 4 * i;
        float g = 0.f;
#pragma unroll
        for (int o = 0; o < 34; ++o) g = fmaf(UfS[q * 34 + o], xpS[p * 35 + o], g);
        float a = sc * (up - 2.f * g);
        if (A[(PASTN + q) * NN + p] == 0.f) a = -INFINITY;
        float mx = a;
#pragma unroll
        for (int off = 32; off > 0; off >>= 1) mx = fmaxf(mx, __shfl_xor(mx, off));
        float e = expf(a - mx);
        float s = e;
#pragma unroll
        for (int off = 32; off > 0; off >>= 1) s += __shfl_xor(s, off);
        float c = (e / s) * y;
#pragma unroll
        for (int off = 32; off > 0; off >>= 1) c += __shfl_xor(c, off);
        if (p == 0) X2[(size_t)(b * 16 + q) * 35 + 34] = c;
    }
}

// ---------------- pairwise distances (float4, ld 40 padded) ----------------
__global__ __launch_bounds__(256) void k_cd(const float* __restrict__ X, const float* __restrict__ X2,
                                            float* __restrict__ cd)
{
    const int b = blockIdx.x;
    const int t = threadIdx.x;
    __shared__ float xa[80 * 40];
    __shared__ float sq[80];
    for (int idx = t; idx < 80 * 40; idx += 256) {
        int nrow = idx / 40, k = idx - 40 * nrow;
        float v = 0.f;
        if (k < 35)
            v = (nrow < 64) ? X[(size_t)(b * 64 + nrow) * 35 + k]
                            : X2[(size_t)(b * 16 + (nrow - 64)) * 35 + k];
        xa[idx] = v;
    }
    __syncthreads();
    const float4* xa4 = (const float4*)xa;
    if (t < 80) {
        float acc = 0.f;
#pragma unroll
        for (int c = 0; c < 10; ++c) {
            float4 v = xa4[t * 10 + c];
            acc = fmaf(v.x, v.x, fmaf(v.y, v.y, fmaf(v.z, v.z, fmaf(v.w, v.w, acc))));
        }
        sq[t] = acc;
    }
    __syncthreads();
    for (int idx = t; idx < 6400; idx += 256) {
        int n_ = idx / 80, m = idx - 80 * n_;
        float dot = 0.f;
#pragma unroll
        for (int c = 0; c < 10; ++c) {
            float4 a4 = xa4[n_ * 10 + c];
            float4 b4 = xa4[m * 10 + c];
            dot = fmaf(a4.x, b4.x, fmaf(a4.y, b4.y, fmaf(a4.z, b4.z, fmaf(a4.w, b4.w, dot))));
        }
        float d2 = sq[n_] + sq[m] - 2.f * dot;
        cd[(size_t)b * 6400 + idx] = sqrtf(fmaxf(d2, 0.f));
    }
}

extern "C" void kernel_launch(void* const* d_in, const int* in_sizes, int n_in,
                              void* d_out, int out_size, void* d_ws, size_t ws_size,
                              hipStream_t stream)
{
    const int* x1_cat = (const int*)d_in[0];
    const float* x1_num = (const float*)d_in[1];
    const int* x2_cat = (const int*)d_in[2];
    const float* x2_num = (const float*)d_in[3];
    const int* e1 = (const int*)d_in[4];
    const int* e2 = (const int*)d_in[5];
    const float* emb0 = (const float*)d_in[6];
    const float* emb1 = (const float*)d_in[7];
    const float* emb2 = (const float*)d_in[8];
    const float* pW1 = (const float*)d_in[9];
    const float* pb1 = (const float*)d_in[10];
    const float* pW2 = (const float*)d_in[11];
    const float* pb2 = (const float*)d_in[12];
    const float* pW3 = (const float*)d_in[13];
    const float* pb3 = (const float*)d_in[14];
    const float* g1W1 = (const float*)d_in[15];
    const float* g1b1 = (const float*)d_in[16];
    const float* g1W2 = (const float*)d_in[17];
    const float* g1b2 = (const float*)d_in[18];
    const float* g2W1 = (const float*)d_in[19];
    const float* g2b1 = (const float*)d_in[20];
    const float* g2W2 = (const float*)d_in[21];
    const float* g2b2 = (const float*)d_in[22];
    const float* kerW = (const float*)d_in[23];
    const float* smoothing = (const float*)d_in[24];
    const float* M = (const float*)d_in[25];

    const int n1 = in_sizes[0] / 3;
    const int n2 = in_sizes[2] / 3;
    const int E1 = in_sizes[4] / 2;
    const int E2 = in_sizes[5] / 2;
    const int SBc = n2 / FUTN;

    float* w = (float*)d_ws;
    size_t off = 0;
    float* scale = w + off; off += 16;
    float* theta = w + off; off += 1184;
    float* Aws = w + off; off += 6400;
    float* X = w + off; off += (size_t)n1 * 35;
    float* X2 = w + off; off += (size_t)n2 * 35;
    float* dinv1 = w + off; off += (size_t)n1;
    float* dinv2 = w + off; off += (size_t)n2;
    float* B2 = w + off; off += (size_t)n1 * 64;
    float* B3 = w + off; off += (size_t)n1 * 34;
    float* B4 = w + off; off += (size_t)n1 * 34;
    int* iw = (int*)(w + off);
    size_t ioff = 0;
    int* degi1 = iw + ioff; ioff += n1;
    int* rs1 = iw + ioff; ioff += n1;
    int* cur1 = iw + ioff; ioff += n1;
    int* srcs1 = iw + ioff; ioff += E1;
    int* degi2 = iw + ioff; ioff += n2;
    int* rs2 = iw + ioff; ioff += n2;
    int* cur2 = iw + ioff; ioff += n2;
    int* srcs2 = iw + ioff; ioff += E2;
    int* bsumA = iw + ioff; ioff += 1024;
    int* bsumB = iw + ioff; ioff += 1024;

    float* out_f = (float*)d_out;
    float* cd_f = out_f + (size_t)SBc * FUTN;
    float* A_out = cd_f + (size_t)SBc * NN * NN;

    auto cdiv = [](long long a, long long b) { return (unsigned)((a + b - 1) / b); };

    // ---- degrees + CSR build ----
    hipMemsetAsync(degi1, 0, (size_t)n1 * 4, stream);
    hipMemsetAsync(degi2, 0, (size_t)n2 * 4, stream);
    k_setup<<<1, 256, 0, stream>>>(M, kerW, smoothing, Aws, A_out, theta, scale);
    k_deg<<<cdiv(E1, 256), 256, 0, stream>>>(e1 + E1, degi1, E1);
    k_deg<<<cdiv(E2, 256), 256, 0, stream>>>(e2 + E2, degi2, E2);
    k_dinv<<<cdiv(n1, 256), 256, 0, stream>>>(degi1, dinv1, n1);
    k_dinv<<<cdiv(n2, 256), 256, 0, stream>>>(degi2, dinv2, n2);

    const int nb1 = cdiv(n1, SCHUNK), nb2 = cdiv(n2, SCHUNK);
    k_scan_reduce<<<nb1, 256, 0, stream>>>(degi1, bsumA, n1);
    k_scan_mid<<<1, 1024, 0, stream>>>(bsumA, nb1);
    k_scan_final<<<nb1, 256, 0, stream>>>(degi1, bsumA, rs1, n1);
    k_scan_reduce<<<nb2, 256, 0, stream>>>(degi2, bsumB, n2);
    k_scan_mid<<<1, 1024, 0, stream>>>(bsumB, nb2);
    k_scan_final<<<nb2, 256, 0, stream>>>(degi2, bsumB, rs2, n2);

    hipMemcpyAsync(cur1, rs1, (size_t)n1 * 4, hipMemcpyDeviceToDevice, stream);
    hipMemcpyAsync(cur2, rs2, (size_t)n2 * 4, hipMemcpyDeviceToDevice, stream);
    k_fill<<<cdiv(E1, 256), 256, 0, stream>>>(e1, e1 + E1, cur1, srcs1, E1);
    k_fill<<<cdiv(E2, 256), 256, 0, stream>>>(e2, e2 + E2, cur2, srcs2, E2);

    // ---- pre MLP ----
    k_pre<<<n1 / PR, 256, 0, stream>>>(x1_cat, x1_num, emb0, emb1, emb2, pW1, pb1, pW2, pb2, pW3, pb3, X, n1);
    k_pre<<<n2 / PR, 256, 0, stream>>>(x2_cat, x2_num, emb0, emb1, emb2, pW1, pb1, pW2, pb2, pW3, pb3, X2, n2);

    // ---- g1 layer 1: fused pull(35)+gemm(35->64)+relu ----
    k_gcn_a<35><<<cdiv(n1, 4), 256, 0, stream>>>(rs1, degi1, srcs1, dinv1, X, g1W1, g1b1, B2, n1);

    // ---- g1 layer 2: gemm 64->34 then fused pull(34)+combine ----
    k_gemm<64, 34, false, false><<<cdiv((long long)n1 * 34, 256), 256, 0, stream>>>(B2, 64, g1W2, nullptr, B3, n1);
    k_pcomb<34><<<cdiv(n1, 4), 256, 0, stream>>>(rs1, degi1, srcs1, dinv1, B3, g1b2, B4, n1);

    // ---- alpha / yh -> X2 col 34 ----
    k_alpha<<<SBc, 256, 0, stream>>>(B4, X, X2, theta, Aws, scale);

    // ---- g2 layer 1 ----
    k_gcn_a<35><<<cdiv(n2, 4), 256, 0, stream>>>(rs2, degi2, srcs2, dinv2, X2, g2W1, g2b1, B2, n2);

    // ---- g2 layer 2: gemm 64->1, fused pull+combine ----
    k_gemm<64, 1, false, false><<<cdiv(n2, 256), 256, 0, stream>>>(B2, 64, g2W2, nullptr, B3, n2);
    k_pcomb1<<<cdiv(n2, 256), 256, 0, stream>>>(rs2, degi2, srcs2, dinv2, B3, g2b2, out_f, n2);

    // ---- pairwise distances ----
    k_cd<<<SBc, 256, 0, stream>>>(X, X2, cd_f);
}

// Round 6
// 824.336 us; speedup vs baseline: 1.7874x; 1.1906x over previous
//
#include <hip/hip_runtime.h>
#include <math.h>

#define PASTN 64
#define FUTN 16
#define NN 80

// ---------------- setup: A (causal softmax of relu(M M^T)), theta, scale ----------------
__global__ __launch_bounds__(256) void k_setup(const float* __restrict__ M, const float* __restrict__ kerW,
                                               const float* __restrict__ smoothing,
                                               float* __restrict__ A_ws, float* __restrict__ A_out,
                                               float* __restrict__ theta, float* __restrict__ scale)
{
    __shared__ float Ms[80 * 26];
    __shared__ float Ar[80 * 80];
    const int t = threadIdx.x;
    for (int i = t; i < 80 * 26; i += 256) Ms[i] = M[i];
    __syncthreads();
    for (int idx = t; idx < 6400; idx += 256) {
        int i = idx / 80, j = idx - 80 * i;
        float acc = 0.f;
#pragma unroll
        for (int k = 0; k < 26; ++k) acc = fmaf(Ms[i * 26 + k], Ms[j * 26 + k], acc);
        Ar[idx] = fmaxf(acc, 0.f);
    }
    __syncthreads();
    if (t < 80) {
        float mx = -1e30f;
        for (int j = 0; j <= t; ++j) mx = fmaxf(mx, Ar[t * 80 + j]);
        float s = 0.f;
        for (int j = 0; j <= t; ++j) s += expf(Ar[t * 80 + j] - mx);
        float inv = 1.f / s;
        for (int j = 0; j < 80; ++j) {
            float v = (j <= t) ? expf(Ar[t * 80 + j] - mx) * inv : 0.f;
            A_ws[t * 80 + j] = v;
            A_out[t * 80 + j] = v;
        }
    }
    for (int idx = t; idx < 34 * 34; idx += 256) {
        int i = idx / 34, j = idx - 34 * i;
        float acc = 0.f;
        for (int k = 0; k < 128; ++k) acc = fmaf(kerW[i * 128 + k], kerW[j * 128 + k], acc);
        theta[idx] = acc;
    }
    if (t == 0) {
        float s0 = smoothing[0];
        float sig = 1.f / (1.f + expf(-s0));
        scale[0] = -0.5f / (sig * 0.01f);
    }
}

// ---------------- degree (int) / dinv ----------------
__global__ void k_deg(const int* __restrict__ dst, int* __restrict__ deg, int E)
{
    int e = blockIdx.x * blockDim.x + threadIdx.x;
    if (e < E) atomicAdd(&deg[dst[e]], 1);
}

__global__ void k_dinv(const int* __restrict__ deg, float* __restrict__ d, int n)
{
    int i = blockIdx.x * blockDim.x + threadIdx.x;
    if (i < n) d[i] = rsqrtf(1.f + (float)deg[i]);
}

// ---------------- exclusive scan (3-phase), chunk = 1024 ----------------
#define SCHUNK 1024
__global__ __launch_bounds__(256) void k_scan_reduce(const int* __restrict__ deg, int* __restrict__ bsum, int n)
{
    __shared__ int sd[256];
    const int b = blockIdx.x, t = threadIdx.x;
    const int base = b * SCHUNK;
    int s = 0;
#pragma unroll
    for (int j = 0; j < 4; ++j) {
        int i = base + t + j * 256;
        if (i < n) s += deg[i];
    }
    sd[t] = s;
    __syncthreads();
    for (int o = 128; o > 0; o >>= 1) {
        if (t < o) sd[t] += sd[t + o];
        __syncthreads();
    }
    if (t == 0) bsum[b] = sd[0];
}

__global__ __launch_bounds__(1024) void k_scan_mid(int* __restrict__ bsum, int nb)
{
    __shared__ int sd[1024];
    const int t = threadIdx.x;
    int orig = (t < nb) ? bsum[t] : 0;
    sd[t] = orig;
    __syncthreads();
    for (int o = 1; o < 1024; o <<= 1) {
        int v = (t >= o) ? sd[t - o] : 0;
        __syncthreads();
        sd[t] += v;
        __syncthreads();
    }
    if (t < nb) bsum[t] = sd[t] - orig;  // exclusive
}

__global__ __launch_bounds__(256) void k_scan_final(const int* __restrict__ deg, const int* __restrict__ bsum,
                                                    int* __restrict__ rs, int n)
{
    __shared__ int sd[256];
    const int b = blockIdx.x, t = threadIdx.x;
    const int base = b * SCHUNK + t * 4;
    int v0 = (base + 0 < n) ? deg[base + 0] : 0;
    int v1 = (base + 1 < n) ? deg[base + 1] : 0;
    int v2 = (base + 2 < n) ? deg[base + 2] : 0;
    int v3 = (base + 3 < n) ? deg[base + 3] : 0;
    int tsum = v0 + v1 + v2 + v3;
    sd[t] = tsum;
    __syncthreads();
    int incl = tsum;
    for (int o = 1; o < 256; o <<= 1) {
        int v = (t >= o) ? sd[t - o] : 0;
        __syncthreads();
        incl += v;
        sd[t] = incl;
        __syncthreads();
    }
    int off = bsum[b] + incl - tsum;
    if (base + 0 < n) rs[base + 0] = off;
    if (base + 1 < n) rs[base + 1] = off + v0;
    if (base + 2 < n) rs[base + 2] = off + v0 + v1;
    if (base + 3 < n) rs[base + 3] = off + v0 + v1 + v2;
}

// ---------------- CSR fill (counting sort of src by dst) ----------------
__global__ void k_fill(const int* __restrict__ src, const int* __restrict__ dst,
                       int* __restrict__ cur, int* __restrict__ srcs_sorted, int E)
{
    int e = blockIdx.x * blockDim.x + threadIdx.x;
    if (e < E) {
        int pos = atomicAdd(&cur[dst[e]], 1);
        srcs_sorted[pos] = src[e];
    }
}

// ---------------- fused GCN layer 1 (scaled input): pull(DIN rows of Hs) + gemm(DIN->64) + relu
// Hs rows are pre-scaled by dinv[src]. agg = Hs[row] + sum_edges Hs[s];
// Out[row,col] = relu( dinv[row] * (agg . W[:,col]) + b[col] )
template <int DIN>
__global__ __launch_bounds__(256) void k_gcn_s(const int* __restrict__ rs, const int* __restrict__ deg,
                                               const int* __restrict__ srcs, const float* __restrict__ dinv,
                                               const float* __restrict__ Hs, const float* __restrict__ W,
                                               const float* __restrict__ b, float* __restrict__ Out, int n)
{
    const int w = threadIdx.x >> 6, lane = threadIdx.x & 63;
    const int row = blockIdx.x * 4 + w;
    __shared__ float ag[4][DIN];
    const float di = dinv[row];
    const int e0 = rs[row];
    const int d = deg[row];
    float acc = (lane < DIN) ? Hs[(size_t)row * DIN + lane] : 0.f;
    int e = 0;
    for (; e + 4 <= d; e += 4) {
        int s0 = srcs[e0 + e + 0];
        int s1 = srcs[e0 + e + 1];
        int s2 = srcs[e0 + e + 2];
        int s3 = srcs[e0 + e + 3];
        float h0 = 0.f, h1 = 0.f, h2 = 0.f, h3 = 0.f;
        if (lane < DIN) {
            h0 = Hs[(size_t)s0 * DIN + lane];
            h1 = Hs[(size_t)s1 * DIN + lane];
            h2 = Hs[(size_t)s2 * DIN + lane];
            h3 = Hs[(size_t)s3 * DIN + lane];
        }
        acc += (h0 + h1) + (h2 + h3);
    }
    for (; e < d; ++e) {
        int s = srcs[e0 + e];
        if (lane < DIN) acc += Hs[(size_t)s * DIN + lane];
    }
    if (lane < DIN) ag[w][lane] = acc;
    __syncthreads();
    float o = 0.f;
#pragma unroll
    for (int i = 0; i < DIN; ++i) o = fmaf(ag[w][i], W[i * 64 + lane], o);
    Out[(size_t)row * 64 + lane] = fmaxf(fmaf(di, o, b[lane]), 0.f);
}

// ---------------- fused pull+combine (scaled input): dest = di*(Hs[row] + sum Hs[s]) + b
template <int D>
__global__ __launch_bounds__(256) void k_pcomb_s(const int* __restrict__ rs, const int* __restrict__ deg,
                                                 const int* __restrict__ srcs, const float* __restrict__ dinv,
                                                 const float* __restrict__ Hs, const float* __restrict__ b,
                                                 float* __restrict__ dest, int n)
{
    const int wid = (blockIdx.x * blockDim.x + threadIdx.x) >> 6;
    const int lane = threadIdx.x & 63;
    if (wid >= n) return;
    const float di = dinv[wid];
    const int e0 = rs[wid];
    const int d = deg[wid];
    float acc = (lane < D) ? Hs[(size_t)wid * D + lane] : 0.f;
    int e = 0;
    for (; e + 4 <= d; e += 4) {
        int s0 = srcs[e0 + e + 0];
        int s1 = srcs[e0 + e + 1];
        int s2 = srcs[e0 + e + 2];
        int s3 = srcs[e0 + e + 3];
        float h0 = 0.f, h1 = 0.f, h2 = 0.f, h3 = 0.f;
        if (lane < D) {
            h0 = Hs[(size_t)s0 * D + lane];
            h1 = Hs[(size_t)s1 * D + lane];
            h2 = Hs[(size_t)s2 * D + lane];
            h3 = Hs[(size_t)s3 * D + lane];
        }
        acc += (h0 + h1) + (h2 + h3);
    }
    for (; e < d; ++e) {
        int s = srcs[e0 + e];
        if (lane < D) acc += Hs[(size_t)s * D + lane];
    }
    if (lane < D) dest[(size_t)wid * D + lane] = fmaf(di, acc, b[lane]);
}

// D=1 scaled pull+combine: thread per row
__global__ void k_pcomb1_s(const int* __restrict__ rs, const int* __restrict__ deg,
                           const int* __restrict__ srcs, const float* __restrict__ dinv,
                           const float* __restrict__ Hs, const float* __restrict__ b,
                           float* __restrict__ dest, int n)
{
    int r = blockIdx.x * blockDim.x + threadIdx.x;
    if (r >= n) return;
    int e0 = rs[r], d = deg[r];
    float acc = Hs[r];
    int e = 0;
    for (; e + 4 <= d; e += 4) {
        int s0 = srcs[e0 + e + 0];
        int s1 = srcs[e0 + e + 1];
        int s2 = srcs[e0 + e + 2];
        int s3 = srcs[e0 + e + 3];
        acc += (Hs[s0] + Hs[s1]) + (Hs[s2] + Hs[s3]);
    }
    for (; e < d; ++e) acc += Hs[srcs[e0 + e]];
    dest[r] = fmaf(dinv[r], acc, b[0]);
}

// ---------------- pre MLP: 35 -> 128 -> 128 -> 34 (+passthrough num col) ----------------
// Writes X (raw) and Xs (scaled by dinv[row]) in one pass.
#define PR 32
__global__ __launch_bounds__(256) void k_pre(const int* __restrict__ cat, const float* __restrict__ num,
                                             const float* __restrict__ emb0, const float* __restrict__ emb1,
                                             const float* __restrict__ emb2,
                                             const float* __restrict__ W1, const float* __restrict__ b1,
                                             const float* __restrict__ W2, const float* __restrict__ b2,
                                             const float* __restrict__ W3, const float* __restrict__ b3,
                                             const float* __restrict__ dinv,
                                             float* __restrict__ X, float* __restrict__ Xs, int nrows)
{
    __shared__ float oT[35 * PR];
    __shared__ float h1T[128 * PR];
    __shared__ float h2T[128 * PR];
    const int t = threadIdx.x;
    const int ct = t & 31;
    const int rg = t >> 5;  // 0..7
    const int base = blockIdx.x * PR;

    for (int idx = t; idx < 35 * PR; idx += 256) {
        int i = idx >> 5, r = idx & 31;
        int row = base + r;
        float v;
        if (i < 16) v = emb0[cat[row * 3 + 0] * 16 + i];
        else if (i < 24) v = emb1[cat[row * 3 + 1] * 8 + (i - 16)];
        else if (i < 32) v = emb2[cat[row * 3 + 2] * 8 + (i - 24)];
        else v = num[row * 3 + (i - 32)];
        oT[i * PR + (((r >> 2) ^ (i & 7)) << 2) + (r & 3)] = v;
    }
    __syncthreads();

    float acc[4][4];
    // layer 1: 35 -> 128
    {
        float4 bb = *(const float4*)(b1 + 4 * ct);
        const float bbv[4] = {bb.x, bb.y, bb.z, bb.w};
#pragma unroll
        for (int c = 0; c < 4; ++c)
#pragma unroll
            for (int r = 0; r < 4; ++r) acc[c][r] = bbv[c];
        for (int i = 0; i < 35; ++i) {
            float4 ov = *(const float4*)(oT + i * PR + ((rg ^ (i & 7)) << 2));
            float4 wv = *(const float4*)(W1 + i * 128 + 4 * ct);
            const float o4[4] = {ov.x, ov.y, ov.z, ov.w};
            const float w4[4] = {wv.x, wv.y, wv.z, wv.w};
#pragma unroll
            for (int c = 0; c < 4; ++c)
#pragma unroll
                for (int r = 0; r < 4; ++r) acc[c][r] = fmaf(w4[c], o4[r], acc[c][r]);
        }
#pragma unroll
        for (int c = 0; c < 4; ++c) {
            int col = 4 * ct + c;
            float4 v;
            v.x = fmaxf(acc[c][0], 0.f);
            v.y = fmaxf(acc[c][1], 0.f);
            v.z = fmaxf(acc[c][2], 0.f);
            v.w = fmaxf(acc[c][3], 0.f);
            *(float4*)(h1T + col * PR + ((rg ^ (col & 7)) << 2)) = v;
        }
    }
    __syncthreads();
    // layer 2: 128 -> 128
    {
        float4 bb = *(const float4*)(b2 + 4 * ct);
        const float bbv[4] = {bb.x, bb.y, bb.z, bb.w};
#pragma unroll
        for (int c = 0; c < 4; ++c)
#pragma unroll
            for (int r = 0; r < 4; ++r) acc[c][r] = bbv[c];
#pragma unroll 4
        for (int k = 0; k < 128; ++k) {
            float4 hv = *(const float4*)(h1T + k * PR + ((rg ^ (k & 7)) << 2));
            float4 wv = *(const float4*)(W2 + k * 128 + 4 * ct);
            const float h4[4] = {hv.x, hv.y, hv.z, hv.w};
            const float w4[4] = {wv.x, wv.y, wv.z, wv.w};
#pragma unroll
            for (int c = 0; c < 4; ++c)
#pragma unroll
                for (int r = 0; r < 4; ++r) acc[c][r] = fmaf(w4[c], h4[r], acc[c][r]);
        }
#pragma unroll
        for (int c = 0; c < 4; ++c) {
            int col = 4 * ct + c;
            float4 v;
            v.x = fmaxf(acc[c][0], 0.f);
            v.y = fmaxf(acc[c][1], 0.f);
            v.z = fmaxf(acc[c][2], 0.f);
            v.w = fmaxf(acc[c][3], 0.f);
            *(float4*)(h2T + col * PR + ((rg ^ (col & 7)) << 2)) = v;
        }
    }
    __syncthreads();
    // layer 3: 128 -> 34, tasks = (j, row-group): 34*8 = 272
    for (int task = t; task < 34 * 8; task += 256) {
        int j = task >> 3, rg3 = task & 7;
        float a0 = b3[j], a1 = a0, a2 = a0, a3 = a0;
#pragma unroll 4
        for (int k = 0; k < 128; ++k) {
            float4 hv = *(const float4*)(h2T + k * PR + ((rg3 ^ (k & 7)) << 2));
            float wv = W3[k * 34 + j];
            a0 = fmaf(hv.x, wv, a0);
            a1 = fmaf(hv.y, wv, a1);
            a2 = fmaf(hv.z, wv, a2);
            a3 = fmaf(hv.w, wv, a3);
        }
        size_t rb = (size_t)(base + rg3 * 4);
        float d0 = dinv[rb + 0], d1 = dinv[rb + 1], d2 = dinv[rb + 2], d3 = dinv[rb + 3];
        X[(rb + 0) * 35 + j] = a0;  Xs[(rb + 0) * 35 + j] = a0 * d0;
        X[(rb + 1) * 35 + j] = a1;  Xs[(rb + 1) * 35 + j] = a1 * d1;
        X[(rb + 2) * 35 + j] = a2;  Xs[(rb + 2) * 35 + j] = a2 * d2;
        X[(rb + 3) * 35 + j] = a3;  Xs[(rb + 3) * 35 + j] = a3 * d3;
    }
    if (t < PR) {
        int row = base + t;
        float v = num[row * 3 + 2];
        X[(size_t)row * 35 + 34] = v;
        Xs[(size_t)row * 35 + 34] = v * dinv[row];
    }
}

// ---------------- plain dense gemm (row-major W: DIN x DOUT), optional output scale ----------------
template <int DIN, int DOUT, bool BIAS, bool RELU, bool SCALE>
__global__ void k_gemm(const float* __restrict__ Xin, int ldin, const float* __restrict__ W,
                       const float* __restrict__ b, const float* __restrict__ oscale,
                       float* __restrict__ Out, int n)
{
    __shared__ float Ws[DIN * DOUT];
    for (int i = threadIdx.x; i < DIN * DOUT; i += blockDim.x) Ws[i] = W[i];
    __syncthreads();
    int idx = blockIdx.x * blockDim.x + threadIdx.x;
    if (idx >= n * DOUT) return;
    int row = idx / DOUT, j = idx - row * DOUT;
    const float* xr = Xin + (size_t)row * ldin;
    float acc = BIAS ? b[j] : 0.f;
#pragma unroll
    for (int i = 0; i < DIN; ++i) acc = fmaf(xr[i], Ws[i * DOUT + j], acc);
    if (RELU) acc = fmaxf(acc, 0.f);
    if (SCALE) acc *= oscale[row];
    Out[idx] = acc;
}

// ---------------- alpha / yh: per-batch kernel regression ----------------
// Writes yh into X2 col 34 (raw) and Xs2 col 34 (scaled by dinv2).
__global__ __launch_bounds__(256) void k_alpha(const float* __restrict__ X1,  // n1 x 34 (g1 out)
                                               const float* __restrict__ X,   // n1 x 35 (y col)
                                               float* __restrict__ X2,        // n2 x 35
                                               float* __restrict__ Xs2,       // n2 x 35 scaled
                                               const float* __restrict__ dinv2,
                                               const float* __restrict__ theta,
                                               const float* __restrict__ A,
                                               const float* __restrict__ scale)
{
    const int b = blockIdx.x;
    const int t = threadIdx.x;
    const int p = t & 63;
    const int w = t >> 6;
    __shared__ float th[34 * 34];
    __shared__ float xpS[64 * 35];
    __shared__ float xfS[16 * 34];
    __shared__ float UfS[16 * 34];
    __shared__ float upPart[4][64];
    __shared__ float upS[64];
    __shared__ float yS[64];

    for (int i = t; i < 34 * 34; i += 256) th[i] = theta[i];
    for (int i = t; i < 64 * 34; i += 256) {
        int r = i / 34, o = i - 34 * r;
        xpS[r * 35 + o] = X1[(size_t)(b * 64 + r) * 34 + o];
    }
    for (int i = t; i < 16 * 34; i += 256) {
        int q = i / 34, o = i - 34 * q;
        xfS[i] = X2[(size_t)(b * 16 + q) * 35 + o];
    }
    if (t < 64) yS[t] = X[(size_t)(b * 64 + t) * 35 + 34];
    __syncthreads();

    for (int i = t; i < 16 * 34; i += 256) {
        int q = i / 34, o = i - 34 * q;
        float a = 0.f;
#pragma unroll
        for (int O = 0; O < 34; ++O) a = fmaf(th[o * 34 + O], xfS[q * 34 + O], a);
        UfS[i] = a;
    }
    {
        const int o0 = w * 9;
        const int o1 = (o0 + 9 < 34) ? o0 + 9 : 34;
        float a = 0.f;
        for (int o = o0; o < o1; ++o) {
            float s2 = 0.f;
#pragma unroll
            for (int O = 0; O < 34; ++O) s2 = fmaf(th[o * 34 + O], xpS[p * 35 + O], s2);
            a = fmaf(xpS[p * 35 + o], s2, a);
        }
        upPart[w][p] = a;
    }
    __syncthreads();
    if (t < 64) upS[t] = upPart[0][t] + upPart[1][t] + upPart[2][t] + upPart[3][t];
    __syncthreads();

    const float sc = scale[0];
    const float up = upS[p];
    const float y = yS[p];
#pragma unroll
    for (int i = 0; i < 4; ++i) {
        const int q = w + 4 * i;
        float g = 0.f;
#pragma unroll
        for (int o = 0; o < 34; ++o) g = fmaf(UfS[q * 34 + o], xpS[p * 35 + o], g);
        float a = sc * (up - 2.f * g);
        if (A[(PASTN + q) * NN + p] == 0.f) a = -INFINITY;
        float mx = a;
#pragma unroll
        for (int off = 32; off > 0; off >>= 1) mx = fmaxf(mx, __shfl_xor(mx, off));
        float e = expf(a - mx);
        float s = e;
#pragma unroll
        for (int off = 32; off > 0; off >>= 1) s += __shfl_xor(s, off);
        float c = (e / s) * y;
#pragma unroll
        for (int off = 32; off > 0; off >>= 1) c += __shfl_xor(c, off);
        if (p == 0) {
            size_t ridx = (size_t)(b * 16 + q);
            X2[ridx * 35 + 34] = c;
            Xs2[ridx * 35 + 34] = c * dinv2[ridx];
        }
    }
}

// ---------------- pairwise distances (float4, ld 40 padded) ----------------
__global__ __launch_bounds__(256) void k_cd(const float* __restrict__ X, const float* __restrict__ X2,
                                            float* __restrict__ cd)
{
    const int b = blockIdx.x;
    const int t = threadIdx.x;
    __shared__ float xa[80 * 40];
    __shared__ float sq[80];
    for (int idx = t; idx < 80 * 40; idx += 256) {
        int nrow = idx / 40, k = idx - 40 * nrow;
        float v = 0.f;
        if (k < 35)
            v = (nrow < 64) ? X[(size_t)(b * 64 + nrow) * 35 + k]
                            : X2[(size_t)(b * 16 + (nrow - 64)) * 35 + k];
        xa[idx] = v;
    }
    __syncthreads();
    const float4* xa4 = (const float4*)xa;
    if (t < 80) {
        float acc = 0.f;
#pragma unroll
        for (int c = 0; c < 10; ++c) {
            float4 v = xa4[t * 10 + c];
            acc = fmaf(v.x, v.x, fmaf(v.y, v.y, fmaf(v.z, v.z, fmaf(v.w, v.w, acc))));
        }
        sq[t] = acc;
    }
    __syncthreads();
    for (int idx = t; idx < 6400; idx += 256) {
        int n_ = idx / 80, m = idx - 80 * n_;
        float dot = 0.f;
#pragma unroll
        for (int c = 0; c < 10; ++c) {
            float4 a4 = xa4[n_ * 10 + c];
            float4 b4 = xa4[m * 10 + c];
            dot = fmaf(a4.x, b4.x, fmaf(a4.y, b4.y, fmaf(a4.z, b4.z, fmaf(a4.w, b4.w, dot))));
        }
        float d2 = sq[n_] + sq[m] - 2.f * dot;
        cd[(size_t)b * 6400 + idx] = sqrtf(fmaxf(d2, 0.f));
    }
}

extern "C" void kernel_launch(void* const* d_in, const int* in_sizes, int n_in,
                              void* d_out, int out_size, void* d_ws, size_t ws_size,
                              hipStream_t stream)
{
    const int* x1_cat = (const int*)d_in[0];
    const float* x1_num = (const float*)d_in[1];
    const int* x2_cat = (const int*)d_in[2];
    const float* x2_num = (const float*)d_in[3];
    const int* e1 = (const int*)d_in[4];
    const int* e2 = (const int*)d_in[5];
    const float* emb0 = (const float*)d_in[6];
    const float* emb1 = (const float*)d_in[7];
    const float* emb2 = (const float*)d_in[8];
    const float* pW1 = (const float*)d_in[9];
    const float* pb1 = (const float*)d_in[10];
    const float* pW2 = (const float*)d_in[11];
    const float* pb2 = (const float*)d_in[12];
    const float* pW3 = (const float*)d_in[13];
    const float* pb3 = (const float*)d_in[14];
    const float* g1W1 = (const float*)d_in[15];
    const float* g1b1 = (const float*)d_in[16];
    const float* g1W2 = (const float*)d_in[17];
    const float* g1b2 = (const float*)d_in[18];
    const float* g2W1 = (const float*)d_in[19];
    const float* g2b1 = (const float*)d_in[20];
    const float* g2W2 = (const float*)d_in[21];
    const float* g2b2 = (const float*)d_in[22];
    const float* kerW = (const float*)d_in[23];
    const float* smoothing = (const float*)d_in[24];
    const float* M = (const float*)d_in[25];

    const int n1 = in_sizes[0] / 3;
    const int n2 = in_sizes[2] / 3;
    const int E1 = in_sizes[4] / 2;
    const int E2 = in_sizes[5] / 2;
    const int SBc = n2 / FUTN;

    float* w = (float*)d_ws;
    size_t off = 0;
    float* scale = w + off; off += 16;
    float* theta = w + off; off += 1184;
    float* Aws = w + off; off += 6400;
    float* X = w + off; off += (size_t)n1 * 35;
    float* Xs1 = w + off; off += (size_t)n1 * 35;
    float* X2 = w + off; off += (size_t)n2 * 35;
    float* Xs2 = w + off; off += (size_t)n2 * 35;
    float* dinv1 = w + off; off += (size_t)n1;
    float* dinv2 = w + off; off += (size_t)n2;
    float* B2 = w + off; off += (size_t)n1 * 64;
    float* B3 = w + off; off += (size_t)n1 * 34;
    float* B4 = w + off; off += (size_t)n1 * 34;
    int* iw = (int*)(w + off);
    size_t ioff = 0;
    int* degi1 = iw + ioff; ioff += n1;
    int* rs1 = iw + ioff; ioff += n1;
    int* cur1 = iw + ioff; ioff += n1;
    int* srcs1 = iw + ioff; ioff += E1;
    int* degi2 = iw + ioff; ioff += n2;
    int* rs2 = iw + ioff; ioff += n2;
    int* cur2 = iw + ioff; ioff += n2;
    int* srcs2 = iw + ioff; ioff += E2;
    int* bsumA = iw + ioff; ioff += 1024;
    int* bsumB = iw + ioff; ioff += 1024;

    float* out_f = (float*)d_out;
    float* cd_f = out_f + (size_t)SBc * FUTN;
    float* A_out = cd_f + (size_t)SBc * NN * NN;

    auto cdiv = [](long long a, long long b) { return (unsigned)((a + b - 1) / b); };

    // ---- degrees + CSR build ----
    hipMemsetAsync(degi1, 0, (size_t)n1 * 4, stream);
    hipMemsetAsync(degi2, 0, (size_t)n2 * 4, stream);
    k_setup<<<1, 256, 0, stream>>>(M, kerW, smoothing, Aws, A_out, theta, scale);
    k_deg<<<cdiv(E1, 256), 256, 0, stream>>>(e1 + E1, degi1, E1);
    k_deg<<<cdiv(E2, 256), 256, 0, stream>>>(e2 + E2, degi2, E2);
    k_dinv<<<cdiv(n1, 256), 256, 0, stream>>>(degi1, dinv1, n1);
    k_dinv<<<cdiv(n2, 256), 256, 0, stream>>>(degi2, dinv2, n2);

    const int nb1 = cdiv(n1, SCHUNK), nb2 = cdiv(n2, SCHUNK);
    k_scan_reduce<<<nb1, 256, 0, stream>>>(degi1, bsumA, n1);
    k_scan_mid<<<1, 1024, 0, stream>>>(bsumA, nb1);
    k_scan_final<<<nb1, 256, 0, stream>>>(degi1, bsumA, rs1, n1);
    k_scan_reduce<<<nb2, 256, 0, stream>>>(degi2, bsumB, n2);
    k_scan_mid<<<1, 1024, 0, stream>>>(bsumB, nb2);
    k_scan_final<<<nb2, 256, 0, stream>>>(degi2, bsumB, rs2, n2);

    hipMemcpyAsync(cur1, rs1, (size_t)n1 * 4, hipMemcpyDeviceToDevice, stream);
    hipMemcpyAsync(cur2, rs2, (size_t)n2 * 4, hipMemcpyDeviceToDevice, stream);
    k_fill<<<cdiv(E1, 256), 256, 0, stream>>>(e1, e1 + E1, cur1, srcs1, E1);
    k_fill<<<cdiv(E2, 256), 256, 0, stream>>>(e2, e2 + E2, cur2, srcs2, E2);

    // ---- pre MLP (writes raw + dinv-scaled copies) ----
    k_pre<<<n1 / PR, 256, 0, stream>>>(x1_cat, x1_num, emb0, emb1, emb2, pW1, pb1, pW2, pb2, pW3, pb3,
                                       dinv1, X, Xs1, n1);
    k_pre<<<n2 / PR, 256, 0, stream>>>(x2_cat, x2_num, emb0, emb1, emb2, pW1, pb1, pW2, pb2, pW3, pb3,
                                       dinv2, X2, Xs2, n2);

    // ---- g1 layer 1: fused pull(35, scaled)+gemm(35->64)+relu ----
    k_gcn_s<35><<<cdiv(n1, 4), 256, 0, stream>>>(rs1, degi1, srcs1, dinv1, Xs1, g1W1, g1b1, B2, n1);

    // ---- g1 layer 2: gemm 64->34 (output pre-scaled by dinv1) then fused pull+combine ----
    k_gemm<64, 34, false, false, true><<<cdiv((long long)n1 * 34, 256), 256, 0, stream>>>(B2, 64, g1W2, nullptr, dinv1, B3, n1);
    k_pcomb_s<34><<<cdiv(n1, 4), 256, 0, stream>>>(rs1, degi1, srcs1, dinv1, B3, g1b2, B4, n1);

    // ---- alpha / yh -> X2 col 34 (+ scaled copy) ----
    k_alpha<<<SBc, 256, 0, stream>>>(B4, X, X2, Xs2, dinv2, theta, Aws, scale);

    // ---- g2 layer 1 ----
    k_gcn_s<35><<<cdiv(n2, 4), 256, 0, stream>>>(rs2, degi2, srcs2, dinv2, Xs2, g2W1, g2b1, B2, n2);

    // ---- g2 layer 2: gemm 64->1 (pre-scaled), fused pull+combine ----
    k_gemm<64, 1, false, false, true><<<cdiv(n2, 256), 256, 0, stream>>>(B2, 64, g2W2, nullptr, dinv2, B3, n2);
    k_pcomb1_s<<<cdiv(n2, 256), 256, 0, stream>>>(rs2, degi2, srcs2, dinv2, B3, g2b2, out_f, n2);

    // ---- pairwise distances ----
    k_cd<<<SBc, 256, 0, stream>>>(X, X2, cd_f);
}

// Round 7
// 781.457 us; speedup vs baseline: 1.8855x; 1.0549x over previous
//
#include <hip/hip_runtime.h>
#include <math.h>

#define PASTN 64
#define FUTN 16
#define NN 80

// ---------------- setup: A (causal softmax of relu(M M^T)), theta, scale ----------------
__global__ __launch_bounds__(256) void k_setup(const float* __restrict__ M, const float* __restrict__ kerW,
                                               const float* __restrict__ smoothing,
                                               float* __restrict__ A_ws, float* __restrict__ A_out,
                                               float* __restrict__ theta, float* __restrict__ scale)
{
    __shared__ float Ms[80 * 26];
    __shared__ float Ar[80 * 80];
    const int t = threadIdx.x;
    for (int i = t; i < 80 * 26; i += 256) Ms[i] = M[i];
    __syncthreads();
    for (int idx = t; idx < 6400; idx += 256) {
        int i = idx / 80, j = idx - 80 * i;
        float acc = 0.f;
#pragma unroll
        for (int k = 0; k < 26; ++k) acc = fmaf(Ms[i * 26 + k], Ms[j * 26 + k], acc);
        Ar[idx] = fmaxf(acc, 0.f);
    }
    __syncthreads();
    if (t < 80) {
        float mx = -1e30f;
        for (int j = 0; j <= t; ++j) mx = fmaxf(mx, Ar[t * 80 + j]);
        float s = 0.f;
        for (int j = 0; j <= t; ++j) s += expf(Ar[t * 80 + j] - mx);
        float inv = 1.f / s;
        for (int j = 0; j < 80; ++j) {
            float v = (j <= t) ? expf(Ar[t * 80 + j] - mx) * inv : 0.f;
            A_ws[t * 80 + j] = v;
            A_out[t * 80 + j] = v;
        }
    }
    for (int idx = t; idx < 34 * 34; idx += 256) {
        int i = idx / 34, j = idx - 34 * i;
        float acc = 0.f;
        for (int k = 0; k < 128; ++k) acc = fmaf(kerW[i * 128 + k], kerW[j * 128 + k], acc);
        theta[idx] = acc;
    }
    if (t == 0) {
        float s0 = smoothing[0];
        float sig = 1.f / (1.f + expf(-s0));
        scale[0] = -0.5f / (sig * 0.01f);
    }
}

// ---------------- merged degree count (both graphs) ----------------
__global__ void k_deg2(const int* __restrict__ dst1, const int* __restrict__ dst2,
                       int* __restrict__ deg1, int* __restrict__ deg2,
                       int E1, int E2, int nbe1)
{
    int gb = blockIdx.x;
    if (gb < nbe1) {
        int e = gb * 256 + threadIdx.x;
        if (e < E1) atomicAdd(&deg1[dst1[e]], 1);
    } else {
        int e = (gb - nbe1) * 256 + threadIdx.x;
        if (e < E2) atomicAdd(&deg2[dst2[e]], 1);
    }
}

// ---------------- merged exclusive scan, chunk = 1024 ----------------
#define SCHUNK 1024
__global__ __launch_bounds__(256) void k_scan_reduce2(const int* __restrict__ deg1, const int* __restrict__ deg2,
                                                      int* __restrict__ bsumA, int* __restrict__ bsumB,
                                                      int n1, int n2, int nb1)
{
    __shared__ int sd[256];
    const int gb = blockIdx.x, t = threadIdx.x;
    const int which = (gb < nb1) ? 0 : 1;
    const int b = which ? gb - nb1 : gb;
    const int* deg = which ? deg2 : deg1;
    const int n = which ? n2 : n1;
    const int base = b * SCHUNK;
    int s = 0;
#pragma unroll
    for (int j = 0; j < 4; ++j) {
        int i = base + t + j * 256;
        if (i < n) s += deg[i];
    }
    sd[t] = s;
    __syncthreads();
    for (int o = 128; o > 0; o >>= 1) {
        if (t < o) sd[t] += sd[t + o];
        __syncthreads();
    }
    if (t == 0) (which ? bsumB : bsumA)[b] = sd[0];
}

__global__ __launch_bounds__(1024) void k_scan_mid2(int* __restrict__ bsumA, int* __restrict__ bsumB,
                                                    int nbA, int nbB)
{
    __shared__ int sd[1024];
    const int t = threadIdx.x;
    int* bsum = (blockIdx.x == 0) ? bsumA : bsumB;
    int nb = (blockIdx.x == 0) ? nbA : nbB;
    int orig = (t < nb) ? bsum[t] : 0;
    sd[t] = orig;
    __syncthreads();
    for (int o = 1; o < 1024; o <<= 1) {
        int v = (t >= o) ? sd[t - o] : 0;
        __syncthreads();
        sd[t] += v;
        __syncthreads();
    }
    if (t < nb) bsum[t] = sd[t] - orig;  // exclusive
}

// final scan; also writes cur (copy of rs) and dinv = rsqrt(1+deg)
__global__ __launch_bounds__(256) void k_scan_final2(const int* __restrict__ deg1, const int* __restrict__ deg2,
                                                     const int* __restrict__ bsumA, const int* __restrict__ bsumB,
                                                     int* __restrict__ rs1, int* __restrict__ rs2,
                                                     int* __restrict__ cur1, int* __restrict__ cur2,
                                                     float* __restrict__ dinv1, float* __restrict__ dinv2,
                                                     int n1, int n2, int nb1)
{
    __shared__ int sd[256];
    const int gb = blockIdx.x, t = threadIdx.x;
    const int which = (gb < nb1) ? 0 : 1;
    const int b = which ? gb - nb1 : gb;
    const int* deg = which ? deg2 : deg1;
    const int* bsum = which ? bsumB : bsumA;
    int* rs = which ? rs2 : rs1;
    int* cur = which ? cur2 : cur1;
    float* dinv = which ? dinv2 : dinv1;
    const int n = which ? n2 : n1;
    const int base = b * SCHUNK + t * 4;
    int v0 = (base + 0 < n) ? deg[base + 0] : 0;
    int v1 = (base + 1 < n) ? deg[base + 1] : 0;
    int v2 = (base + 2 < n) ? deg[base + 2] : 0;
    int v3 = (base + 3 < n) ? deg[base + 3] : 0;
    int tsum = v0 + v1 + v2 + v3;
    sd[t] = tsum;
    __syncthreads();
    int incl = tsum;
    for (int o = 1; o < 256; o <<= 1) {
        int v = (t >= o) ? sd[t - o] : 0;
        __syncthreads();
        incl += v;
        sd[t] = incl;
        __syncthreads();
    }
    int off = bsum[b] + incl - tsum;
    if (base + 0 < n) { rs[base + 0] = off;            cur[base + 0] = off;            dinv[base + 0] = rsqrtf(1.f + (float)v0); }
    if (base + 1 < n) { rs[base + 1] = off + v0;       cur[base + 1] = off + v0;       dinv[base + 1] = rsqrtf(1.f + (float)v1); }
    if (base + 2 < n) { rs[base + 2] = off + v0 + v1;  cur[base + 2] = off + v0 + v1;  dinv[base + 2] = rsqrtf(1.f + (float)v2); }
    if (base + 3 < n) { rs[base + 3] = off + v0 + v1 + v2; cur[base + 3] = off + v0 + v1 + v2; dinv[base + 3] = rsqrtf(1.f + (float)v3); }
}

// ---------------- merged CSR fill ----------------
__global__ void k_fill2(const int* __restrict__ src1, const int* __restrict__ dst1,
                        const int* __restrict__ src2, const int* __restrict__ dst2,
                        int* __restrict__ cur1, int* __restrict__ cur2,
                        int* __restrict__ out1, int* __restrict__ out2,
                        int E1, int E2, int nbe1)
{
    int gb = blockIdx.x;
    if (gb < nbe1) {
        int e = gb * 256 + threadIdx.x;
        if (e < E1) { int pos = atomicAdd(&cur1[dst1[e]], 1); out1[pos] = src1[e]; }
    } else {
        int e = (gb - nbe1) * 256 + threadIdx.x;
        if (e < E2) { int pos = atomicAdd(&cur2[dst2[e]], 1); out2[pos] = src2[e]; }
    }
}

// ---------------- fused GCN layer 1 (scaled input): pull + gemm(DIN->64) + relu ----------------
template <int DIN>
__global__ __launch_bounds__(256) void k_gcn_s(const int* __restrict__ rs, const int* __restrict__ deg,
                                               const int* __restrict__ srcs, const float* __restrict__ dinv,
                                               const float* __restrict__ Hs, const float* __restrict__ W,
                                               const float* __restrict__ b, float* __restrict__ Out, int n)
{
    const int w = threadIdx.x >> 6, lane = threadIdx.x & 63;
    const int row = blockIdx.x * 4 + w;
    __shared__ float ag[4][DIN];
    const float di = dinv[row];
    const int e0 = rs[row];
    const int d = deg[row];
    float acc = (lane < DIN) ? Hs[(size_t)row * DIN + lane] : 0.f;
    int e = 0;
    for (; e + 8 <= d; e += 8) {
        int s0 = srcs[e0 + e + 0], s1 = srcs[e0 + e + 1], s2 = srcs[e0 + e + 2], s3 = srcs[e0 + e + 3];
        int s4 = srcs[e0 + e + 4], s5 = srcs[e0 + e + 5], s6 = srcs[e0 + e + 6], s7 = srcs[e0 + e + 7];
        float h0 = 0.f, h1 = 0.f, h2 = 0.f, h3 = 0.f, h4 = 0.f, h5 = 0.f, h6 = 0.f, h7 = 0.f;
        if (lane < DIN) {
            h0 = Hs[(size_t)s0 * DIN + lane]; h1 = Hs[(size_t)s1 * DIN + lane];
            h2 = Hs[(size_t)s2 * DIN + lane]; h3 = Hs[(size_t)s3 * DIN + lane];
            h4 = Hs[(size_t)s4 * DIN + lane]; h5 = Hs[(size_t)s5 * DIN + lane];
            h6 = Hs[(size_t)s6 * DIN + lane]; h7 = Hs[(size_t)s7 * DIN + lane];
        }
        acc += ((h0 + h1) + (h2 + h3)) + ((h4 + h5) + (h6 + h7));
    }
    for (; e + 4 <= d; e += 4) {
        int s0 = srcs[e0 + e + 0], s1 = srcs[e0 + e + 1], s2 = srcs[e0 + e + 2], s3 = srcs[e0 + e + 3];
        float h0 = 0.f, h1 = 0.f, h2 = 0.f, h3 = 0.f;
        if (lane < DIN) {
            h0 = Hs[(size_t)s0 * DIN + lane]; h1 = Hs[(size_t)s1 * DIN + lane];
            h2 = Hs[(size_t)s2 * DIN + lane]; h3 = Hs[(size_t)s3 * DIN + lane];
        }
        acc += (h0 + h1) + (h2 + h3);
    }
    for (; e < d; ++e) {
        int s = srcs[e0 + e];
        if (lane < DIN) acc += Hs[(size_t)s * DIN + lane];
    }
    if (lane < DIN) ag[w][lane] = acc;
    __syncthreads();
    float o = 0.f;
#pragma unroll
    for (int i = 0; i < DIN; ++i) o = fmaf(ag[w][i], W[i * 64 + lane], o);
    Out[(size_t)row * 64 + lane] = fmaxf(fmaf(di, o, b[lane]), 0.f);
}

// ---------------- fused pull+combine (scaled input): dest = di*(Hs[row] + sum Hs[s]) + b
template <int D>
__global__ __launch_bounds__(256) void k_pcomb_s(const int* __restrict__ rs, const int* __restrict__ deg,
                                                 const int* __restrict__ srcs, const float* __restrict__ dinv,
                                                 const float* __restrict__ Hs, const float* __restrict__ b,
                                                 float* __restrict__ dest, int n)
{
    const int wid = (blockIdx.x * blockDim.x + threadIdx.x) >> 6;
    const int lane = threadIdx.x & 63;
    if (wid >= n) return;
    const float di = dinv[wid];
    const int e0 = rs[wid];
    const int d = deg[wid];
    float acc = (lane < D) ? Hs[(size_t)wid * D + lane] : 0.f;
    int e = 0;
    for (; e + 8 <= d; e += 8) {
        int s0 = srcs[e0 + e + 0], s1 = srcs[e0 + e + 1], s2 = srcs[e0 + e + 2], s3 = srcs[e0 + e + 3];
        int s4 = srcs[e0 + e + 4], s5 = srcs[e0 + e + 5], s6 = srcs[e0 + e + 6], s7 = srcs[e0 + e + 7];
        float h0 = 0.f, h1 = 0.f, h2 = 0.f, h3 = 0.f, h4 = 0.f, h5 = 0.f, h6 = 0.f, h7 = 0.f;
        if (lane < D) {
            h0 = Hs[(size_t)s0 * D + lane]; h1 = Hs[(size_t)s1 * D + lane];
            h2 = Hs[(size_t)s2 * D + lane]; h3 = Hs[(size_t)s3 * D + lane];
            h4 = Hs[(size_t)s4 * D + lane]; h5 = Hs[(size_t)s5 * D + lane];
            h6 = Hs[(size_t)s6 * D + lane]; h7 = Hs[(size_t)s7 * D + lane];
        }
        acc += ((h0 + h1) + (h2 + h3)) + ((h4 + h5) + (h6 + h7));
    }
    for (; e + 4 <= d; e += 4) {
        int s0 = srcs[e0 + e + 0], s1 = srcs[e0 + e + 1], s2 = srcs[e0 + e + 2], s3 = srcs[e0 + e + 3];
        float h0 = 0.f, h1 = 0.f, h2 = 0.f, h3 = 0.f;
        if (lane < D) {
            h0 = Hs[(size_t)s0 * D + lane]; h1 = Hs[(size_t)s1 * D + lane];
            h2 = Hs[(size_t)s2 * D + lane]; h3 = Hs[(size_t)s3 * D + lane];
        }
        acc += (h0 + h1) + (h2 + h3);
    }
    for (; e < d; ++e) {
        int s = srcs[e0 + e];
        if (lane < D) acc += Hs[(size_t)s * D + lane];
    }
    if (lane < D) dest[(size_t)wid * D + lane] = fmaf(di, acc, b[lane]);
}

// D=1 scaled pull+combine: thread per row
__global__ void k_pcomb1_s(const int* __restrict__ rs, const int* __restrict__ deg,
                           const int* __restrict__ srcs, const float* __restrict__ dinv,
                           const float* __restrict__ Hs, const float* __restrict__ b,
                           float* __restrict__ dest, int n)
{
    int r = blockIdx.x * blockDim.x + threadIdx.x;
    if (r >= n) return;
    int e0 = rs[r], d = deg[r];
    float acc = Hs[r];
    int e = 0;
    for (; e + 8 <= d; e += 8) {
        acc += ((Hs[srcs[e0 + e + 0]] + Hs[srcs[e0 + e + 1]]) + (Hs[srcs[e0 + e + 2]] + Hs[srcs[e0 + e + 3]]))
             + ((Hs[srcs[e0 + e + 4]] + Hs[srcs[e0 + e + 5]]) + (Hs[srcs[e0 + e + 6]] + Hs[srcs[e0 + e + 7]]));
    }
    for (; e + 4 <= d; e += 4) {
        acc += (Hs[srcs[e0 + e + 0]] + Hs[srcs[e0 + e + 1]]) + (Hs[srcs[e0 + e + 2]] + Hs[srcs[e0 + e + 3]]);
    }
    for (; e < d; ++e) acc += Hs[srcs[e0 + e]];
    dest[r] = fmaf(dinv[r], acc, b[0]);
}

// ---------------- merged pre MLP for both node sets ----------------
// 35 -> 128 -> 128 -> 34 (+passthrough). Writes X (raw) and Xs (dinv-scaled).
// k-loops unrolled x8 so (k&7) swizzle is compile-time; writes rotated (c=(ct+j)&3)
// to spread bank groups across lanes.
#define PR 32
__global__ __launch_bounds__(256) void k_pre_all(const int* __restrict__ cat1, const float* __restrict__ num1,
                                                 const int* __restrict__ cat2, const float* __restrict__ num2,
                                                 const float* __restrict__ emb0, const float* __restrict__ emb1,
                                                 const float* __restrict__ emb2,
                                                 const float* __restrict__ W1, const float* __restrict__ b1,
                                                 const float* __restrict__ W2, const float* __restrict__ b2,
                                                 const float* __restrict__ W3, const float* __restrict__ b3,
                                                 const float* __restrict__ dinv1, const float* __restrict__ dinv2,
                                                 float* __restrict__ X1, float* __restrict__ Xs1,
                                                 float* __restrict__ X2, float* __restrict__ Xs2,
                                                 int nblk1)
{
    __shared__ float oT[35 * PR];
    __shared__ float h1T[128 * PR];
    __shared__ float h2T[128 * PR];
    const int t = threadIdx.x;
    const int ct = t & 31;
    const int rg = t >> 5;  // 0..7
    const int gb = blockIdx.x;
    const int g2 = (gb >= nblk1);
    const int* cat = g2 ? cat2 : cat1;
    const float* num = g2 ? num2 : num1;
    const float* dinv = g2 ? dinv2 : dinv1;
    float* X = g2 ? X2 : X1;
    float* Xs = g2 ? Xs2 : Xs1;
    const int base = (g2 ? gb - nblk1 : gb) * PR;

    for (int idx = t; idx < 35 * PR; idx += 256) {
        int i = idx >> 5, r = idx & 31;
        int row = base + r;
        float v;
        if (i < 16) v = emb0[cat[row * 3 + 0] * 16 + i];
        else if (i < 24) v = emb1[cat[row * 3 + 1] * 8 + (i - 16)];
        else if (i < 32) v = emb2[cat[row * 3 + 2] * 8 + (i - 24)];
        else v = num[row * 3 + (i - 32)];
        oT[i * PR + (((r >> 2) ^ (i & 7)) << 2) + (r & 3)] = v;
    }
    __syncthreads();

    float acc[4][4];
    // layer 1: 35 -> 128
    {
        float4 bb = *(const float4*)(b1 + 4 * ct);
        const float bbv[4] = {bb.x, bb.y, bb.z, bb.w};
#pragma unroll
        for (int c = 0; c < 4; ++c)
#pragma unroll
            for (int r = 0; r < 4; ++r) acc[c][r] = bbv[c];
#pragma unroll
        for (int kk = 0; kk < 32; kk += 8) {
#pragma unroll
            for (int u = 0; u < 8; ++u) {
                const int i = kk + u;
                float4 ov = *(const float4*)(oT + i * PR + ((rg ^ u) << 2));
                float4 wv = *(const float4*)(W1 + i * 128 + 4 * ct);
                const float o4[4] = {ov.x, ov.y, ov.z, ov.w};
                const float w4[4] = {wv.x, wv.y, wv.z, wv.w};
#pragma unroll
                for (int c = 0; c < 4; ++c)
#pragma unroll
                    for (int r = 0; r < 4; ++r) acc[c][r] = fmaf(w4[c], o4[r], acc[c][r]);
            }
        }
#pragma unroll
        for (int u = 0; u < 3; ++u) {
            const int i = 32 + u;
            float4 ov = *(const float4*)(oT + i * PR + ((rg ^ u) << 2));
            float4 wv = *(const float4*)(W1 + i * 128 + 4 * ct);
            const float o4[4] = {ov.x, ov.y, ov.z, ov.w};
            const float w4[4] = {wv.x, wv.y, wv.z, wv.w};
#pragma unroll
            for (int c = 0; c < 4; ++c)
#pragma unroll
                for (int r = 0; r < 4; ++r) acc[c][r] = fmaf(w4[c], o4[r], acc[c][r]);
        }
#pragma unroll
        for (int j = 0; j < 4; ++j) {
            int c = (ct + j) & 3;  // rotate write order to spread bank groups
            int col = 4 * ct + c;
            float4 v;
            v.x = fmaxf(acc[c][0], 0.f);
            v.y = fmaxf(acc[c][1], 0.f);
            v.z = fmaxf(acc[c][2], 0.f);
            v.w = fmaxf(acc[c][3], 0.f);
            *(float4*)(h1T + col * PR + ((rg ^ (col & 7)) << 2)) = v;
        }
    }
    __syncthreads();
    // layer 2: 128 -> 128
    {
        float4 bb = *(const float4*)(b2 + 4 * ct);
        const float bbv[4] = {bb.x, bb.y, bb.z, bb.w};
#pragma unroll
        for (int c = 0; c < 4; ++c)
#pragma unroll
            for (int r = 0; r < 4; ++r) acc[c][r] = bbv[c];
        for (int kk = 0; kk < 128; kk += 8) {
#pragma unroll
            for (int u = 0; u < 8; ++u) {
                const int k = kk + u;
                float4 hv = *(const float4*)(h1T + k * PR + ((rg ^ u) << 2));
                float4 wv = *(const float4*)(W2 + k * 128 + 4 * ct);
                const float h4[4] = {hv.x, hv.y, hv.z, hv.w};
                const float w4[4] = {wv.x, wv.y, wv.z, wv.w};
#pragma unroll
                for (int c = 0; c < 4; ++c)
#pragma unroll
                    for (int r = 0; r < 4; ++r) acc[c][r] = fmaf(w4[c], h4[r], acc[c][r]);
            }
        }
#pragma unroll
        for (int j = 0; j < 4; ++j) {
            int c = (ct + j) & 3;
            int col = 4 * ct + c;
            float4 v;
            v.x = fmaxf(acc[c][0], 0.f);
            v.y = fmaxf(acc[c][1], 0.f);
            v.z = fmaxf(acc[c][2], 0.f);
            v.w = fmaxf(acc[c][3], 0.f);
            *(float4*)(h2T + col * PR + ((rg ^ (col & 7)) << 2)) = v;
        }
    }
    __syncthreads();
    // layer 3: 128 -> 34, tasks = (j, row-group): 34*8 = 272
    for (int task = t; task < 34 * 8; task += 256) {
        int j = task >> 3, rg3 = task & 7;
        float a0 = b3[j], a1 = a0, a2 = a0, a3 = a0;
        for (int kk = 0; kk < 128; kk += 8) {
#pragma unroll
            for (int u = 0; u < 8; ++u) {
                const int k = kk + u;
                float4 hv = *(const float4*)(h2T + k * PR + ((rg3 ^ u) << 2));
                float wv = W3[k * 34 + j];
                a0 = fmaf(hv.x, wv, a0);
                a1 = fmaf(hv.y, wv, a1);
                a2 = fmaf(hv.z, wv, a2);
                a3 = fmaf(hv.w, wv, a3);
            }
        }
        size_t rb = (size_t)(base + rg3 * 4);
        float d0 = dinv[rb + 0], d1 = dinv[rb + 1], d2 = dinv[rb + 2], d3 = dinv[rb + 3];
        X[(rb + 0) * 35 + j] = a0;  Xs[(rb + 0) * 35 + j] = a0 * d0;
        X[(rb + 1) * 35 + j] = a1;  Xs[(rb + 1) * 35 + j] = a1 * d1;
        X[(rb + 2) * 35 + j] = a2;  Xs[(rb + 2) * 35 + j] = a2 * d2;
        X[(rb + 3) * 35 + j] = a3;  Xs[(rb + 3) * 35 + j] = a3 * d3;
    }
    if (t < PR) {
        int row = base + t;
        float v = num[row * 3 + 2];
        X[(size_t)row * 35 + 34] = v;
        Xs[(size_t)row * 35 + 34] = v * dinv[row];
    }
}

// ---------------- plain dense gemm (row-major W: DIN x DOUT), float4 row loads ----------------
template <int DIN, int DOUT, bool BIAS, bool RELU, bool SCALE>
__global__ void k_gemm(const float* __restrict__ Xin, int ldin, const float* __restrict__ W,
                       const float* __restrict__ b, const float* __restrict__ oscale,
                       float* __restrict__ Out, int n)
{
    __shared__ float Ws[DIN * DOUT];
    for (int i = threadIdx.x; i < DIN * DOUT; i += blockDim.x) Ws[i] = W[i];
    __syncthreads();
    int idx = blockIdx.x * blockDim.x + threadIdx.x;
    if (idx >= n * DOUT) return;
    int row = idx / DOUT, j = idx - row * DOUT;
    const float4* xr4 = (const float4*)(Xin + (size_t)row * ldin);
    float acc = BIAS ? b[j] : 0.f;
#pragma unroll
    for (int i4 = 0; i4 < DIN / 4; ++i4) {
        float4 x = xr4[i4];
        acc = fmaf(x.x, Ws[(4 * i4 + 0) * DOUT + j], acc);
        acc = fmaf(x.y, Ws[(4 * i4 + 1) * DOUT + j], acc);
        acc = fmaf(x.z, Ws[(4 * i4 + 2) * DOUT + j], acc);
        acc = fmaf(x.w, Ws[(4 * i4 + 3) * DOUT + j], acc);
    }
    if (RELU) acc = fmaxf(acc, 0.f);
    if (SCALE) acc *= oscale[row];
    Out[idx] = acc;
}

// ---------------- alpha / yh: per-batch kernel regression ----------------
__global__ __launch_bounds__(256) void k_alpha(const float* __restrict__ X1,  // n1 x 34 (g1 out)
                                               const float* __restrict__ X,   // n1 x 35 (y col)
                                               float* __restrict__ X2,        // n2 x 35
                                               float* __restrict__ Xs2,       // n2 x 35 scaled
                                               const float* __restrict__ dinv2,
                                               const float* __restrict__ theta,
                                               const float* __restrict__ A,
                                               const float* __restrict__ scale)
{
    const int b = blockIdx.x;
    const int t = threadIdx.x;
    const int p = t & 63;
    const int w = t >> 6;
    __shared__ float th[34 * 34];
    __shared__ float xpS[64 * 35];
    __shared__ float xfS[16 * 34];
    __shared__ float UfS[16 * 34];
    __shared__ float upPart[4][64];
    __shared__ float upS[64];
    __shared__ float yS[64];

    for (int i = t; i < 34 * 34; i += 256) th[i] = theta[i];
    for (int i = t; i < 64 * 34; i += 256) {
        int r = i / 34, o = i - 34 * r;
        xpS[r * 35 + o] = X1[(size_t)(b * 64 + r) * 34 + o];
    }
    for (int i = t; i < 16 * 34; i += 256) {
        int q = i / 34, o = i - 34 * q;
        xfS[i] = X2[(size_t)(b * 16 + q) * 35 + o];
    }
    if (t < 64) yS[t] = X[(size_t)(b * 64 + t) * 35 + 34];
    __syncthreads();

    for (int i = t; i < 16 * 34; i += 256) {
        int q = i / 34, o = i - 34 * q;
        float a = 0.f;
#pragma unroll
        for (int O = 0; O < 34; ++O) a = fmaf(th[o * 34 + O], xfS[q * 34 + O], a);
        UfS[i] = a;
    }
    {
        const int o0 = w * 9;
        const int o1 = (o0 + 9 < 34) ? o0 + 9 : 34;
        float a = 0.f;
        for (int o = o0; o < o1; ++o) {
            float s2 = 0.f;
#pragma unroll
            for (int O = 0; O < 34; ++O) s2 = fmaf(th[o * 34 + O], xpS[p * 35 + O], s2);
            a = fmaf(xpS[p * 35 + o], s2, a);
        }
        upPart[w][p] = a;
    }
    __syncthreads();
    if (t < 64) upS[t] = upPart[0][t] + upPart[1][t] + upPart[2][t] + upPart[3][t];
    __syncthreads();

    const float sc = scale[0];
    const float up = upS[p];
    const float y = yS[p];
#pragma unroll
    for (int i = 0; i < 4; ++i) {
        const int q = w + 4 * i;
        float g = 0.f;
#pragma unroll
        for (int o = 0; o < 34; ++o) g = fmaf(UfS[q * 34 + o], xpS[p * 35 + o], g);
        float a = sc * (up - 2.f * g);
        if (A[(PASTN + q) * NN + p] == 0.f) a = -INFINITY;
        float mx = a;
#pragma unroll
        for (int off = 32; off > 0; off >>= 1) mx = fmaxf(mx, __shfl_xor(mx, off));
        float e = expf(a - mx);
        float s = e;
#pragma unroll
        for (int off = 32; off > 0; off >>= 1) s += __shfl_xor(s, off);
        float c = (e / s) * y;
#pragma unroll
        for (int off = 32; off > 0; off >>= 1) c += __shfl_xor(c, off);
        if (p == 0) {
            size_t ridx = (size_t)(b * 16 + q);
            X2[ridx * 35 + 34] = c;
            Xs2[ridx * 35 + 34] = c * dinv2[ridx];
        }
    }
}

// ---------------- pairwise distances: 5x5 register tiles, pitch 44 ----------------
__global__ __launch_bounds__(256) void k_cd(const float* __restrict__ X, const float* __restrict__ X2,
                                            float* __restrict__ cd)
{
    const int b = blockIdx.x;
    const int t = threadIdx.x;
    __shared__ float xa[80 * 44];
    __shared__ float sq[80];
    for (int idx = t; idx < 80 * 44; idx += 256) {
        int nrow = idx / 44, k = idx - 44 * nrow;
        float v = 0.f;
        if (k < 35)
            v = (nrow < 64) ? X[(size_t)(b * 64 + nrow) * 35 + k]
                            : X2[(size_t)(b * 16 + (nrow - 64)) * 35 + k];
        xa[idx] = v;
    }
    __syncthreads();
    const float4* xa4 = (const float4*)xa;
    if (t < 80) {
        float acc = 0.f;
#pragma unroll
        for (int c = 0; c < 9; ++c) {
            float4 v = xa4[t * 11 + c];
            acc = fmaf(v.x, v.x, fmaf(v.y, v.y, fmaf(v.z, v.z, fmaf(v.w, v.w, acc))));
        }
        sq[t] = acc;
    }
    __syncthreads();
    const int ti = t >> 4;   // 0..15 -> rows 5ti..5ti+4
    const int tj = t & 15;   // 0..15 -> cols 5tj..5tj+4
    float dot[5][5];
#pragma unroll
    for (int r = 0; r < 5; ++r)
#pragma unroll
        for (int c = 0; c < 5; ++c) dot[r][c] = 0.f;
#pragma unroll
    for (int ch = 0; ch < 9; ++ch) {
        float4 av[5], bv[5];
#pragma unroll
        for (int r = 0; r < 5; ++r) av[r] = xa4[(5 * ti + r) * 11 + ch];
#pragma unroll
        for (int c = 0; c < 5; ++c) bv[c] = xa4[(5 * tj + c) * 11 + ch];
#pragma unroll
        for (int r = 0; r < 5; ++r)
#pragma unroll
            for (int c = 0; c < 5; ++c)
                dot[r][c] = fmaf(av[r].x, bv[c].x, fmaf(av[r].y, bv[c].y,
                              fmaf(av[r].z, bv[c].z, fmaf(av[r].w, bv[c].w, dot[r][c]))));
    }
    float* out = cd + (size_t)b * 6400;
#pragma unroll
    for (int r = 0; r < 5; ++r) {
        int n_ = 5 * ti + r;
        float sn = sq[n_];
#pragma unroll
        for (int c = 0; c < 5; ++c) {
            int m = 5 * tj + c;
            float d2 = sn + sq[m] - 2.f * dot[r][c];
            out[n_ * 80 + m] = sqrtf(fmaxf(d2, 0.f));
        }
    }
}

extern "C" void kernel_launch(void* const* d_in, const int* in_sizes, int n_in,
                              void* d_out, int out_size, void* d_ws, size_t ws_size,
                              hipStream_t stream)
{
    const int* x1_cat = (const int*)d_in[0];
    const float* x1_num = (const float*)d_in[1];
    const int* x2_cat = (const int*)d_in[2];
    const float* x2_num = (const float*)d_in[3];
    const int* e1 = (const int*)d_in[4];
    const int* e2 = (const int*)d_in[5];
    const float* emb0 = (const float*)d_in[6];
    const float* emb1 = (const float*)d_in[7];
    const float* emb2 = (const float*)d_in[8];
    const float* pW1 = (const float*)d_in[9];
    const float* pb1 = (const float*)d_in[10];
    const float* pW2 = (const float*)d_in[11];
    const float* pb2 = (const float*)d_in[12];
    const float* pW3 = (const float*)d_in[13];
    const float* pb3 = (const float*)d_in[14];
    const float* g1W1 = (const float*)d_in[15];
    const float* g1b1 = (const float*)d_in[16];
    const float* g1W2 = (const float*)d_in[17];
    const float* g1b2 = (const float*)d_in[18];
    const float* g2W1 = (const float*)d_in[19];
    const float* g2b1 = (const float*)d_in[20];
    const float* g2W2 = (const float*)d_in[21];
    const float* g2b2 = (const float*)d_in[22];
    const float* kerW = (const float*)d_in[23];
    const float* smoothing = (const float*)d_in[24];
    const float* M = (const float*)d_in[25];

    const int n1 = in_sizes[0] / 3;
    const int n2 = in_sizes[2] / 3;
    const int E1 = in_sizes[4] / 2;
    const int E2 = in_sizes[5] / 2;
    const int SBc = n2 / FUTN;

    float* w = (float*)d_ws;
    size_t off = 0;
    float* scale = w + off; off += 16;
    float* theta = w + off; off += 1184;
    float* Aws = w + off; off += 6400;
    float* X = w + off; off += (size_t)n1 * 35;
    float* Xs1 = w + off; off += (size_t)n1 * 35;
    float* X2 = w + off; off += (size_t)n2 * 35;
    float* Xs2 = w + off; off += (size_t)n2 * 35;
    float* dinv1 = w + off; off += (size_t)n1;
    float* dinv2 = w + off; off += (size_t)n2;
    float* B2 = w + off; off += (size_t)n1 * 64;
    float* B3 = w + off; off += (size_t)n1 * 34;
    float* B4 = w + off; off += (size_t)n1 * 34;
    int* iw = (int*)(w + off);
    size_t ioff = 0;
    int* degi1 = iw + ioff; ioff += n1;   // degi1/degi2 adjacent: single memset
    int* degi2 = iw + ioff; ioff += n2;
    int* rs1 = iw + ioff; ioff += n1;
    int* cur1 = iw + ioff; ioff += n1;
    int* srcs1 = iw + ioff; ioff += E1;
    int* rs2 = iw + ioff; ioff += n2;
    int* cur2 = iw + ioff; ioff += n2;
    int* srcs2 = iw + ioff; ioff += E2;
    int* bsumA = iw + ioff; ioff += 1024;
    int* bsumB = iw + ioff; ioff += 1024;

    float* out_f = (float*)d_out;
    float* cd_f = out_f + (size_t)SBc * FUTN;
    float* A_out = cd_f + (size_t)SBc * NN * NN;

    auto cdiv = [](long long a, long long b) { return (unsigned)((a + b - 1) / b); };

    // ---- degrees + CSR build (merged kernels) ----
    hipMemsetAsync(degi1, 0, ((size_t)n1 + n2) * 4, stream);
    k_setup<<<1, 256, 0, stream>>>(M, kerW, smoothing, Aws, A_out, theta, scale);

    const int nbe1 = cdiv(E1, 256), nbe2 = cdiv(E2, 256);
    k_deg2<<<nbe1 + nbe2, 256, 0, stream>>>(e1 + E1, e2 + E2, degi1, degi2, E1, E2, nbe1);

    const int nb1 = cdiv(n1, SCHUNK), nb2 = cdiv(n2, SCHUNK);
    k_scan_reduce2<<<nb1 + nb2, 256, 0, stream>>>(degi1, degi2, bsumA, bsumB, n1, n2, nb1);
    k_scan_mid2<<<2, 1024, 0, stream>>>(bsumA, bsumB, nb1, nb2);
    k_scan_final2<<<nb1 + nb2, 256, 0, stream>>>(degi1, degi2, bsumA, bsumB, rs1, rs2, cur1, cur2,
                                                 dinv1, dinv2, n1, n2, nb1);
    k_fill2<<<nbe1 + nbe2, 256, 0, stream>>>(e1, e1 + E1, e2, e2 + E2, cur1, cur2, srcs1, srcs2, E1, E2, nbe1);

    // ---- pre MLP, both node sets in one dispatch ----
    k_pre_all<<<n1 / PR + n2 / PR, 256, 0, stream>>>(x1_cat, x1_num, x2_cat, x2_num,
                                                     emb0, emb1, emb2, pW1, pb1, pW2, pb2, pW3, pb3,
                                                     dinv1, dinv2, X, Xs1, X2, Xs2, n1 / PR);

    // ---- g1 layer 1: fused pull(35, scaled)+gemm(35->64)+relu ----
    k_gcn_s<35><<<cdiv(n1, 4), 256, 0, stream>>>(rs1, degi1, srcs1, dinv1, Xs1, g1W1, g1b1, B2, n1);

    // ---- g1 layer 2: gemm 64->34 (output pre-scaled by dinv1) then fused pull+combine ----
    k_gemm<64, 34, false, false, true><<<cdiv((long long)n1 * 34, 256), 256, 0, stream>>>(B2, 64, g1W2, nullptr, dinv1, B3, n1);
    k_pcomb_s<34><<<cdiv(n1, 4), 256, 0, stream>>>(rs1, degi1, srcs1, dinv1, B3, g1b2, B4, n1);

    // ---- alpha / yh -> X2 col 34 (+ scaled copy) ----
    k_alpha<<<SBc, 256, 0, stream>>>(B4, X, X2, Xs2, dinv2, theta, Aws, scale);

    // ---- g2 layer 1 ----
    k_gcn_s<35><<<cdiv(n2, 4), 256, 0, stream>>>(rs2, degi2, srcs2, dinv2, Xs2, g2W1, g2b1, B2, n2);

    // ---- g2 layer 2: gemm 64->1 (pre-scaled), fused pull+combine ----
    k_gemm<64, 1, false, false, true><<<cdiv(n2, 256), 256, 0, stream>>>(B2, 64, g2W2, nullptr, dinv2, B3, n2);
    k_pcomb1_s<<<cdiv(n2, 256), 256, 0, stream>>>(rs2, degi2, srcs2, dinv2, B3, g2b2, out_f, n2);

    // ---- pairwise distances ----
    k_cd<<<SBc, 256, 0, stream>>>(X, X2, cd_f);
}

// Round 8
// 709.975 us; speedup vs baseline: 2.0753x; 1.1007x over previous
//
#include <hip/hip_runtime.h>
#include <math.h>

#define PASTN 64
#define FUTN 16
#define NN 80

typedef __attribute__((ext_vector_type(8))) short sh8;
typedef __attribute__((ext_vector_type(4))) float f32x4;

__device__ __forceinline__ unsigned short f2bf(float f) {
    unsigned int u = __float_as_uint(f);
    return (unsigned short)((u + 0x7FFFu + ((u >> 16) & 1u)) >> 16);
}
__device__ __forceinline__ float bf2f(unsigned short s) {
    return __uint_as_float(((unsigned int)s) << 16);
}

// ---------------- setup: A (causal softmax of relu(M M^T)), theta, scale ----------------
__global__ __launch_bounds__(256) void k_setup(const float* __restrict__ M, const float* __restrict__ kerW,
                                               const float* __restrict__ smoothing,
                                               float* __restrict__ A_ws, float* __restrict__ A_out,
                                               float* __restrict__ theta, float* __restrict__ scale)
{
    __shared__ float Ms[80 * 26];
    __shared__ float Ar[80 * 80];
    const int t = threadIdx.x;
    for (int i = t; i < 80 * 26; i += 256) Ms[i] = M[i];
    __syncthreads();
    for (int idx = t; idx < 6400; idx += 256) {
        int i = idx / 80, j = idx - 80 * i;
        float acc = 0.f;
#pragma unroll
        for (int k = 0; k < 26; ++k) acc = fmaf(Ms[i * 26 + k], Ms[j * 26 + k], acc);
        Ar[idx] = fmaxf(acc, 0.f);
    }
    __syncthreads();
    if (t < 80) {
        float mx = -1e30f;
        for (int j = 0; j <= t; ++j) mx = fmaxf(mx, Ar[t * 80 + j]);
        float s = 0.f;
        for (int j = 0; j <= t; ++j) s += expf(Ar[t * 80 + j] - mx);
        float inv = 1.f / s;
        for (int j = 0; j < 80; ++j) {
            float v = (j <= t) ? expf(Ar[t * 80 + j] - mx) * inv : 0.f;
            A_ws[t * 80 + j] = v;
            A_out[t * 80 + j] = v;
        }
    }
    for (int idx = t; idx < 34 * 34; idx += 256) {
        int i = idx / 34, j = idx - 34 * i;
        float acc = 0.f;
        for (int k = 0; k < 128; ++k) acc = fmaf(kerW[i * 128 + k], kerW[j * 128 + k], acc);
        theta[idx] = acc;
    }
    if (t == 0) {
        float s0 = smoothing[0];
        float sig = 1.f / (1.f + expf(-s0));
        scale[0] = -0.5f / (sig * 0.01f);
    }
}

// ---------------- W2 -> fragment-ordered bf16 hi/lo (once per launch) ----------------
// fragment id g = ((nt*4+ks)*64+lane)*8+i ; col = nt*16+(lane&15); k = ks*32+(lane>>4)*8+i
__global__ void k_wconv(const float* __restrict__ W2, unsigned short* __restrict__ Wh,
                        unsigned short* __restrict__ Wl)
{
    int g = blockIdx.x * 256 + threadIdx.x;  // 0..16383
    int i = g & 7, ln = (g >> 3) & 63, ks = (g >> 9) & 3, nt = g >> 11;
    int col = nt * 16 + (ln & 15);
    int k = ks * 32 + ((ln >> 4) << 3) + i;
    float w = W2[k * 128 + col];
    unsigned short hi = f2bf(w);
    Wh[g] = hi;
    Wl[g] = f2bf(w - bf2f(hi));
}

// ---------------- merged degree count (both graphs) ----------------
__global__ void k_deg2(const int* __restrict__ dst1, const int* __restrict__ dst2,
                       int* __restrict__ deg1, int* __restrict__ deg2,
                       int E1, int E2, int nbe1)
{
    int gb = blockIdx.x;
    if (gb < nbe1) {
        int e = gb * 256 + threadIdx.x;
        if (e < E1) atomicAdd(&deg1[dst1[e]], 1);
    } else {
        int e = (gb - nbe1) * 256 + threadIdx.x;
        if (e < E2) atomicAdd(&deg2[dst2[e]], 1);
    }
}

// ---------------- merged exclusive scan, chunk = 1024 ----------------
#define SCHUNK 1024
__global__ __launch_bounds__(256) void k_scan_reduce2(const int* __restrict__ deg1, const int* __restrict__ deg2,
                                                      int* __restrict__ bsumA, int* __restrict__ bsumB,
                                                      int n1, int n2, int nb1)
{
    __shared__ int sd[256];
    const int gb = blockIdx.x, t = threadIdx.x;
    const int which = (gb < nb1) ? 0 : 1;
    const int b = which ? gb - nb1 : gb;
    const int* deg = which ? deg2 : deg1;
    const int n = which ? n2 : n1;
    const int base = b * SCHUNK;
    int s = 0;
#pragma unroll
    for (int j = 0; j < 4; ++j) {
        int i = base + t + j * 256;
        if (i < n) s += deg[i];
    }
    sd[t] = s;
    __syncthreads();
    for (int o = 128; o > 0; o >>= 1) {
        if (t < o) sd[t] += sd[t + o];
        __syncthreads();
    }
    if (t == 0) (which ? bsumB : bsumA)[b] = sd[0];
}

__global__ __launch_bounds__(1024) void k_scan_mid2(int* __restrict__ bsumA, int* __restrict__ bsumB,
                                                    int nbA, int nbB)
{
    __shared__ int sd[1024];
    const int t = threadIdx.x;
    int* bsum = (blockIdx.x == 0) ? bsumA : bsumB;
    int nb = (blockIdx.x == 0) ? nbA : nbB;
    int orig = (t < nb) ? bsum[t] : 0;
    sd[t] = orig;
    __syncthreads();
    for (int o = 1; o < 1024; o <<= 1) {
        int v = (t >= o) ? sd[t - o] : 0;
        __syncthreads();
        sd[t] += v;
        __syncthreads();
    }
    if (t < nb) bsum[t] = sd[t] - orig;  // exclusive
}

// final scan; also writes cur (copy of rs) and dinv = rsqrt(1+deg)
__global__ __launch_bounds__(256) void k_scan_final2(const int* __restrict__ deg1, const int* __restrict__ deg2,
                                                     const int* __restrict__ bsumA, const int* __restrict__ bsumB,
                                                     int* __restrict__ rs1, int* __restrict__ rs2,
                                                     int* __restrict__ cur1, int* __restrict__ cur2,
                                                     float* __restrict__ dinv1, float* __restrict__ dinv2,
                                                     int n1, int n2, int nb1)
{
    __shared__ int sd[256];
    const int gb = blockIdx.x, t = threadIdx.x;
    const int which = (gb < nb1) ? 0 : 1;
    const int b = which ? gb - nb1 : gb;
    const int* deg = which ? deg2 : deg1;
    const int* bsum = which ? bsumB : bsumA;
    int* rs = which ? rs2 : rs1;
    int* cur = which ? cur2 : cur1;
    float* dinv = which ? dinv2 : dinv1;
    const int n = which ? n2 : n1;
    const int base = b * SCHUNK + t * 4;
    int v0 = (base + 0 < n) ? deg[base + 0] : 0;
    int v1 = (base + 1 < n) ? deg[base + 1] : 0;
    int v2 = (base + 2 < n) ? deg[base + 2] : 0;
    int v3 = (base + 3 < n) ? deg[base + 3] : 0;
    int tsum = v0 + v1 + v2 + v3;
    sd[t] = tsum;
    __syncthreads();
    int incl = tsum;
    for (int o = 1; o < 256; o <<= 1) {
        int v = (t >= o) ? sd[t - o] : 0;
        __syncthreads();
        incl += v;
        sd[t] = incl;
        __syncthreads();
    }
    int off = bsum[b] + incl - tsum;
    if (base + 0 < n) { rs[base + 0] = off;            cur[base + 0] = off;            dinv[base + 0] = rsqrtf(1.f + (float)v0); }
    if (base + 1 < n) { rs[base + 1] = off + v0;       cur[base + 1] = off + v0;       dinv[base + 1] = rsqrtf(1.f + (float)v1); }
    if (base + 2 < n) { rs[base + 2] = off + v0 + v1;  cur[base + 2] = off + v0 + v1;  dinv[base + 2] = rsqrtf(1.f + (float)v2); }
    if (base + 3 < n) { rs[base + 3] = off + v0 + v1 + v2; cur[base + 3] = off + v0 + v1 + v2; dinv[base + 3] = rsqrtf(1.f + (float)v3); }
}

// ---------------- merged CSR fill ----------------
__global__ void k_fill2(const int* __restrict__ src1, const int* __restrict__ dst1,
                        const int* __restrict__ src2, const int* __restrict__ dst2,
                        int* __restrict__ cur1, int* __restrict__ cur2,
                        int* __restrict__ out1, int* __restrict__ out2,
                        int E1, int E2, int nbe1)
{
    int gb = blockIdx.x;
    if (gb < nbe1) {
        int e = gb * 256 + threadIdx.x;
        if (e < E1) { int pos = atomicAdd(&cur1[dst1[e]], 1); out1[pos] = src1[e]; }
    } else {
        int e = (gb - nbe1) * 256 + threadIdx.x;
        if (e < E2) { int pos = atomicAdd(&cur2[dst2[e]], 1); out2[pos] = src2[e]; }
    }
}

// ---------------- fused GCN layer 1 (scaled input): pull + gemm(DIN->64) + relu ----------------
template <int DIN>
__global__ __launch_bounds__(256) void k_gcn_s(const int* __restrict__ rs, const int* __restrict__ deg,
                                               const int* __restrict__ srcs, const float* __restrict__ dinv,
                                               const float* __restrict__ Hs, const float* __restrict__ W,
                                               const float* __restrict__ b, float* __restrict__ Out, int n)
{
    const int w = threadIdx.x >> 6, lane = threadIdx.x & 63;
    const int row = blockIdx.x * 4 + w;
    __shared__ float ag[4][DIN];
    const float di = dinv[row];
    const int e0 = rs[row];
    const int d = deg[row];
    float acc = (lane < DIN) ? Hs[(size_t)row * DIN + lane] : 0.f;
    int e = 0;
    for (; e + 8 <= d; e += 8) {
        int s0 = srcs[e0 + e + 0], s1 = srcs[e0 + e + 1], s2 = srcs[e0 + e + 2], s3 = srcs[e0 + e + 3];
        int s4 = srcs[e0 + e + 4], s5 = srcs[e0 + e + 5], s6 = srcs[e0 + e + 6], s7 = srcs[e0 + e + 7];
        float h0 = 0.f, h1 = 0.f, h2 = 0.f, h3 = 0.f, h4 = 0.f, h5 = 0.f, h6 = 0.f, h7 = 0.f;
        if (lane < DIN) {
            h0 = Hs[(size_t)s0 * DIN + lane]; h1 = Hs[(size_t)s1 * DIN + lane];
            h2 = Hs[(size_t)s2 * DIN + lane]; h3 = Hs[(size_t)s3 * DIN + lane];
            h4 = Hs[(size_t)s4 * DIN + lane]; h5 = Hs[(size_t)s5 * DIN + lane];
            h6 = Hs[(size_t)s6 * DIN + lane]; h7 = Hs[(size_t)s7 * DIN + lane];
        }
        acc += ((h0 + h1) + (h2 + h3)) + ((h4 + h5) + (h6 + h7));
    }
    for (; e + 4 <= d; e += 4) {
        int s0 = srcs[e0 + e + 0], s1 = srcs[e0 + e + 1], s2 = srcs[e0 + e + 2], s3 = srcs[e0 + e + 3];
        float h0 = 0.f, h1 = 0.f, h2 = 0.f, h3 = 0.f;
        if (lane < DIN) {
            h0 = Hs[(size_t)s0 * DIN + lane]; h1 = Hs[(size_t)s1 * DIN + lane];
            h2 = Hs[(size_t)s2 * DIN + lane]; h3 = Hs[(size_t)s3 * DIN + lane];
        }
        acc += (h0 + h1) + (h2 + h3);
    }
    for (; e < d; ++e) {
        int s = srcs[e0 + e];
        if (lane < DIN) acc += Hs[(size_t)s * DIN + lane];
    }
    if (lane < DIN) ag[w][lane] = acc;
    __syncthreads();
    float o = 0.f;
#pragma unroll
    for (int i = 0; i < DIN; ++i) o = fmaf(ag[w][i], W[i * 64 + lane], o);
    Out[(size_t)row * 64 + lane] = fmaxf(fmaf(di, o, b[lane]), 0.f);
}

// ---------------- fused pull+combine (scaled input): dest = di*(Hs[row] + sum Hs[s]) + b
template <int D>
__global__ __launch_bounds__(256) void k_pcomb_s(const int* __restrict__ rs, const int* __restrict__ deg,
                                                 const int* __restrict__ srcs, const float* __restrict__ dinv,
                                                 const float* __restrict__ Hs, const float* __restrict__ b,
                                                 float* __restrict__ dest, int n)
{
    const int wid = (blockIdx.x * blockDim.x + threadIdx.x) >> 6;
    const int lane = threadIdx.x & 63;
    if (wid >= n) return;
    const float di = dinv[wid];
    const int e0 = rs[wid];
    const int d = deg[wid];
    float acc = (lane < D) ? Hs[(size_t)wid * D + lane] : 0.f;
    int e = 0;
    for (; e + 8 <= d; e += 8) {
        int s0 = srcs[e0 + e + 0], s1 = srcs[e0 + e + 1], s2 = srcs[e0 + e + 2], s3 = srcs[e0 + e + 3];
        int s4 = srcs[e0 + e + 4], s5 = srcs[e0 + e + 5], s6 = srcs[e0 + e + 6], s7 = srcs[e0 + e + 7];
        float h0 = 0.f, h1 = 0.f, h2 = 0.f, h3 = 0.f, h4 = 0.f, h5 = 0.f, h6 = 0.f, h7 = 0.f;
        if (lane < D) {
            h0 = Hs[(size_t)s0 * D + lane]; h1 = Hs[(size_t)s1 * D + lane];
            h2 = Hs[(size_t)s2 * D + lane]; h3 = Hs[(size_t)s3 * D + lane];
            h4 = Hs[(size_t)s4 * D + lane]; h5 = Hs[(size_t)s5 * D + lane];
            h6 = Hs[(size_t)s6 * D + lane]; h7 = Hs[(size_t)s7 * D + lane];
        }
        acc += ((h0 + h1) + (h2 + h3)) + ((h4 + h5) + (h6 + h7));
    }
    for (; e + 4 <= d; e += 4) {
        int s0 = srcs[e0 + e + 0], s1 = srcs[e0 + e + 1], s2 = srcs[e0 + e + 2], s3 = srcs[e0 + e + 3];
        float h0 = 0.f, h1 = 0.f, h2 = 0.f, h3 = 0.f;
        if (lane < D) {
            h0 = Hs[(size_t)s0 * D + lane]; h1 = Hs[(size_t)s1 * D + lane];
            h2 = Hs[(size_t)s2 * D + lane]; h3 = Hs[(size_t)s3 * D + lane];
        }
        acc += (h0 + h1) + (h2 + h3);
    }
    for (; e < d; ++e) {
        int s = srcs[e0 + e];
        if (lane < D) acc += Hs[(size_t)s * D + lane];
    }
    if (lane < D) dest[(size_t)wid * D + lane] = fmaf(di, acc, b[lane]);
}

// D=1 scaled pull+combine: thread per row
__global__ void k_pcomb1_s(const int* __restrict__ rs, const int* __restrict__ deg,
                           const int* __restrict__ srcs, const float* __restrict__ dinv,
                           const float* __restrict__ Hs, const float* __restrict__ b,
                           float* __restrict__ dest, int n)
{
    int r = blockIdx.x * blockDim.x + threadIdx.x;
    if (r >= n) return;
    int e0 = rs[r], d = deg[r];
    float acc = Hs[r];
    int e = 0;
    for (; e + 8 <= d; e += 8) {
        acc += ((Hs[srcs[e0 + e + 0]] + Hs[srcs[e0 + e + 1]]) + (Hs[srcs[e0 + e + 2]] + Hs[srcs[e0 + e + 3]]))
             + ((Hs[srcs[e0 + e + 4]] + Hs[srcs[e0 + e + 5]]) + (Hs[srcs[e0 + e + 6]] + Hs[srcs[e0 + e + 7]]));
    }
    for (; e + 4 <= d; e += 4) {
        acc += (Hs[srcs[e0 + e + 0]] + Hs[srcs[e0 + e + 1]]) + (Hs[srcs[e0 + e + 2]] + Hs[srcs[e0 + e + 3]]);
    }
    for (; e < d; ++e) acc += Hs[srcs[e0 + e]];
    dest[r] = fmaf(dinv[r], acc, b[0]);
}

// ---------------- merged pre MLP: 35 -> 128(fp32) -> 128(MFMA split-bf16) -> 34(fp32) ----------------
// Layer 2 via mfma_f32_16x16x32_bf16, 3-term split (hi*Whi + hi*Wlo + lo*Whi) => ~fp32 accuracy.
// LDS: ldsB(16KB, oT aliases h2T) + h1 hi/lo bf16 (16KB) = 32KB -> 5 blocks/CU.
#define PR 32
__global__ __launch_bounds__(256) void k_pre_all(const int* __restrict__ cat1, const float* __restrict__ num1,
                                                 const int* __restrict__ cat2, const float* __restrict__ num2,
                                                 const float* __restrict__ emb0, const float* __restrict__ emb1,
                                                 const float* __restrict__ emb2,
                                                 const float* __restrict__ W1, const float* __restrict__ b1,
                                                 const unsigned short* __restrict__ W2fh,
                                                 const unsigned short* __restrict__ W2fl,
                                                 const float* __restrict__ b2,
                                                 const float* __restrict__ W3, const float* __restrict__ b3,
                                                 const float* __restrict__ dinv1, const float* __restrict__ dinv2,
                                                 float* __restrict__ X1, float* __restrict__ Xs1,
                                                 float* __restrict__ X2, float* __restrict__ Xs2,
                                                 int nblk1)
{
    __shared__ float ldsB[128 * 32];                       // h2T; oT aliases (oT dead before h2T written)
    __shared__ __align__(16) unsigned short h1h[128 * 32]; // h1 bf16 hi, [row][k] chunk-swizzled
    __shared__ __align__(16) unsigned short h1l[128 * 32]; // h1 bf16 lo
    float* oT = ldsB;
    float* h2T = ldsB;
    const int t = threadIdx.x;
    const int ct = t & 31;
    const int rg = t >> 5;  // 0..7
    const int gb = blockIdx.x;
    const int g2 = (gb >= nblk1);
    const int* cat = g2 ? cat2 : cat1;
    const float* num = g2 ? num2 : num1;
    const float* dinv = g2 ? dinv2 : dinv1;
    float* X = g2 ? X2 : X1;
    float* Xs = g2 ? Xs2 : Xs1;
    const int base = (g2 ? gb - nblk1 : gb) * PR;

    for (int idx = t; idx < 35 * PR; idx += 256) {
        int i = idx >> 5, r = idx & 31;
        int row = base + r;
        float v;
        if (i < 16) v = emb0[cat[row * 3 + 0] * 16 + i];
        else if (i < 24) v = emb1[cat[row * 3 + 1] * 8 + (i - 16)];
        else if (i < 32) v = emb2[cat[row * 3 + 2] * 8 + (i - 24)];
        else v = num[row * 3 + (i - 32)];
        oT[i * PR + (((r >> 2) ^ (i & 7)) << 2) + (r & 3)] = v;
    }
    __syncthreads();

    // ---- layer 1: 35 -> 128, fp32 vector, 4 cols x 4 rows per thread ----
    {
        float acc[4][4];
        float4 bb = *(const float4*)(b1 + 4 * ct);
        const float bbv[4] = {bb.x, bb.y, bb.z, bb.w};
#pragma unroll
        for (int c = 0; c < 4; ++c)
#pragma unroll
            for (int r = 0; r < 4; ++r) acc[c][r] = bbv[c];
        for (int i = 0; i < 35; ++i) {
            float4 ov = *(const float4*)(oT + i * PR + ((rg ^ (i & 7)) << 2));
            float4 wv = *(const float4*)(W1 + i * 128 + 4 * ct);
            const float o4[4] = {ov.x, ov.y, ov.z, ov.w};
            const float w4[4] = {wv.x, wv.y, wv.z, wv.w};
#pragma unroll
            for (int c = 0; c < 4; ++c)
#pragma unroll
                for (int r = 0; r < 4; ++r) acc[c][r] = fmaf(w4[c], o4[r], acc[c][r]);
        }
        // must finish all oT reads before layer2 overwrites ldsB (h2T) -- barrier below guarantees.
        // write h1 as bf16 hi/lo: thread covers k = 4ct..4ct+3, rows 4rg..4rg+3
#pragma unroll
        for (int j = 0; j < 4; ++j) {
            int row32 = 4 * rg + j;
            int rowm = row32 & 15;
            int off = row32 * 128 + ((((ct >> 1) ^ rowm)) << 3) + ((ct & 1) << 2);
            ushort4 hi4, lo4;
            float h0 = fmaxf(acc[0][j], 0.f);
            float h1v = fmaxf(acc[1][j], 0.f);
            float h2v = fmaxf(acc[2][j], 0.f);
            float h3v = fmaxf(acc[3][j], 0.f);
            hi4.x = f2bf(h0); lo4.x = f2bf(h0 - bf2f(hi4.x));
            hi4.y = f2bf(h1v); lo4.y = f2bf(h1v - bf2f(hi4.y));
            hi4.z = f2bf(h2v); lo4.z = f2bf(h2v - bf2f(hi4.z));
            hi4.w = f2bf(h3v); lo4.w = f2bf(h3v - bf2f(hi4.w));
            *(ushort4*)(h1h + off) = hi4;
            *(ushort4*)(h1l + off) = lo4;
        }
    }
    __syncthreads();

    // ---- layer 2: 128 -> 128 via MFMA (split bf16), writes h2T (fp32, swizzled) ----
    {
        const int wv = t >> 6, ln = t & 63;
        const int mt = wv & 1, ng = wv >> 1;
        const int lr = ln & 15, lh = ln >> 4;
        f32x4 acc[4];
#pragma unroll
        for (int j = 0; j < 4; ++j) acc[j] = (f32x4){0.f, 0.f, 0.f, 0.f};
        const int arow = (mt * 16 + lr) * 128;
#pragma unroll
        for (int ks = 0; ks < 4; ++ks) {
            const int sc = (((ks * 4 + lh) ^ lr) << 3);
            sh8 ahi = *(const sh8*)(h1h + arow + sc);
            sh8 alo = *(const sh8*)(h1l + arow + sc);
#pragma unroll
            for (int j = 0; j < 4; ++j) {
                const int fbase = ((((ng * 4 + j) * 4 + ks) * 64 + ln) << 3);
                sh8 bhi = *(const sh8*)(W2fh + fbase);
                sh8 blo = *(const sh8*)(W2fl + fbase);
                acc[j] = __builtin_amdgcn_mfma_f32_16x16x32_bf16(ahi, bhi, acc[j], 0, 0, 0);
                acc[j] = __builtin_amdgcn_mfma_f32_16x16x32_bf16(ahi, blo, acc[j], 0, 0, 0);
                acc[j] = __builtin_amdgcn_mfma_f32_16x16x32_bf16(alo, bhi, acc[j], 0, 0, 0);
            }
        }
        __syncthreads();  // all oT/layer-1 traffic done; safe to overwrite ldsB
#pragma unroll
        for (int j = 0; j < 4; ++j) {
            int col = (ng * 4 + j) * 16 + lr;
            int rg3 = mt * 4 + lh;
            float bc = b2[col];
            float4 v;
            v.x = fmaxf(acc[j][0] + bc, 0.f);
            v.y = fmaxf(acc[j][1] + bc, 0.f);
            v.z = fmaxf(acc[j][2] + bc, 0.f);
            v.w = fmaxf(acc[j][3] + bc, 0.f);
            *(float4*)(h2T + col * PR + ((rg3 ^ (col & 7)) << 2)) = v;
        }
    }
    __syncthreads();

    // ---- layer 3: 128 -> 34, tasks = (j, row-group): 34*8 = 272 ----
    for (int task = t; task < 34 * 8; task += 256) {
        int j = task >> 3, rg3 = task & 7;
        float a0 = b3[j], a1 = a0, a2 = a0, a3 = a0;
#pragma unroll 4
        for (int k = 0; k < 128; ++k) {
            float4 hv = *(const float4*)(h2T + k * PR + ((rg3 ^ (k & 7)) << 2));
            float wv = W3[k * 34 + j];
            a0 = fmaf(hv.x, wv, a0);
            a1 = fmaf(hv.y, wv, a1);
            a2 = fmaf(hv.z, wv, a2);
            a3 = fmaf(hv.w, wv, a3);
        }
        size_t rb = (size_t)(base + rg3 * 4);
        float d0 = dinv[rb + 0], d1 = dinv[rb + 1], d2 = dinv[rb + 2], d3 = dinv[rb + 3];
        X[(rb + 0) * 35 + j] = a0;  Xs[(rb + 0) * 35 + j] = a0 * d0;
        X[(rb + 1) * 35 + j] = a1;  Xs[(rb + 1) * 35 + j] = a1 * d1;
        X[(rb + 2) * 35 + j] = a2;  Xs[(rb + 2) * 35 + j] = a2 * d2;
        X[(rb + 3) * 35 + j] = a3;  Xs[(rb + 3) * 35 + j] = a3 * d3;
    }
    if (t < PR) {
        int row = base + t;
        float v = num[row * 3 + 2];
        X[(size_t)row * 35 + 34] = v;
        Xs[(size_t)row * 35 + 34] = v * dinv[row];
    }
}

// ---------------- plain dense gemm (row-major W: DIN x DOUT), float4 row loads ----------------
template <int DIN, int DOUT, bool BIAS, bool RELU, bool SCALE>
__global__ void k_gemm(const float* __restrict__ Xin, int ldin, const float* __restrict__ W,
                       const float* __restrict__ b, const float* __restrict__ oscale,
                       float* __restrict__ Out, int n)
{
    __shared__ float Ws[DIN * DOUT];
    for (int i = threadIdx.x; i < DIN * DOUT; i += blockDim.x) Ws[i] = W[i];
    __syncthreads();
    int idx = blockIdx.x * blockDim.x + threadIdx.x;
    if (idx >= n * DOUT) return;
    int row = idx / DOUT, j = idx - row * DOUT;
    const float4* xr4 = (const float4*)(Xin + (size_t)row * ldin);
    float acc = BIAS ? b[j] : 0.f;
#pragma unroll
    for (int i4 = 0; i4 < DIN / 4; ++i4) {
        float4 x = xr4[i4];
        acc = fmaf(x.x, Ws[(4 * i4 + 0) * DOUT + j], acc);
        acc = fmaf(x.y, Ws[(4 * i4 + 1) * DOUT + j], acc);
        acc = fmaf(x.z, Ws[(4 * i4 + 2) * DOUT + j], acc);
        acc = fmaf(x.w, Ws[(4 * i4 + 3) * DOUT + j], acc);
    }
    if (RELU) acc = fmaxf(acc, 0.f);
    if (SCALE) acc *= oscale[row];
    Out[idx] = acc;
}

// ---------------- alpha / yh: per-batch kernel regression ----------------
__global__ __launch_bounds__(256) void k_alpha(const float* __restrict__ X1,  // n1 x 34 (g1 out)
                                               const float* __restrict__ X,   // n1 x 35 (y col)
                                               float* __restrict__ X2,        // n2 x 35
                                               float* __restrict__ Xs2,       // n2 x 35 scaled
                                               const float* __restrict__ dinv2,
                                               const float* __restrict__ theta,
                                               const float* __restrict__ A,
                                               const float* __restrict__ scale)
{
    const int b = blockIdx.x;
    const int t = threadIdx.x;
    const int p = t & 63;
    const int w = t >> 6;
    __shared__ float th[34 * 34];
    __shared__ float xpS[64 * 35];
    __shared__ float xfS[16 * 34];
    __shared__ float UfS[16 * 34];
    __shared__ float upPart[4][64];
    __shared__ float upS[64];
    __shared__ float yS[64];

    for (int i = t; i < 34 * 34; i += 256) th[i] = theta[i];
    for (int i = t; i < 64 * 34; i += 256) {
        int r = i / 34, o = i - 34 * r;
        xpS[r * 35 + o] = X1[(size_t)(b * 64 + r) * 34 + o];
    }
    for (int i = t; i < 16 * 34; i += 256) {
        int q = i / 34, o = i - 34 * q;
        xfS[i] = X2[(size_t)(b * 16 + q) * 35 + o];
    }
    if (t < 64) yS[t] = X[(size_t)(b * 64 + t) * 35 + 34];
    __syncthreads();

    for (int i = t; i < 16 * 34; i += 256) {
        int q = i / 34, o = i - 34 * q;
        float a = 0.f;
#pragma unroll
        for (int O = 0; O < 34; ++O) a = fmaf(th[o * 34 + O], xfS[q * 34 + O], a);
        UfS[i] = a;
    }
    {
        const int o0 = w * 9;
        const int o1 = (o0 + 9 < 34) ? o0 + 9 : 34;
        float a = 0.f;
        for (int o = o0; o < o1; ++o) {
            float s2 = 0.f;
#pragma unroll
            for (int O = 0; O < 34; ++O) s2 = fmaf(th[o * 34 + O], xpS[p * 35 + O], s2);
            a = fmaf(xpS[p * 35 + o], s2, a);
        }
        upPart[w][p] = a;
    }
    __syncthreads();
    if (t < 64) upS[t] = upPart[0][t] + upPart[1][t] + upPart[2][t] + upPart[3][t];
    __syncthreads();

    const float sc = scale[0];
    const float up = upS[p];
    const float y = yS[p];
#pragma unroll
    for (int i = 0; i < 4; ++i) {
        const int q = w + 4 * i;
        float g = 0.f;
#pragma unroll
        for (int o = 0; o < 34; ++o) g = fmaf(UfS[q * 34 + o], xpS[p * 35 + o], g);
        float a = sc * (up - 2.f * g);
        if (A[(PASTN + q) * NN + p] == 0.f) a = -INFINITY;
        float mx = a;
#pragma unroll
        for (int off = 32; off > 0; off >>= 1) mx = fmaxf(mx, __shfl_xor(mx, off));
        float e = expf(a - mx);
        float s = e;
#pragma unroll
        for (int off = 32; off > 0; off >>= 1) s += __shfl_xor(s, off);
        float c = (e / s) * y;
#pragma unroll
        for (int off = 32; off > 0; off >>= 1) c += __shfl_xor(c, off);
        if (p == 0) {
            size_t ridx = (size_t)(b * 16 + q);
            X2[ridx * 35 + 34] = c;
            Xs2[ridx * 35 + 34] = c * dinv2[ridx];
        }
    }
}

// ---------------- pairwise distances: 5x5 register tiles, pitch 44 ----------------
__global__ __launch_bounds__(256) void k_cd(const float* __restrict__ X, const float* __restrict__ X2,
                                            float* __restrict__ cd)
{
    const int b = blockIdx.x;
    const int t = threadIdx.x;
    __shared__ float xa[80 * 44];
    __shared__ float sq[80];
    for (int idx = t; idx < 80 * 44; idx += 256) {
        int nrow = idx / 44, k = idx - 44 * nrow;
        float v = 0.f;
        if (k < 35)
            v = (nrow < 64) ? X[(size_t)(b * 64 + nrow) * 35 + k]
                            : X2[(size_t)(b * 16 + (nrow - 64)) * 35 + k];
        xa[idx] = v;
    }
    __syncthreads();
    const float4* xa4 = (const float4*)xa;
    if (t < 80) {
        float acc = 0.f;
#pragma unroll
        for (int c = 0; c < 9; ++c) {
            float4 v = xa4[t * 11 + c];
            acc = fmaf(v.x, v.x, fmaf(v.y, v.y, fmaf(v.z, v.z, fmaf(v.w, v.w, acc))));
        }
        sq[t] = acc;
    }
    __syncthreads();
    const int ti = t >> 4;
    const int tj = t & 15;
    float dot[5][5];
#pragma unroll
    for (int r = 0; r < 5; ++r)
#pragma unroll
        for (int c = 0; c < 5; ++c) dot[r][c] = 0.f;
#pragma unroll
    for (int ch = 0; ch < 9; ++ch) {
        float4 av[5], bv[5];
#pragma unroll
        for (int r = 0; r < 5; ++r) av[r] = xa4[(5 * ti + r) * 11 + ch];
#pragma unroll
        for (int c = 0; c < 5; ++c) bv[c] = xa4[(5 * tj + c) * 11 + ch];
#pragma unroll
        for (int r = 0; r < 5; ++r)
#pragma unroll
            for (int c = 0; c < 5; ++c)
                dot[r][c] = fmaf(av[r].x, bv[c].x, fmaf(av[r].y, bv[c].y,
                              fmaf(av[r].z, bv[c].z, fmaf(av[r].w, bv[c].w, dot[r][c]))));
    }
    float* out = cd + (size_t)b * 6400;
#pragma unroll
    for (int r = 0; r < 5; ++r) {
        int n_ = 5 * ti + r;
        float sn = sq[n_];
#pragma unroll
        for (int c = 0; c < 5; ++c) {
            int m = 5 * tj + c;
            float d2 = sn + sq[m] - 2.f * dot[r][c];
            out[n_ * 80 + m] = sqrtf(fmaxf(d2, 0.f));
        }
    }
}

extern "C" void kernel_launch(void* const* d_in, const int* in_sizes, int n_in,
                              void* d_out, int out_size, void* d_ws, size_t ws_size,
                              hipStream_t stream)
{
    const int* x1_cat = (const int*)d_in[0];
    const float* x1_num = (const float*)d_in[1];
    const int* x2_cat = (const int*)d_in[2];
    const float* x2_num = (const float*)d_in[3];
    const int* e1 = (const int*)d_in[4];
    const int* e2 = (const int*)d_in[5];
    const float* emb0 = (const float*)d_in[6];
    const float* emb1 = (const float*)d_in[7];
    const float* emb2 = (const float*)d_in[8];
    const float* pW1 = (const float*)d_in[9];
    const float* pb1 = (const float*)d_in[10];
    const float* pW2 = (const float*)d_in[11];
    const float* pb2 = (const float*)d_in[12];
    const float* pW3 = (const float*)d_in[13];
    const float* pb3 = (const float*)d_in[14];
    const float* g1W1 = (const float*)d_in[15];
    const float* g1b1 = (const float*)d_in[16];
    const float* g1W2 = (const float*)d_in[17];
    const float* g1b2 = (const float*)d_in[18];
    const float* g2W1 = (const float*)d_in[19];
    const float* g2b1 = (const float*)d_in[20];
    const float* g2W2 = (const float*)d_in[21];
    const float* g2b2 = (const float*)d_in[22];
    const float* kerW = (const float*)d_in[23];
    const float* smoothing = (const float*)d_in[24];
    const float* M = (const float*)d_in[25];

    const int n1 = in_sizes[0] / 3;
    const int n2 = in_sizes[2] / 3;
    const int E1 = in_sizes[4] / 2;
    const int E2 = in_sizes[5] / 2;
    const int SBc = n2 / FUTN;

    float* w = (float*)d_ws;
    size_t off = 0;
    float* scale = w + off; off += 16;
    float* theta = w + off; off += 1184;
    float* Aws = w + off; off += 6400;
    float* X = w + off; off += (size_t)n1 * 35;
    float* Xs1 = w + off; off += (size_t)n1 * 35;
    float* X2 = w + off; off += (size_t)n2 * 35;
    float* Xs2 = w + off; off += (size_t)n2 * 35;
    float* dinv1 = w + off; off += (size_t)n1;
    float* dinv2 = w + off; off += (size_t)n2;
    float* B2 = w + off; off += (size_t)n1 * 64;
    float* B3 = w + off; off += (size_t)n1 * 34;
    float* B4 = w + off; off += (size_t)n1 * 34;
    off = (off + 3) & ~(size_t)3;  // 16B align for bf16 fragment arrays
    unsigned short* W2fh = (unsigned short*)(w + off); off += 8192;  // 16384 ushorts
    unsigned short* W2fl = (unsigned short*)(w + off); off += 8192;
    int* iw = (int*)(w + off);
    size_t ioff = 0;
    int* degi1 = iw + ioff; ioff += n1;
    int* degi2 = iw + ioff; ioff += n2;
    int* rs1 = iw + ioff; ioff += n1;
    int* cur1 = iw + ioff; ioff += n1;
    int* srcs1 = iw + ioff; ioff += E1;
    int* rs2 = iw + ioff; ioff += n2;
    int* cur2 = iw + ioff; ioff += n2;
    int* srcs2 = iw + ioff; ioff += E2;
    int* bsumA = iw + ioff; ioff += 1024;
    int* bsumB = iw + ioff; ioff += 1024;

    float* out_f = (float*)d_out;
    float* cd_f = out_f + (size_t)SBc * FUTN;
    float* A_out = cd_f + (size_t)SBc * NN * NN;

    auto cdiv = [](long long a, long long b) { return (unsigned)((a + b - 1) / b); };

    // ---- degrees + CSR build (merged kernels) ----
    hipMemsetAsync(degi1, 0, ((size_t)n1 + n2) * 4, stream);
    k_setup<<<1, 256, 0, stream>>>(M, kerW, smoothing, Aws, A_out, theta, scale);
    k_wconv<<<64, 256, 0, stream>>>(pW2, W2fh, W2fl);

    const int nbe1 = cdiv(E1, 256), nbe2 = cdiv(E2, 256);
    k_deg2<<<nbe1 + nbe2, 256, 0, stream>>>(e1 + E1, e2 + E2, degi1, degi2, E1, E2, nbe1);

    const int nb1 = cdiv(n1, SCHUNK), nb2 = cdiv(n2, SCHUNK);
    k_scan_reduce2<<<nb1 + nb2, 256, 0, stream>>>(degi1, degi2, bsumA, bsumB, n1, n2, nb1);
    k_scan_mid2<<<2, 1024, 0, stream>>>(bsumA, bsumB, nb1, nb2);
    k_scan_final2<<<nb1 + nb2, 256, 0, stream>>>(degi1, degi2, bsumA, bsumB, rs1, rs2, cur1, cur2,
                                                 dinv1, dinv2, n1, n2, nb1);
    k_fill2<<<nbe1 + nbe2, 256, 0, stream>>>(e1, e1 + E1, e2, e2 + E2, cur1, cur2, srcs1, srcs2, E1, E2, nbe1);

    // ---- pre MLP, both node sets in one dispatch (layer 2 = MFMA split-bf16) ----
    k_pre_all<<<n1 / PR + n2 / PR, 256, 0, stream>>>(x1_cat, x1_num, x2_cat, x2_num,
                                                     emb0, emb1, emb2, pW1, pb1, W2fh, W2fl, pb2, pW3, pb3,
                                                     dinv1, dinv2, X, Xs1, X2, Xs2, n1 / PR);

    // ---- g1 layer 1: fused pull(35, scaled)+gemm(35->64)+relu ----
    k_gcn_s<35><<<cdiv(n1, 4), 256, 0, stream>>>(rs1, degi1, srcs1, dinv1, Xs1, g1W1, g1b1, B2, n1);

    // ---- g1 layer 2: gemm 64->34 (output pre-scaled by dinv1) then fused pull+combine ----
    k_gemm<64, 34, false, false, true><<<cdiv((long long)n1 * 34, 256), 256, 0, stream>>>(B2, 64, g1W2, nullptr, dinv1, B3, n1);
    k_pcomb_s<34><<<cdiv(n1, 4), 256, 0, stream>>>(rs1, degi1, srcs1, dinv1, B3, g1b2, B4, n1);

    // ---- alpha / yh -> X2 col 34 (+ scaled copy) ----
    k_alpha<<<SBc, 256, 0, stream>>>(B4, X, X2, Xs2, dinv2, theta, Aws, scale);

    // ---- g2 layer 1 ----
    k_gcn_s<35><<<cdiv(n2, 4), 256, 0, stream>>>(rs2, degi2, srcs2, dinv2, Xs2, g2W1, g2b1, B2, n2);

    // ---- g2 layer 2: gemm 64->1 (pre-scaled), fused pull+combine ----
    k_gemm<64, 1, false, false, true><<<cdiv(n2, 256), 256, 0, stream>>>(B2, 64, g2W2, nullptr, dinv2, B3, n2);
    k_pcomb1_s<<<cdiv(n2, 256), 256, 0, stream>>>(rs2, degi2, srcs2, dinv2, B3, g2b2, out_f, n2);

    // ---- pairwise distances ----
    k_cd<<<SBc, 256, 0, stream>>>(X, X2, cd_f);
}

// Round 9
// 671.359 us; speedup vs baseline: 2.1947x; 1.0575x over previous
//
#include <hip/hip_runtime.h>
#include <math.h>

#define PASTN 64
#define FUTN 16
#define NN 80

typedef __attribute__((ext_vector_type(8))) short sh8;
typedef __attribute__((ext_vector_type(4))) float f32x4;

__device__ __forceinline__ unsigned short f2bf(float f) {
    unsigned int u = __float_as_uint(f);
    return (unsigned short)((u + 0x7FFFu + ((u >> 16) & 1u)) >> 16);
}
__device__ __forceinline__ float bf2f(unsigned short s) {
    return __uint_as_float(((unsigned int)s) << 16);
}

// ---------------- setup: A (causal softmax of relu(M M^T)), theta, scale ----------------
__global__ __launch_bounds__(256) void k_setup(const float* __restrict__ M, const float* __restrict__ kerW,
                                               const float* __restrict__ smoothing,
                                               float* __restrict__ A_ws, float* __restrict__ A_out,
                                               float* __restrict__ theta, float* __restrict__ scale)
{
    __shared__ float Ms[80 * 26];
    __shared__ float Ar[80 * 80];
    const int t = threadIdx.x;
    for (int i = t; i < 80 * 26; i += 256) Ms[i] = M[i];
    __syncthreads();
    for (int idx = t; idx < 6400; idx += 256) {
        int i = idx / 80, j = idx - 80 * i;
        float acc = 0.f;
#pragma unroll
        for (int k = 0; k < 26; ++k) acc = fmaf(Ms[i * 26 + k], Ms[j * 26 + k], acc);
        Ar[idx] = fmaxf(acc, 0.f);
    }
    __syncthreads();
    if (t < 80) {
        float mx = -1e30f;
        for (int j = 0; j <= t; ++j) mx = fmaxf(mx, Ar[t * 80 + j]);
        float s = 0.f;
        for (int j = 0; j <= t; ++j) s += expf(Ar[t * 80 + j] - mx);
        float inv = 1.f / s;
        for (int j = 0; j < 80; ++j) {
            float v = (j <= t) ? expf(Ar[t * 80 + j] - mx) * inv : 0.f;
            A_ws[t * 80 + j] = v;
            A_out[t * 80 + j] = v;
        }
    }
    for (int idx = t; idx < 34 * 34; idx += 256) {
        int i = idx / 34, j = idx - 34 * i;
        float acc = 0.f;
        for (int k = 0; k < 128; ++k) acc = fmaf(kerW[i * 128 + k], kerW[j * 128 + k], acc);
        theta[idx] = acc;
    }
    if (t == 0) {
        float s0 = smoothing[0];
        float sig = 1.f / (1.f + expf(-s0));
        scale[0] = -0.5f / (sig * 0.01f);
    }
}

// ---------------- W1/W2/W3 -> fragment-ordered bf16 hi/lo (once per launch) ----------------
// B fragment for 16x16x32: lane l holds col = nt*16+(l&15), k = ks*32+(l>>4)*8+i.
// W1: 35x128 zero-padded K->64 (2 ks, 8 nt) -> 8192 halves.
// W2: 128x128 (4 ks, 8 nt) -> 16384 halves.
// W3: 128x34 zero-padded N->64 (4 ks, 4 nt) -> 8192 halves.
__global__ void k_wconv(const float* __restrict__ W1, const float* __restrict__ W2,
                        const float* __restrict__ W3,
                        unsigned short* __restrict__ W1h, unsigned short* __restrict__ W1l,
                        unsigned short* __restrict__ W2h, unsigned short* __restrict__ W2l,
                        unsigned short* __restrict__ W3h, unsigned short* __restrict__ W3l)
{
    int g = blockIdx.x * 256 + threadIdx.x;  // 0..32767
    float w;
    unsigned short *dh, *dl;
    int gi;
    if (g < 8192) {
        gi = g;
        int i = gi & 7, l = (gi >> 3) & 63, ks = (gi >> 9) & 1, nt = gi >> 10;
        int col = nt * 16 + (l & 15);
        int k = ks * 32 + ((l >> 4) << 3) + i;
        w = (k < 35) ? W1[k * 128 + col] : 0.f;
        dh = W1h; dl = W1l;
    } else if (g < 24576) {
        gi = g - 8192;
        int i = gi & 7, l = (gi >> 3) & 63, ks = (gi >> 9) & 3, nt = gi >> 11;
        int col = nt * 16 + (l & 15);
        int k = ks * 32 + ((l >> 4) << 3) + i;
        w = W2[k * 128 + col];
        dh = W2h; dl = W2l;
    } else {
        gi = g - 24576;
        int i = gi & 7, l = (gi >> 3) & 63, ks = (gi >> 9) & 3, nt = gi >> 11;
        int col = nt * 16 + (l & 15);
        int k = ks * 32 + ((l >> 4) << 3) + i;
        w = (col < 34) ? W3[k * 34 + col] : 0.f;
        dh = W3h; dl = W3l;
    }
    unsigned short hi = f2bf(w);
    dh[gi] = hi;
    dl[gi] = f2bf(w - bf2f(hi));
}

// ---------------- merged degree count (both graphs) ----------------
__global__ void k_deg2(const int* __restrict__ dst1, const int* __restrict__ dst2,
                       int* __restrict__ deg1, int* __restrict__ deg2,
                       int E1, int E2, int nbe1)
{
    int gb = blockIdx.x;
    if (gb < nbe1) {
        int e = gb * 256 + threadIdx.x;
        if (e < E1) atomicAdd(&deg1[dst1[e]], 1);
    } else {
        int e = (gb - nbe1) * 256 + threadIdx.x;
        if (e < E2) atomicAdd(&deg2[dst2[e]], 1);
    }
}

// ---------------- merged exclusive scan, chunk = 1024 ----------------
#define SCHUNK 1024
__global__ __launch_bounds__(256) void k_scan_reduce2(const int* __restrict__ deg1, const int* __restrict__ deg2,
                                                      int* __restrict__ bsumA, int* __restrict__ bsumB,
                                                      int n1, int n2, int nb1)
{
    __shared__ int sd[256];
    const int gb = blockIdx.x, t = threadIdx.x;
    const int which = (gb < nb1) ? 0 : 1;
    const int b = which ? gb - nb1 : gb;
    const int* deg = which ? deg2 : deg1;
    const int n = which ? n2 : n1;
    const int base = b * SCHUNK;
    int s = 0;
#pragma unroll
    for (int j = 0; j < 4; ++j) {
        int i = base + t + j * 256;
        if (i < n) s += deg[i];
    }
    sd[t] = s;
    __syncthreads();
    for (int o = 128; o > 0; o >>= 1) {
        if (t < o) sd[t] += sd[t + o];
        __syncthreads();
    }
    if (t == 0) (which ? bsumB : bsumA)[b] = sd[0];
}

__global__ __launch_bounds__(1024) void k_scan_mid2(int* __restrict__ bsumA, int* __restrict__ bsumB,
                                                    int nbA, int nbB)
{
    __shared__ int sd[1024];
    const int t = threadIdx.x;
    int* bsum = (blockIdx.x == 0) ? bsumA : bsumB;
    int nb = (blockIdx.x == 0) ? nbA : nbB;
    int orig = (t < nb) ? bsum[t] : 0;
    sd[t] = orig;
    __syncthreads();
    for (int o = 1; o < 1024; o <<= 1) {
        int v = (t >= o) ? sd[t - o] : 0;
        __syncthreads();
        sd[t] += v;
        __syncthreads();
    }
    if (t < nb) bsum[t] = sd[t] - orig;  // exclusive
}

// final scan; also writes cur (copy of rs) and dinv = rsqrt(1+deg)
__global__ __launch_bounds__(256) void k_scan_final2(const int* __restrict__ deg1, const int* __restrict__ deg2,
                                                     const int* __restrict__ bsumA, const int* __restrict__ bsumB,
                                                     int* __restrict__ rs1, int* __restrict__ rs2,
                                                     int* __restrict__ cur1, int* __restrict__ cur2,
                                                     float* __restrict__ dinv1, float* __restrict__ dinv2,
                                                     int n1, int n2, int nb1)
{
    __shared__ int sd[256];
    const int gb = blockIdx.x, t = threadIdx.x;
    const int which = (gb < nb1) ? 0 : 1;
    const int b = which ? gb - nb1 : gb;
    const int* deg = which ? deg2 : deg1;
    const int* bsum = which ? bsumB : bsumA;
    int* rs = which ? rs2 : rs1;
    int* cur = which ? cur2 : cur1;
    float* dinv = which ? dinv2 : dinv1;
    const int n = which ? n2 : n1;
    const int base = b * SCHUNK + t * 4;
    int v0 = (base + 0 < n) ? deg[base + 0] : 0;
    int v1 = (base + 1 < n) ? deg[base + 1] : 0;
    int v2 = (base + 2 < n) ? deg[base + 2] : 0;
    int v3 = (base + 3 < n) ? deg[base + 3] : 0;
    int tsum = v0 + v1 + v2 + v3;
    sd[t] = tsum;
    __syncthreads();
    int incl = tsum;
    for (int o = 1; o < 256; o <<= 1) {
        int v = (t >= o) ? sd[t - o] : 0;
        __syncthreads();
        incl += v;
        sd[t] = incl;
        __syncthreads();
    }
    int off = bsum[b] + incl - tsum;
    if (base + 0 < n) { rs[base + 0] = off;            cur[base + 0] = off;            dinv[base + 0] = rsqrtf(1.f + (float)v0); }
    if (base + 1 < n) { rs[base + 1] = off + v0;       cur[base + 1] = off + v0;       dinv[base + 1] = rsqrtf(1.f + (float)v1); }
    if (base + 2 < n) { rs[base + 2] = off + v0 + v1;  cur[base + 2] = off + v0 + v1;  dinv[base + 2] = rsqrtf(1.f + (float)v2); }
    if (base + 3 < n) { rs[base + 3] = off + v0 + v1 + v2; cur[base + 3] = off + v0 + v1 + v2; dinv[base + 3] = rsqrtf(1.f + (float)v3); }
}

// ---------------- merged CSR fill ----------------
__global__ void k_fill2(const int* __restrict__ src1, const int* __restrict__ dst1,
                        const int* __restrict__ src2, const int* __restrict__ dst2,
                        int* __restrict__ cur1, int* __restrict__ cur2,
                        int* __restrict__ out1, int* __restrict__ out2,
                        int E1, int E2, int nbe1)
{
    int gb = blockIdx.x;
    if (gb < nbe1) {
        int e = gb * 256 + threadIdx.x;
        if (e < E1) { int pos = atomicAdd(&cur1[dst1[e]], 1); out1[pos] = src1[e]; }
    } else {
        int e = (gb - nbe1) * 256 + threadIdx.x;
        if (e < E2) { int pos = atomicAdd(&cur2[dst2[e]], 1); out2[pos] = src2[e]; }
    }
}

// ---------------- fused GCN layer 1 (scaled input): pull + gemm(DIN->64) + relu ----------------
template <int DIN>
__global__ __launch_bounds__(256) void k_gcn_s(const int* __restrict__ rs, const int* __restrict__ deg,
                                               const int* __restrict__ srcs, const float* __restrict__ dinv,
                                               const float* __restrict__ Hs, const float* __restrict__ W,
                                               const float* __restrict__ b, float* __restrict__ Out, int n)
{
    const int w = threadIdx.x >> 6, lane = threadIdx.x & 63;
    const int row = blockIdx.x * 4 + w;
    __shared__ float ag[4][DIN];
    const float di = dinv[row];
    const int e0 = rs[row];
    const int d = deg[row];
    float acc = (lane < DIN) ? Hs[(size_t)row * DIN + lane] : 0.f;
    int e = 0;
    for (; e + 8 <= d; e += 8) {
        int s0 = srcs[e0 + e + 0], s1 = srcs[e0 + e + 1], s2 = srcs[e0 + e + 2], s3 = srcs[e0 + e + 3];
        int s4 = srcs[e0 + e + 4], s5 = srcs[e0 + e + 5], s6 = srcs[e0 + e + 6], s7 = srcs[e0 + e + 7];
        float h0 = 0.f, h1 = 0.f, h2 = 0.f, h3 = 0.f, h4 = 0.f, h5 = 0.f, h6 = 0.f, h7 = 0.f;
        if (lane < DIN) {
            h0 = Hs[(size_t)s0 * DIN + lane]; h1 = Hs[(size_t)s1 * DIN + lane];
            h2 = Hs[(size_t)s2 * DIN + lane]; h3 = Hs[(size_t)s3 * DIN + lane];
            h4 = Hs[(size_t)s4 * DIN + lane]; h5 = Hs[(size_t)s5 * DIN + lane];
            h6 = Hs[(size_t)s6 * DIN + lane]; h7 = Hs[(size_t)s7 * DIN + lane];
        }
        acc += ((h0 + h1) + (h2 + h3)) + ((h4 + h5) + (h6 + h7));
    }
    for (; e + 4 <= d; e += 4) {
        int s0 = srcs[e0 + e + 0], s1 = srcs[e0 + e + 1], s2 = srcs[e0 + e + 2], s3 = srcs[e0 + e + 3];
        float h0 = 0.f, h1 = 0.f, h2 = 0.f, h3 = 0.f;
        if (lane < DIN) {
            h0 = Hs[(size_t)s0 * DIN + lane]; h1 = Hs[(size_t)s1 * DIN + lane];
            h2 = Hs[(size_t)s2 * DIN + lane]; h3 = Hs[(size_t)s3 * DIN + lane];
        }
        acc += (h0 + h1) + (h2 + h3);
    }
    for (; e < d; ++e) {
        int s = srcs[e0 + e];
        if (lane < DIN) acc += Hs[(size_t)s * DIN + lane];
    }
    if (lane < DIN) ag[w][lane] = acc;
    __syncthreads();
    float o = 0.f;
#pragma unroll
    for (int i = 0; i < DIN; ++i) o = fmaf(ag[w][i], W[i * 64 + lane], o);
    Out[(size_t)row * 64 + lane] = fmaxf(fmaf(di, o, b[lane]), 0.f);
}

// ---------------- fused pull+combine (scaled input): dest = di*(Hs[row] + sum Hs[s]) + b
template <int D>
__global__ __launch_bounds__(256) void k_pcomb_s(const int* __restrict__ rs, const int* __restrict__ deg,
                                                 const int* __restrict__ srcs, const float* __restrict__ dinv,
                                                 const float* __restrict__ Hs, const float* __restrict__ b,
                                                 float* __restrict__ dest, int n)
{
    const int wid = (blockIdx.x * blockDim.x + threadIdx.x) >> 6;
    const int lane = threadIdx.x & 63;
    if (wid >= n) return;
    const float di = dinv[wid];
    const int e0 = rs[wid];
    const int d = deg[wid];
    float acc = (lane < D) ? Hs[(size_t)wid * D + lane] : 0.f;
    int e = 0;
    for (; e + 8 <= d; e += 8) {
        int s0 = srcs[e0 + e + 0], s1 = srcs[e0 + e + 1], s2 = srcs[e0 + e + 2], s3 = srcs[e0 + e + 3];
        int s4 = srcs[e0 + e + 4], s5 = srcs[e0 + e + 5], s6 = srcs[e0 + e + 6], s7 = srcs[e0 + e + 7];
        float h0 = 0.f, h1 = 0.f, h2 = 0.f, h3 = 0.f, h4 = 0.f, h5 = 0.f, h6 = 0.f, h7 = 0.f;
        if (lane < D) {
            h0 = Hs[(size_t)s0 * D + lane]; h1 = Hs[(size_t)s1 * D + lane];
            h2 = Hs[(size_t)s2 * D + lane]; h3 = Hs[(size_t)s3 * D + lane];
            h4 = Hs[(size_t)s4 * D + lane]; h5 = Hs[(size_t)s5 * D + lane];
            h6 = Hs[(size_t)s6 * D + lane]; h7 = Hs[(size_t)s7 * D + lane];
        }
        acc += ((h0 + h1) + (h2 + h3)) + ((h4 + h5) + (h6 + h7));
    }
    for (; e + 4 <= d; e += 4) {
        int s0 = srcs[e0 + e + 0], s1 = srcs[e0 + e + 1], s2 = srcs[e0 + e + 2], s3 = srcs[e0 + e + 3];
        float h0 = 0.f, h1 = 0.f, h2 = 0.f, h3 = 0.f;
        if (lane < D) {
            h0 = Hs[(size_t)s0 * D + lane]; h1 = Hs[(size_t)s1 * D + lane];
            h2 = Hs[(size_t)s2 * D + lane]; h3 = Hs[(size_t)s3 * D + lane];
        }
        acc += (h0 + h1) + (h2 + h3);
    }
    for (; e < d; ++e) {
        int s = srcs[e0 + e];
        if (lane < D) acc += Hs[(size_t)s * D + lane];
    }
    if (lane < D) dest[(size_t)wid * D + lane] = fmaf(di, acc, b[lane]);
}

// D=1 scaled pull+combine: thread per row
__global__ void k_pcomb1_s(const int* __restrict__ rs, const int* __restrict__ deg,
                           const int* __restrict__ srcs, const float* __restrict__ dinv,
                           const float* __restrict__ Hs, const float* __restrict__ b,
                           float* __restrict__ dest, int n)
{
    int r = blockIdx.x * blockDim.x + threadIdx.x;
    if (r >= n) return;
    int e0 = rs[r], d = deg[r];
    float acc = Hs[r];
    int e = 0;
    for (; e + 8 <= d; e += 8) {
        acc += ((Hs[srcs[e0 + e + 0]] + Hs[srcs[e0 + e + 1]]) + (Hs[srcs[e0 + e + 2]] + Hs[srcs[e0 + e + 3]]))
             + ((Hs[srcs[e0 + e + 4]] + Hs[srcs[e0 + e + 5]]) + (Hs[srcs[e0 + e + 6]] + Hs[srcs[e0 + e + 7]]));
    }
    for (; e + 4 <= d; e += 4) {
        acc += (Hs[srcs[e0 + e + 0]] + Hs[srcs[e0 + e + 1]]) + (Hs[srcs[e0 + e + 2]] + Hs[srcs[e0 + e + 3]]);
    }
    for (; e < d; ++e) acc += Hs[srcs[e0 + e]];
    dest[r] = fmaf(dinv[r], acc, b[0]);
}

// ---------------- merged pre MLP: ALL layers via split-bf16 MFMA ----------------
// 35(->64 pad) -> 128 -> 128 -> 34(->64 pad). 3-term split per layer (~fp32 accuracy).
// A-fragment LDS layout: [32 rows][K halves], 16B chunk c=k>>3 XOR'd with row (mod chunk count).
// LDS: single aliased 16KB bf16 hi/lo buffer pair -> 8 blocks/CU (100% occupancy cap).
#define PR 32
__global__ __launch_bounds__(256) void k_pre_all(const int* __restrict__ cat1, const float* __restrict__ num1,
                                                 const int* __restrict__ cat2, const float* __restrict__ num2,
                                                 const float* __restrict__ emb0, const float* __restrict__ emb1,
                                                 const float* __restrict__ emb2,
                                                 const unsigned short* __restrict__ W1h, const unsigned short* __restrict__ W1l,
                                                 const float* __restrict__ b1,
                                                 const unsigned short* __restrict__ W2h, const unsigned short* __restrict__ W2l,
                                                 const float* __restrict__ b2,
                                                 const unsigned short* __restrict__ W3h, const unsigned short* __restrict__ W3l,
                                                 const float* __restrict__ b3,
                                                 const float* __restrict__ dinv1, const float* __restrict__ dinv2,
                                                 float* __restrict__ X1, float* __restrict__ Xs1,
                                                 float* __restrict__ X2, float* __restrict__ Xs2,
                                                 int nblk1)
{
    __shared__ __align__(16) unsigned short bufh[32 * 128];
    __shared__ __align__(16) unsigned short bufl[32 * 128];
    const int t = threadIdx.x;
    const int wv = t >> 6, ln = t & 63;
    const int mt = wv & 1, wg = wv >> 1;   // M-tile, wave-group
    const int lr = ln & 15, lh = ln >> 4;
    const int gb = blockIdx.x;
    const int g2 = (gb >= nblk1);
    const int* cat = g2 ? cat2 : cat1;
    const float* num = g2 ? num2 : num1;
    const float* dinv = g2 ? dinv2 : dinv1;
    float* X = g2 ? X2 : X1;
    float* Xs = g2 ? Xs2 : Xs1;
    const int base = (g2 ? gb - nblk1 : gb) * PR;

    // ---- stage o as bf16 hi/lo fragments [32][64] (K zero-padded 35->64) ----
    for (int idx = t; idx < 32 * 64; idx += 256) {
        int r = idx >> 6, k = idx & 63;
        float v = 0.f;
        if (k < 16) v = emb0[cat[(base + r) * 3 + 0] * 16 + k];
        else if (k < 24) v = emb1[cat[(base + r) * 3 + 1] * 8 + (k - 16)];
        else if (k < 32) v = emb2[cat[(base + r) * 3 + 2] * 8 + (k - 24)];
        else if (k < 35) v = num[(base + r) * 3 + (k - 32)];
        unsigned short hi = f2bf(v);
        int ho = r * 64 + (((k >> 3) ^ (r & 7)) << 3) + (k & 7);
        bufh[ho] = hi;
        bufl[ho] = f2bf(v - bf2f(hi));
    }
    __syncthreads();

    // ---- layer 1: K=64 (2 ks), 2 mt x 8 nt; wave does nt = wg + 2*j ----
    f32x4 a1[4];
    {
        const int ra = mt * 16 + lr;
        sh8 ah[2], al[2];
#pragma unroll
        for (int ks = 0; ks < 2; ++ks) {
            int off = ra * 64 + ((((ks * 4 + lh)) ^ (ra & 7)) << 3);
            ah[ks] = *(const sh8*)(bufh + off);
            al[ks] = *(const sh8*)(bufl + off);
        }
#pragma unroll
        for (int j = 0; j < 4; ++j) {
            const int nt = wg + 2 * j;
            f32x4 acc = (f32x4){0.f, 0.f, 0.f, 0.f};
#pragma unroll
            for (int ks = 0; ks < 2; ++ks) {
                const int fb = (((nt * 2 + ks) * 64 + ln) << 3);
                sh8 bh = *(const sh8*)(W1h + fb);
                sh8 bl = *(const sh8*)(W1l + fb);
                acc = __builtin_amdgcn_mfma_f32_16x16x32_bf16(ah[ks], bh, acc, 0, 0, 0);
                acc = __builtin_amdgcn_mfma_f32_16x16x32_bf16(ah[ks], bl, acc, 0, 0, 0);
                acc = __builtin_amdgcn_mfma_f32_16x16x32_bf16(al[ks], bh, acc, 0, 0, 0);
            }
            a1[j] = acc;
        }
    }
    __syncthreads();  // all oT reads done
    // ---- L1 epilogue: bias+relu, write h1 fragments [32][128] ----
#pragma unroll
    for (int j = 0; j < 4; ++j) {
        const int f = (wg + 2 * j) * 16 + lr;
        const float bb = b1[f];
#pragma unroll
        for (int reg = 0; reg < 4; ++reg) {
            const int row = mt * 16 + lh * 4 + reg;
            float v = fmaxf(a1[j][reg] + bb, 0.f);
            unsigned short hi = f2bf(v);
            int ho = row * 128 + ((((f >> 3)) ^ (row & 15)) << 3) + (f & 7);
            bufh[ho] = hi;
            bufl[ho] = f2bf(v - bf2f(hi));
        }
    }
    __syncthreads();

    // ---- layer 2: K=128 (4 ks), 2 mt x 8 nt; wave does nt = wg*4 + j ----
    f32x4 a2[4];
#pragma unroll
    for (int j = 0; j < 4; ++j) a2[j] = (f32x4){0.f, 0.f, 0.f, 0.f};
    {
        const int ra = mt * 16 + lr;
#pragma unroll
        for (int ks = 0; ks < 4; ++ks) {
            int off = ra * 128 + (((ks * 4 + lh) ^ lr) << 3);
            sh8 ah = *(const sh8*)(bufh + off);
            sh8 al = *(const sh8*)(bufl + off);
#pragma unroll
            for (int j = 0; j < 4; ++j) {
                const int nt = wg * 4 + j;
                const int fb = (((nt * 4 + ks) * 64 + ln) << 3);
                sh8 bh = *(const sh8*)(W2h + fb);
                sh8 bl = *(const sh8*)(W2l + fb);
                a2[j] = __builtin_amdgcn_mfma_f32_16x16x32_bf16(ah, bh, a2[j], 0, 0, 0);
                a2[j] = __builtin_amdgcn_mfma_f32_16x16x32_bf16(ah, bl, a2[j], 0, 0, 0);
                a2[j] = __builtin_amdgcn_mfma_f32_16x16x32_bf16(al, bh, a2[j], 0, 0, 0);
            }
        }
    }
    __syncthreads();  // all h1 reads done
    // ---- L2 epilogue: bias+relu, write h2 fragments ----
#pragma unroll
    for (int j = 0; j < 4; ++j) {
        const int f = (wg * 4 + j) * 16 + lr;
        const float bb = b2[f];
#pragma unroll
        for (int reg = 0; reg < 4; ++reg) {
            const int row = mt * 16 + lh * 4 + reg;
            float v = fmaxf(a2[j][reg] + bb, 0.f);
            unsigned short hi = f2bf(v);
            int ho = row * 128 + ((((f >> 3)) ^ (row & 15)) << 3) + (f & 7);
            bufh[ho] = hi;
            bufl[ho] = f2bf(v - bf2f(hi));
        }
    }
    __syncthreads();

    // ---- layer 3: K=128 (4 ks), N=64 pad (cols 34-63 zero); wave does nt = wg*2 + j, skip nt==3 ----
    f32x4 a3[2];
    a3[0] = (f32x4){0.f, 0.f, 0.f, 0.f};
    a3[1] = (f32x4){0.f, 0.f, 0.f, 0.f};
    {
        const int ra = mt * 16 + lr;
#pragma unroll
        for (int ks = 0; ks < 4; ++ks) {
            int off = ra * 128 + (((ks * 4 + lh) ^ lr) << 3);
            sh8 ah = *(const sh8*)(bufh + off);
            sh8 al = *(const sh8*)(bufl + off);
#pragma unroll
            for (int j = 0; j < 2; ++j) {
                const int nt = wg * 2 + j;
                if (nt >= 3) continue;
                const int fb = (((nt * 4 + ks) * 64 + ln) << 3);
                sh8 bh = *(const sh8*)(W3h + fb);
                sh8 bl = *(const sh8*)(W3l + fb);
                a3[j] = __builtin_amdgcn_mfma_f32_16x16x32_bf16(ah, bh, a3[j], 0, 0, 0);
                a3[j] = __builtin_amdgcn_mfma_f32_16x16x32_bf16(ah, bl, a3[j], 0, 0, 0);
                a3[j] = __builtin_amdgcn_mfma_f32_16x16x32_bf16(al, bh, a3[j], 0, 0, 0);
            }
        }
    }
    // ---- L3 epilogue: bias, write X and Xs (no relu) ----
#pragma unroll
    for (int j = 0; j < 2; ++j) {
        const int nt = wg * 2 + j;
        if (nt >= 3) continue;
        const int jc = nt * 16 + lr;
        if (jc < 34) {
            const float bb = b3[jc];
#pragma unroll
            for (int reg = 0; reg < 4; ++reg) {
                const int row = mt * 16 + lh * 4 + reg;
                const int gr = base + row;
                float v = a3[j][reg] + bb;
                X[(size_t)gr * 35 + jc] = v;
                Xs[(size_t)gr * 35 + jc] = v * dinv[gr];
            }
        }
    }
    if (t < PR) {
        int row = base + t;
        float v = num[row * 3 + 2];
        X[(size_t)row * 35 + 34] = v;
        Xs[(size_t)row * 35 + 34] = v * dinv[row];
    }
}

// ---------------- plain dense gemm (row-major W: DIN x DOUT), float4 row loads ----------------
template <int DIN, int DOUT, bool BIAS, bool RELU, bool SCALE>
__global__ void k_gemm(const float* __restrict__ Xin, int ldin, const float* __restrict__ W,
                       const float* __restrict__ b, const float* __restrict__ oscale,
                       float* __restrict__ Out, int n)
{
    __shared__ float Ws[DIN * DOUT];
    for (int i = threadIdx.x; i < DIN * DOUT; i += blockDim.x) Ws[i] = W[i];
    __syncthreads();
    int idx = blockIdx.x * blockDim.x + threadIdx.x;
    if (idx >= n * DOUT) return;
    int row = idx / DOUT, j = idx - row * DOUT;
    const float4* xr4 = (const float4*)(Xin + (size_t)row * ldin);
    float acc = BIAS ? b[j] : 0.f;
#pragma unroll
    for (int i4 = 0; i4 < DIN / 4; ++i4) {
        float4 x = xr4[i4];
        acc = fmaf(x.x, Ws[(4 * i4 + 0) * DOUT + j], acc);
        acc = fmaf(x.y, Ws[(4 * i4 + 1) * DOUT + j], acc);
        acc = fmaf(x.z, Ws[(4 * i4 + 2) * DOUT + j], acc);
        acc = fmaf(x.w, Ws[(4 * i4 + 3) * DOUT + j], acc);
    }
    if (RELU) acc = fmaxf(acc, 0.f);
    if (SCALE) acc *= oscale[row];
    Out[idx] = acc;
}

// ---------------- alpha / yh: per-batch kernel regression ----------------
__global__ __launch_bounds__(256) void k_alpha(const float* __restrict__ X1,  // n1 x 34 (g1 out)
                                               const float* __restrict__ X,   // n1 x 35 (y col)
                                               float* __restrict__ X2,        // n2 x 35
                                               float* __restrict__ Xs2,       // n2 x 35 scaled
                                               const float* __restrict__ dinv2,
                                               const float* __restrict__ theta,
                                               const float* __restrict__ A,
                                               const float* __restrict__ scale)
{
    const int b = blockIdx.x;
    const int t = threadIdx.x;
    const int p = t & 63;
    const int w = t >> 6;
    __shared__ float th[34 * 34];
    __shared__ float xpS[64 * 35];
    __shared__ float xfS[16 * 34];
    __shared__ float UfS[16 * 34];
    __shared__ float upPart[4][64];
    __shared__ float upS[64];
    __shared__ float yS[64];

    for (int i = t; i < 34 * 34; i += 256) th[i] = theta[i];
    for (int i = t; i < 64 * 34; i += 256) {
        int r = i / 34, o = i - 34 * r;
        xpS[r * 35 + o] = X1[(size_t)(b * 64 + r) * 34 + o];
    }
    for (int i = t; i < 16 * 34; i += 256) {
        int q = i / 34, o = i - 34 * q;
        xfS[i] = X2[(size_t)(b * 16 + q) * 35 + o];
    }
    if (t < 64) yS[t] = X[(size_t)(b * 64 + t) * 35 + 34];
    __syncthreads();

    for (int i = t; i < 16 * 34; i += 256) {
        int q = i / 34, o = i - 34 * q;
        float a = 0.f;
#pragma unroll
        for (int O = 0; O < 34; ++O) a = fmaf(th[o * 34 + O], xfS[q * 34 + O], a);
        UfS[i] = a;
    }
    {
        const int o0 = w * 9;
        const int o1 = (o0 + 9 < 34) ? o0 + 9 : 34;
        float a = 0.f;
        for (int o = o0; o < o1; ++o) {
            float s2 = 0.f;
#pragma unroll
            for (int O = 0; O < 34; ++O) s2 = fmaf(th[o * 34 + O], xpS[p * 35 + O], s2);
            a = fmaf(xpS[p * 35 + o], s2, a);
        }
        upPart[w][p] = a;
    }
    __syncthreads();
    if (t < 64) upS[t] = upPart[0][t] + upPart[1][t] + upPart[2][t] + upPart[3][t];
    __syncthreads();

    const float sc = scale[0];
    const float up = upS[p];
    const float y = yS[p];
#pragma unroll
    for (int i = 0; i < 4; ++i) {
        const int q = w + 4 * i;
        float g = 0.f;
#pragma unroll
        for (int o = 0; o < 34; ++o) g = fmaf(UfS[q * 34 + o], xpS[p * 35 + o], g);
        float a = sc * (up - 2.f * g);
        if (A[(PASTN + q) * NN + p] == 0.f) a = -INFINITY;
        float mx = a;
#pragma unroll
        for (int off = 32; off > 0; off >>= 1) mx = fmaxf(mx, __shfl_xor(mx, off));
        float e = expf(a - mx);
        float s = e;
#pragma unroll
        for (int off = 32; off > 0; off >>= 1) s += __shfl_xor(s, off);
        float c = (e / s) * y;
#pragma unroll
        for (int off = 32; off > 0; off >>= 1) c += __shfl_xor(c, off);
        if (p == 0) {
            size_t ridx = (size_t)(b * 16 + q);
            X2[ridx * 35 + 34] = c;
            Xs2[ridx * 35 + 34] = c * dinv2[ridx];
        }
    }
}

// ---------------- pairwise distances: 5x5 register tiles, pitch 44 ----------------
__global__ __launch_bounds__(256) void k_cd(const float* __restrict__ X, const float* __restrict__ X2,
                                            float* __restrict__ cd)
{
    const int b = blockIdx.x;
    const int t = threadIdx.x;
    __shared__ float xa[80 * 44];
    __shared__ float sq[80];
    for (int idx = t; idx < 80 * 44; idx += 256) {
        int nrow = idx / 44, k = idx - 44 * nrow;
        float v = 0.f;
        if (k < 35)
            v = (nrow < 64) ? X[(size_t)(b * 64 + nrow) * 35 + k]
                            : X2[(size_t)(b * 16 + (nrow - 64)) * 35 + k];
        xa[idx] = v;
    }
    __syncthreads();
    const float4* xa4 = (const float4*)xa;
    if (t < 80) {
        float acc = 0.f;
#pragma unroll
        for (int c = 0; c < 9; ++c) {
            float4 v = xa4[t * 11 + c];
            acc = fmaf(v.x, v.x, fmaf(v.y, v.y, fmaf(v.z, v.z, fmaf(v.w, v.w, acc))));
        }
        sq[t] = acc;
    }
    __syncthreads();
    const int ti = t >> 4;
    const int tj = t & 15;
    float dot[5][5];
#pragma unroll
    for (int r = 0; r < 5; ++r)
#pragma unroll
        for (int c = 0; c < 5; ++c) dot[r][c] = 0.f;
#pragma unroll
    for (int ch = 0; ch < 9; ++ch) {
        float4 av[5], bv[5];
#pragma unroll
        for (int r = 0; r < 5; ++r) av[r] = xa4[(5 * ti + r) * 11 + ch];
#pragma unroll
        for (int c = 0; c < 5; ++c) bv[c] = xa4[(5 * tj + c) * 11 + ch];
#pragma unroll
        for (int r = 0; r < 5; ++r)
#pragma unroll
            for (int c = 0; c < 5; ++c)
                dot[r][c] = fmaf(av[r].x, bv[c].x, fmaf(av[r].y, bv[c].y,
                              fmaf(av[r].z, bv[c].z, fmaf(av[r].w, bv[c].w, dot[r][c]))));
    }
    float* out = cd + (size_t)b * 6400;
#pragma unroll
    for (int r = 0; r < 5; ++r) {
        int n_ = 5 * ti + r;
        float sn = sq[n_];
#pragma unroll
        for (int c = 0; c < 5; ++c) {
            int m = 5 * tj + c;
            float d2 = sn + sq[m] - 2.f * dot[r][c];
            out[n_ * 80 + m] = sqrtf(fmaxf(d2, 0.f));
        }
    }
}

extern "C" void kernel_launch(void* const* d_in, const int* in_sizes, int n_in,
                              void* d_out, int out_size, void* d_ws, size_t ws_size,
                              hipStream_t stream)
{
    const int* x1_cat = (const int*)d_in[0];
    const float* x1_num = (const float*)d_in[1];
    const int* x2_cat = (const int*)d_in[2];
    const float* x2_num = (const float*)d_in[3];
    const int* e1 = (const int*)d_in[4];
    const int* e2 = (const int*)d_in[5];
    const float* emb0 = (const float*)d_in[6];
    const float* emb1 = (const float*)d_in[7];
    const float* emb2 = (const float*)d_in[8];
    const float* pW1 = (const float*)d_in[9];
    const float* pb1 = (const float*)d_in[10];
    const float* pW2 = (const float*)d_in[11];
    const float* pb2 = (const float*)d_in[12];
    const float* pW3 = (const float*)d_in[13];
    const float* pb3 = (const float*)d_in[14];
    const float* g1W1 = (const float*)d_in[15];
    const float* g1b1 = (const float*)d_in[16];
    const float* g1W2 = (const float*)d_in[17];
    const float* g1b2 = (const float*)d_in[18];
    const float* g2W1 = (const float*)d_in[19];
    const float* g2b1 = (const float*)d_in[20];
    const float* g2W2 = (const float*)d_in[21];
    const float* g2b2 = (const float*)d_in[22];
    const float* kerW = (const float*)d_in[23];
    const float* smoothing = (const float*)d_in[24];
    const float* M = (const float*)d_in[25];

    const int n1 = in_sizes[0] / 3;
    const int n2 = in_sizes[2] / 3;
    const int E1 = in_sizes[4] / 2;
    const int E2 = in_sizes[5] / 2;
    const int SBc = n2 / FUTN;

    float* w = (float*)d_ws;
    size_t off = 0;
    float* scale = w + off; off += 16;
    float* theta = w + off; off += 1184;
    float* Aws = w + off; off += 6400;
    float* X = w + off; off += (size_t)n1 * 35;
    float* Xs1 = w + off; off += (size_t)n1 * 35;
    float* X2 = w + off; off += (size_t)n2 * 35;
    float* Xs2 = w + off; off += (size_t)n2 * 35;
    float* dinv1 = w + off; off += (size_t)n1;
    float* dinv2 = w + off; off += (size_t)n2;
    float* B2 = w + off; off += (size_t)n1 * 64;
    float* B3 = w + off; off += (size_t)n1 * 34;
    float* B4 = w + off; off += (size_t)n1 * 34;
    off = (off + 3) & ~(size_t)3;  // 16B align for bf16 fragment arrays
    unsigned short* W1fh = (unsigned short*)(w + off); off += 4096;   // 8192 halves
    unsigned short* W1fl = (unsigned short*)(w + off); off += 4096;
    unsigned short* W2fh = (unsigned short*)(w + off); off += 8192;   // 16384 halves
    unsigned short* W2fl = (unsigned short*)(w + off); off += 8192;
    unsigned short* W3fh = (unsigned short*)(w + off); off += 4096;   // 8192 halves
    unsigned short* W3fl = (unsigned short*)(w + off); off += 4096;
    int* iw = (int*)(w + off);
    size_t ioff = 0;
    int* degi1 = iw + ioff; ioff += n1;
    int* degi2 = iw + ioff; ioff += n2;
    int* rs1 = iw + ioff; ioff += n1;
    int* cur1 = iw + ioff; ioff += n1;
    int* srcs1 = iw + ioff; ioff += E1;
    int* rs2 = iw + ioff; ioff += n2;
    int* cur2 = iw + ioff; ioff += n2;
    int* srcs2 = iw + ioff; ioff += E2;
    int* bsumA = iw + ioff; ioff += 1024;
    int* bsumB = iw + ioff; ioff += 1024;

    float* out_f = (float*)d_out;
    float* cd_f = out_f + (size_t)SBc * FUTN;
    float* A_out = cd_f + (size_t)SBc * NN * NN;

    auto cdiv = [](long long a, long long b) { return (unsigned)((a + b - 1) / b); };

    // ---- degrees + CSR build (merged kernels) ----
    hipMemsetAsync(degi1, 0, ((size_t)n1 + n2) * 4, stream);
    k_setup<<<1, 256, 0, stream>>>(M, kerW, smoothing, Aws, A_out, theta, scale);
    k_wconv<<<128, 256, 0, stream>>>(pW1, pW2, pW3, W1fh, W1fl, W2fh, W2fl, W3fh, W3fl);

    const int nbe1 = cdiv(E1, 256), nbe2 = cdiv(E2, 256);
    k_deg2<<<nbe1 + nbe2, 256, 0, stream>>>(e1 + E1, e2 + E2, degi1, degi2, E1, E2, nbe1);

    const int nb1 = cdiv(n1, SCHUNK), nb2 = cdiv(n2, SCHUNK);
    k_scan_reduce2<<<nb1 + nb2, 256, 0, stream>>>(degi1, degi2, bsumA, bsumB, n1, n2, nb1);
    k_scan_mid2<<<2, 1024, 0, stream>>>(bsumA, bsumB, nb1, nb2);
    k_scan_final2<<<nb1 + nb2, 256, 0, stream>>>(degi1, degi2, bsumA, bsumB, rs1, rs2, cur1, cur2,
                                                 dinv1, dinv2, n1, n2, nb1);
    k_fill2<<<nbe1 + nbe2, 256, 0, stream>>>(e1, e1 + E1, e2, e2 + E2, cur1, cur2, srcs1, srcs2, E1, E2, nbe1);

    // ---- pre MLP, both node sets in one dispatch (all layers MFMA split-bf16) ----
    k_pre_all<<<n1 / PR + n2 / PR, 256, 0, stream>>>(x1_cat, x1_num, x2_cat, x2_num,
                                                     emb0, emb1, emb2,
                                                     W1fh, W1fl, pb1, W2fh, W2fl, pb2, W3fh, W3fl, pb3,
                                                     dinv1, dinv2, X, Xs1, X2, Xs2, n1 / PR);

    // ---- g1 layer 1: fused pull(35, scaled)+gemm(35->64)+relu ----
    k_gcn_s<35><<<cdiv(n1, 4), 256, 0, stream>>>(rs1, degi1, srcs1, dinv1, Xs1, g1W1, g1b1, B2, n1);

    // ---- g1 layer 2: gemm 64->34 (output pre-scaled by dinv1) then fused pull+combine ----
    k_gemm<64, 34, false, false, true><<<cdiv((long long)n1 * 34, 256), 256, 0, stream>>>(B2, 64, g1W2, nullptr, dinv1, B3, n1);
    k_pcomb_s<34><<<cdiv(n1, 4), 256, 0, stream>>>(rs1, degi1, srcs1, dinv1, B3, g1b2, B4, n1);

    // ---- alpha / yh -> X2 col 34 (+ scaled copy) ----
    k_alpha<<<SBc, 256, 0, stream>>>(B4, X, X2, Xs2, dinv2, theta, Aws, scale);

    // ---- g2 layer 1 ----
    k_gcn_s<35><<<cdiv(n2, 4), 256, 0, stream>>>(rs2, degi2, srcs2, dinv2, Xs2, g2W1, g2b1, B2, n2);

    // ---- g2 layer 2: gemm 64->1 (pre-scaled), fused pull+combine ----
    k_gemm<64, 1, false, false, true><<<cdiv(n2, 256), 256, 0, stream>>>(B2, 64, g2W2, nullptr, dinv2, B3, n2);
    k_pcomb1_s<<<cdiv(n2, 256), 256, 0, stream>>>(rs2, degi2, srcs2, dinv2, B3, g2b2, out_f, n2);

    // ---- pairwise distances ----
    k_cd<<<SBc, 256, 0, stream>>>(X, X2, cd_f);
}

// Round 10
// 653.584 us; speedup vs baseline: 2.2544x; 1.0272x over previous
//
#include <hip/hip_runtime.h>
#include <math.h>

#define PASTN 64
#define FUTN 16
#define NN 80

typedef __attribute__((ext_vector_type(8))) short sh8;
typedef __attribute__((ext_vector_type(4))) float f32x4;

__device__ __forceinline__ unsigned short f2bf(float f) {
    unsigned int u = __float_as_uint(f);
    return (unsigned short)((u + 0x7FFFu + ((u >> 16) & 1u)) >> 16);
}
__device__ __forceinline__ float bf2f(unsigned short s) {
    return __uint_as_float(((unsigned int)s) << 16);
}

// ---------------- merged init: setup (1 blk) + wconv (128 blks) + deg count ----------------
__global__ __launch_bounds__(256) void k_init(const float* __restrict__ M, const float* __restrict__ kerW,
                                              const float* __restrict__ smoothing,
                                              float* __restrict__ A_ws, float* __restrict__ A_out,
                                              float* __restrict__ theta, float* __restrict__ scale,
                                              const float* __restrict__ W1, const float* __restrict__ W2,
                                              const float* __restrict__ W3,
                                              unsigned short* __restrict__ W1h, unsigned short* __restrict__ W1l,
                                              unsigned short* __restrict__ W2h, unsigned short* __restrict__ W2l,
                                              unsigned short* __restrict__ W3h, unsigned short* __restrict__ W3l,
                                              const int* __restrict__ dst1, const int* __restrict__ dst2,
                                              int* __restrict__ deg1, int* __restrict__ deg2,
                                              int E1, int E2, int nbe1)
{
    __shared__ float Ms[80 * 26];
    __shared__ float Ar[80 * 80];
    const int bid = blockIdx.x;
    const int t = threadIdx.x;
    if (bid == 0) {
        // ---- setup: A, theta, scale ----
        for (int i = t; i < 80 * 26; i += 256) Ms[i] = M[i];
        __syncthreads();
        for (int idx = t; idx < 6400; idx += 256) {
            int i = idx / 80, j = idx - 80 * i;
            float acc = 0.f;
#pragma unroll
            for (int k = 0; k < 26; ++k) acc = fmaf(Ms[i * 26 + k], Ms[j * 26 + k], acc);
            Ar[idx] = fmaxf(acc, 0.f);
        }
        __syncthreads();
        if (t < 80) {
            float mx = -1e30f;
            for (int j = 0; j <= t; ++j) mx = fmaxf(mx, Ar[t * 80 + j]);
            float s = 0.f;
            for (int j = 0; j <= t; ++j) s += expf(Ar[t * 80 + j] - mx);
            float inv = 1.f / s;
            for (int j = 0; j < 80; ++j) {
                float v = (j <= t) ? expf(Ar[t * 80 + j] - mx) * inv : 0.f;
                A_ws[t * 80 + j] = v;
                A_out[t * 80 + j] = v;
            }
        }
        for (int idx = t; idx < 34 * 34; idx += 256) {
            int i = idx / 34, j = idx - 34 * i;
            float acc = 0.f;
            for (int k = 0; k < 128; ++k) acc = fmaf(kerW[i * 128 + k], kerW[j * 128 + k], acc);
            theta[idx] = acc;
        }
        if (t == 0) {
            float s0 = smoothing[0];
            float sig = 1.f / (1.f + expf(-s0));
            scale[0] = -0.5f / (sig * 0.01f);
        }
    } else if (bid <= 128) {
        // ---- wconv: W1/W2/W3 -> fragment bf16 hi/lo ----
        int g = (bid - 1) * 256 + t;  // 0..32767
        float w;
        unsigned short *dh, *dl;
        int gi;
        if (g < 8192) {
            gi = g;
            int i = gi & 7, l = (gi >> 3) & 63, ks = (gi >> 9) & 1, nt = gi >> 10;
            int col = nt * 16 + (l & 15);
            int k = ks * 32 + ((l >> 4) << 3) + i;
            w = (k < 35) ? W1[k * 128 + col] : 0.f;
            dh = W1h; dl = W1l;
        } else if (g < 24576) {
            gi = g - 8192;
            int i = gi & 7, l = (gi >> 3) & 63, ks = (gi >> 9) & 3, nt = gi >> 11;
            int col = nt * 16 + (l & 15);
            int k = ks * 32 + ((l >> 4) << 3) + i;
            w = W2[k * 128 + col];
            dh = W2h; dl = W2l;
        } else {
            gi = g - 24576;
            int i = gi & 7, l = (gi >> 3) & 63, ks = (gi >> 9) & 3, nt = gi >> 11;
            int col = nt * 16 + (l & 15);
            int k = ks * 32 + ((l >> 4) << 3) + i;
            w = (col < 34) ? W3[k * 34 + col] : 0.f;
            dh = W3h; dl = W3l;
        }
        unsigned short hi = f2bf(w);
        dh[gi] = hi;
        dl[gi] = f2bf(w - bf2f(hi));
    } else {
        // ---- degree count ----
        int fb = bid - 129;
        if (fb < nbe1) {
            int e = fb * 256 + t;
            if (e < E1) atomicAdd(&deg1[dst1[e]], 1);
        } else {
            int e = (fb - nbe1) * 256 + t;
            if (e < E2) atomicAdd(&deg2[dst2[e]], 1);
        }
    }
}

// ---------------- merged exclusive scan, chunk = 1024 ----------------
#define SCHUNK 1024
__global__ __launch_bounds__(256) void k_scan_reduce2(const int* __restrict__ deg1, const int* __restrict__ deg2,
                                                      int* __restrict__ bsumA, int* __restrict__ bsumB,
                                                      int n1, int n2, int nb1)
{
    __shared__ int sd[256];
    const int gb = blockIdx.x, t = threadIdx.x;
    const int which = (gb < nb1) ? 0 : 1;
    const int b = which ? gb - nb1 : gb;
    const int* deg = which ? deg2 : deg1;
    const int n = which ? n2 : n1;
    const int base = b * SCHUNK;
    int s = 0;
#pragma unroll
    for (int j = 0; j < 4; ++j) {
        int i = base + t + j * 256;
        if (i < n) s += deg[i];
    }
    sd[t] = s;
    __syncthreads();
    for (int o = 128; o > 0; o >>= 1) {
        if (t < o) sd[t] += sd[t + o];
        __syncthreads();
    }
    if (t == 0) (which ? bsumB : bsumA)[b] = sd[0];
}

__global__ __launch_bounds__(1024) void k_scan_mid2(int* __restrict__ bsumA, int* __restrict__ bsumB,
                                                    int nbA, int nbB)
{
    __shared__ int sd[1024];
    const int t = threadIdx.x;
    int* bsum = (blockIdx.x == 0) ? bsumA : bsumB;
    int nb = (blockIdx.x == 0) ? nbA : nbB;
    int orig = (t < nb) ? bsum[t] : 0;
    sd[t] = orig;
    __syncthreads();
    for (int o = 1; o < 1024; o <<= 1) {
        int v = (t >= o) ? sd[t - o] : 0;
        __syncthreads();
        sd[t] += v;
        __syncthreads();
    }
    if (t < nb) bsum[t] = sd[t] - orig;  // exclusive
}

// final scan; also writes cur (copy of rs) and dinv = rsqrt(1+deg)
__global__ __launch_bounds__(256) void k_scan_final2(const int* __restrict__ deg1, const int* __restrict__ deg2,
                                                     const int* __restrict__ bsumA, const int* __restrict__ bsumB,
                                                     int* __restrict__ rs1, int* __restrict__ rs2,
                                                     int* __restrict__ cur1, int* __restrict__ cur2,
                                                     float* __restrict__ dinv1, float* __restrict__ dinv2,
                                                     int n1, int n2, int nb1)
{
    __shared__ int sd[256];
    const int gb = blockIdx.x, t = threadIdx.x;
    const int which = (gb < nb1) ? 0 : 1;
    const int b = which ? gb - nb1 : gb;
    const int* deg = which ? deg2 : deg1;
    const int* bsum = which ? bsumB : bsumA;
    int* rs = which ? rs2 : rs1;
    int* cur = which ? cur2 : cur1;
    float* dinv = which ? dinv2 : dinv1;
    const int n = which ? n2 : n1;
    const int base = b * SCHUNK + t * 4;
    int v0 = (base + 0 < n) ? deg[base + 0] : 0;
    int v1 = (base + 1 < n) ? deg[base + 1] : 0;
    int v2 = (base + 2 < n) ? deg[base + 2] : 0;
    int v3 = (base + 3 < n) ? deg[base + 3] : 0;
    int tsum = v0 + v1 + v2 + v3;
    sd[t] = tsum;
    __syncthreads();
    int incl = tsum;
    for (int o = 1; o < 256; o <<= 1) {
        int v = (t >= o) ? sd[t - o] : 0;
        __syncthreads();
        incl += v;
        sd[t] = incl;
        __syncthreads();
    }
    int off = bsum[b] + incl - tsum;
    if (base + 0 < n) { rs[base + 0] = off;            cur[base + 0] = off;            dinv[base + 0] = rsqrtf(1.f + (float)v0); }
    if (base + 1 < n) { rs[base + 1] = off + v0;       cur[base + 1] = off + v0;       dinv[base + 1] = rsqrtf(1.f + (float)v1); }
    if (base + 2 < n) { rs[base + 2] = off + v0 + v1;  cur[base + 2] = off + v0 + v1;  dinv[base + 2] = rsqrtf(1.f + (float)v2); }
    if (base + 3 < n) { rs[base + 3] = off + v0 + v1 + v2; cur[base + 3] = off + v0 + v1 + v2; dinv[base + 3] = rsqrtf(1.f + (float)v3); }
}

// ---------------- merged CSR fill + pre MLP (interleaved blocks) ----------------
// Fill is HBM-write-amp latency-bound (0.35% VALU); pre is MFMA/VALU-bound -> co-schedule.
#define PR 32
__global__ __launch_bounds__(256) void k_fillpre(
    // fill
    const int* __restrict__ src1, const int* __restrict__ dst1,
    const int* __restrict__ src2, const int* __restrict__ dst2,
    int* __restrict__ cur1, int* __restrict__ cur2,
    int* __restrict__ out1, int* __restrict__ out2,
    int E1, int E2, int nbe1, int nfill,
    // pre
    const int* __restrict__ cat1, const float* __restrict__ num1,
    const int* __restrict__ cat2, const float* __restrict__ num2,
    const float* __restrict__ emb0, const float* __restrict__ emb1, const float* __restrict__ emb2,
    const unsigned short* __restrict__ W1h, const unsigned short* __restrict__ W1l,
    const float* __restrict__ b1,
    const unsigned short* __restrict__ W2h, const unsigned short* __restrict__ W2l,
    const float* __restrict__ b2,
    const unsigned short* __restrict__ W3h, const unsigned short* __restrict__ W3l,
    const float* __restrict__ b3,
    const float* __restrict__ dinv1, const float* __restrict__ dinv2,
    float* __restrict__ X1, float* __restrict__ Xs1,
    float* __restrict__ X2, float* __restrict__ Xs2,
    int nblk1, int npre)
{
    __shared__ __align__(16) unsigned short bufh[32 * 128];
    __shared__ __align__(16) unsigned short bufl[32 * 128];
    const int bid = blockIdx.x;
    const int t = threadIdx.x;
    // interleave mapping
    const int m = (npre < nfill) ? npre : nfill;
    int pre_id = -1, fill_id = -1;
    if (bid < 2 * m) {
        if (bid & 1) fill_id = bid >> 1; else pre_id = bid >> 1;
    } else {
        if (npre > nfill) pre_id = bid - nfill; else fill_id = bid - npre;
    }

    if (fill_id >= 0) {
        if (fill_id < nbe1) {
            int e = fill_id * 256 + t;
            if (e < E1) { int pos = atomicAdd(&cur1[dst1[e]], 1); out1[pos] = src1[e]; }
        } else {
            int e = (fill_id - nbe1) * 256 + t;
            if (e < E2) { int pos = atomicAdd(&cur2[dst2[e]], 1); out2[pos] = src2[e]; }
        }
        return;
    }

    // ---- pre MLP: 35(->64) -> 128 -> 128 -> 34(->64) all MFMA split-bf16 ----
    const int wv = t >> 6, ln = t & 63;
    const int mt = wv & 1, wg = wv >> 1;
    const int lr = ln & 15, lh = ln >> 4;
    const int g2 = (pre_id >= nblk1);
    const int* cat = g2 ? cat2 : cat1;
    const float* num = g2 ? num2 : num1;
    const float* dinv = g2 ? dinv2 : dinv1;
    float* X = g2 ? X2 : X1;
    float* Xs = g2 ? Xs2 : Xs1;
    const int base = (g2 ? pre_id - nblk1 : pre_id) * PR;

    for (int idx = t; idx < 32 * 64; idx += 256) {
        int r = idx >> 6, k = idx & 63;
        float v = 0.f;
        if (k < 16) v = emb0[cat[(base + r) * 3 + 0] * 16 + k];
        else if (k < 24) v = emb1[cat[(base + r) * 3 + 1] * 8 + (k - 16)];
        else if (k < 32) v = emb2[cat[(base + r) * 3 + 2] * 8 + (k - 24)];
        else if (k < 35) v = num[(base + r) * 3 + (k - 32)];
        unsigned short hi = f2bf(v);
        int ho = r * 64 + (((k >> 3) ^ (r & 7)) << 3) + (k & 7);
        bufh[ho] = hi;
        bufl[ho] = f2bf(v - bf2f(hi));
    }
    __syncthreads();

    // layer 1
    f32x4 a1[4];
    {
        const int ra = mt * 16 + lr;
        sh8 ah[2], al[2];
#pragma unroll
        for (int ks = 0; ks < 2; ++ks) {
            int off = ra * 64 + ((((ks * 4 + lh)) ^ (ra & 7)) << 3);
            ah[ks] = *(const sh8*)(bufh + off);
            al[ks] = *(const sh8*)(bufl + off);
        }
#pragma unroll
        for (int j = 0; j < 4; ++j) {
            const int nt = wg + 2 * j;
            f32x4 acc = (f32x4){0.f, 0.f, 0.f, 0.f};
#pragma unroll
            for (int ks = 0; ks < 2; ++ks) {
                const int fb = (((nt * 2 + ks) * 64 + ln) << 3);
                sh8 bh = *(const sh8*)(W1h + fb);
                sh8 bl = *(const sh8*)(W1l + fb);
                acc = __builtin_amdgcn_mfma_f32_16x16x32_bf16(ah[ks], bh, acc, 0, 0, 0);
                acc = __builtin_amdgcn_mfma_f32_16x16x32_bf16(ah[ks], bl, acc, 0, 0, 0);
                acc = __builtin_amdgcn_mfma_f32_16x16x32_bf16(al[ks], bh, acc, 0, 0, 0);
            }
            a1[j] = acc;
        }
    }
    __syncthreads();
#pragma unroll
    for (int j = 0; j < 4; ++j) {
        const int f = (wg + 2 * j) * 16 + lr;
        const float bb = b1[f];
#pragma unroll
        for (int reg = 0; reg < 4; ++reg) {
            const int row = mt * 16 + lh * 4 + reg;
            float v = fmaxf(a1[j][reg] + bb, 0.f);
            unsigned short hi = f2bf(v);
            int ho = row * 128 + ((((f >> 3)) ^ (row & 15)) << 3) + (f & 7);
            bufh[ho] = hi;
            bufl[ho] = f2bf(v - bf2f(hi));
        }
    }
    __syncthreads();

    // layer 2
    f32x4 a2[4];
#pragma unroll
    for (int j = 0; j < 4; ++j) a2[j] = (f32x4){0.f, 0.f, 0.f, 0.f};
    {
        const int ra = mt * 16 + lr;
#pragma unroll
        for (int ks = 0; ks < 4; ++ks) {
            int off = ra * 128 + (((ks * 4 + lh) ^ lr) << 3);
            sh8 ah = *(const sh8*)(bufh + off);
            sh8 al = *(const sh8*)(bufl + off);
#pragma unroll
            for (int j = 0; j < 4; ++j) {
                const int nt = wg * 4 + j;
                const int fb = (((nt * 4 + ks) * 64 + ln) << 3);
                sh8 bh = *(const sh8*)(W2h + fb);
                sh8 bl = *(const sh8*)(W2l + fb);
                a2[j] = __builtin_amdgcn_mfma_f32_16x16x32_bf16(ah, bh, a2[j], 0, 0, 0);
                a2[j] = __builtin_amdgcn_mfma_f32_16x16x32_bf16(ah, bl, a2[j], 0, 0, 0);
                a2[j] = __builtin_amdgcn_mfma_f32_16x16x32_bf16(al, bh, a2[j], 0, 0, 0);
            }
        }
    }
    __syncthreads();
#pragma unroll
    for (int j = 0; j < 4; ++j) {
        const int f = (wg * 4 + j) * 16 + lr;
        const float bb = b2[f];
#pragma unroll
        for (int reg = 0; reg < 4; ++reg) {
            const int row = mt * 16 + lh * 4 + reg;
            float v = fmaxf(a2[j][reg] + bb, 0.f);
            unsigned short hi = f2bf(v);
            int ho = row * 128 + ((((f >> 3)) ^ (row & 15)) << 3) + (f & 7);
            bufh[ho] = hi;
            bufl[ho] = f2bf(v - bf2f(hi));
        }
    }
    __syncthreads();

    // layer 3
    f32x4 a3[2];
    a3[0] = (f32x4){0.f, 0.f, 0.f, 0.f};
    a3[1] = (f32x4){0.f, 0.f, 0.f, 0.f};
    {
        const int ra = mt * 16 + lr;
#pragma unroll
        for (int ks = 0; ks < 4; ++ks) {
            int off = ra * 128 + (((ks * 4 + lh) ^ lr) << 3);
            sh8 ah = *(const sh8*)(bufh + off);
            sh8 al = *(const sh8*)(bufl + off);
#pragma unroll
            for (int j = 0; j < 2; ++j) {
                const int nt = wg * 2 + j;
                if (nt >= 3) continue;
                const int fb = (((nt * 4 + ks) * 64 + ln) << 3);
                sh8 bh = *(const sh8*)(W3h + fb);
                sh8 bl = *(const sh8*)(W3l + fb);
                a3[j] = __builtin_amdgcn_mfma_f32_16x16x32_bf16(ah, bh, a3[j], 0, 0, 0);
                a3[j] = __builtin_amdgcn_mfma_f32_16x16x32_bf16(ah, bl, a3[j], 0, 0, 0);
                a3[j] = __builtin_amdgcn_mfma_f32_16x16x32_bf16(al, bh, a3[j], 0, 0, 0);
            }
        }
    }
#pragma unroll
    for (int j = 0; j < 2; ++j) {
        const int nt = wg * 2 + j;
        if (nt >= 3) continue;
        const int jc = nt * 16 + lr;
        if (jc < 34) {
            const float bb = b3[jc];
#pragma unroll
            for (int reg = 0; reg < 4; ++reg) {
                const int row = mt * 16 + lh * 4 + reg;
                const int gr = base + row;
                float v = a3[j][reg] + bb;
                X[(size_t)gr * 35 + jc] = v;
                Xs[(size_t)gr * 35 + jc] = v * dinv[gr];
            }
        }
    }
    if (t < PR) {
        int row = base + t;
        float v = num[row * 3 + 2];
        X[(size_t)row * 35 + 34] = v;
        Xs[(size_t)row * 35 + 34] = v * dinv[row];
    }
}

// ---------------- fused GCN layer pair: pull(DIN) + gemm(DIN->64)+relu + gemm(64->DOUT2)*di ----------------
// Hs rows pre-scaled by dinv[src]; output B3 rows pre-scaled by dinv[row] (feeds next pull).
template <int DIN, int DOUT2>
__device__ __forceinline__ void gcn_body(int row, int w, int lane,
                                         const int* __restrict__ rs, const int* __restrict__ deg,
                                         const int* __restrict__ srcs, const float* __restrict__ dinv,
                                         const float* __restrict__ Hs, const float* __restrict__ W1,
                                         const float* __restrict__ b1, const float* __restrict__ W2,
                                         float* __restrict__ B3,
                                         float (*ag)[DIN], float (*rg)[64])
{
    const float di = dinv[row];
    const int e0 = rs[row];
    const int d = deg[row];
    float acc = (lane < DIN) ? Hs[(size_t)row * DIN + lane] : 0.f;
    int e = 0;
    for (; e + 8 <= d; e += 8) {
        int s0 = srcs[e0 + e + 0], s1 = srcs[e0 + e + 1], s2 = srcs[e0 + e + 2], s3 = srcs[e0 + e + 3];
        int s4 = srcs[e0 + e + 4], s5 = srcs[e0 + e + 5], s6 = srcs[e0 + e + 6], s7 = srcs[e0 + e + 7];
        float h0 = 0.f, h1 = 0.f, h2 = 0.f, h3 = 0.f, h4 = 0.f, h5 = 0.f, h6 = 0.f, h7 = 0.f;
        if (lane < DIN) {
            h0 = Hs[(size_t)s0 * DIN + lane]; h1 = Hs[(size_t)s1 * DIN + lane];
            h2 = Hs[(size_t)s2 * DIN + lane]; h3 = Hs[(size_t)s3 * DIN + lane];
            h4 = Hs[(size_t)s4 * DIN + lane]; h5 = Hs[(size_t)s5 * DIN + lane];
            h6 = Hs[(size_t)s6 * DIN + lane]; h7 = Hs[(size_t)s7 * DIN + lane];
        }
        acc += ((h0 + h1) + (h2 + h3)) + ((h4 + h5) + (h6 + h7));
    }
    for (; e + 4 <= d; e += 4) {
        int s0 = srcs[e0 + e + 0], s1 = srcs[e0 + e + 1], s2 = srcs[e0 + e + 2], s3 = srcs[e0 + e + 3];
        float h0 = 0.f, h1 = 0.f, h2 = 0.f, h3 = 0.f;
        if (lane < DIN) {
            h0 = Hs[(size_t)s0 * DIN + lane]; h1 = Hs[(size_t)s1 * DIN + lane];
            h2 = Hs[(size_t)s2 * DIN + lane]; h3 = Hs[(size_t)s3 * DIN + lane];
        }
        acc += (h0 + h1) + (h2 + h3);
    }
    for (; e < d; ++e) {
        int s = srcs[e0 + e];
        if (lane < DIN) acc += Hs[(size_t)s * DIN + lane];
    }
    if (lane < DIN) ag[w][lane] = acc;
    __syncthreads();
    float o = 0.f;
#pragma unroll
    for (int i = 0; i < DIN; ++i) o = fmaf(ag[w][i], W1[i * 64 + lane], o);
    float r = fmaxf(fmaf(di, o, b1[lane]), 0.f);
    rg[w][lane] = r;
    __syncthreads();
    if (DOUT2 == 1) {
        float v = r * W2[lane];
#pragma unroll
        for (int off = 32; off > 0; off >>= 1) v += __shfl_xor(v, off);
        if (lane == 0) B3[row] = v * di;
    } else {
        if (lane < DOUT2) {
            float tacc = 0.f;
#pragma unroll
            for (int i = 0; i < 64; ++i) tacc = fmaf(rg[w][i], W2[i * DOUT2 + lane], tacc);
            B3[(size_t)row * DOUT2 + lane] = tacc * di;
        }
    }
}

template <int DIN, int DOUT2>
__global__ __launch_bounds__(256) void k_gcn_f(const int* __restrict__ rs, const int* __restrict__ deg,
                                               const int* __restrict__ srcs, const float* __restrict__ dinv,
                                               const float* __restrict__ Hs, const float* __restrict__ W1,
                                               const float* __restrict__ b1, const float* __restrict__ W2,
                                               float* __restrict__ B3, int n)
{
    __shared__ float ag[4][DIN];
    __shared__ float rg[4][64];
    const int w = threadIdx.x >> 6, lane = threadIdx.x & 63;
    const int row = blockIdx.x * 4 + w;
    gcn_body<DIN, DOUT2>(row, w, lane, rs, deg, srcs, dinv, Hs, W1, b1, W2, B3, ag, rg);
}

// ---------------- merged g2 GCN (fused) + pairwise distances ----------------
__global__ __launch_bounds__(256) void k_g2cd(const int* __restrict__ rs, const int* __restrict__ deg,
                                              const int* __restrict__ srcs, const float* __restrict__ dinv,
                                              const float* __restrict__ Hs, const float* __restrict__ W1,
                                              const float* __restrict__ b1, const float* __restrict__ W2,
                                              float* __restrict__ B3, int ngcn,
                                              const float* __restrict__ X, const float* __restrict__ X2,
                                              float* __restrict__ cd)
{
    __shared__ float xa[80 * 44];
    __shared__ float sq[80];
    __shared__ float ag[4][35];
    __shared__ float rg[4][64];
    const int bid = blockIdx.x;
    const int t = threadIdx.x;
    if (bid < ngcn) {
        const int w = t >> 6, lane = t & 63;
        const int row = bid * 4 + w;
        gcn_body<35, 1>(row, w, lane, rs, deg, srcs, dinv, Hs, W1, b1, W2, B3, ag, rg);
        return;
    }
    const int b = bid - ngcn;
    for (int idx = t; idx < 80 * 44; idx += 256) {
        int nrow = idx / 44, k = idx - 44 * nrow;
        float v = 0.f;
        if (k < 35)
            v = (nrow < 64) ? X[(size_t)(b * 64 + nrow) * 35 + k]
                            : X2[(size_t)(b * 16 + (nrow - 64)) * 35 + k];
        xa[idx] = v;
    }
    __syncthreads();
    const float4* xa4 = (const float4*)xa;
    if (t < 80) {
        float acc = 0.f;
#pragma unroll
        for (int c = 0; c < 9; ++c) {
            float4 v = xa4[t * 11 + c];
            acc = fmaf(v.x, v.x, fmaf(v.y, v.y, fmaf(v.z, v.z, fmaf(v.w, v.w, acc))));
        }
        sq[t] = acc;
    }
    __syncthreads();
    const int ti = t >> 4;
    const int tj = t & 15;
    float dot[5][5];
#pragma unroll
    for (int r = 0; r < 5; ++r)
#pragma unroll
        for (int c = 0; c < 5; ++c) dot[r][c] = 0.f;
#pragma unroll
    for (int ch = 0; ch < 9; ++ch) {
        float4 av[5], bv[5];
#pragma unroll
        for (int r = 0; r < 5; ++r) av[r] = xa4[(5 * ti + r) * 11 + ch];
#pragma unroll
        for (int c = 0; c < 5; ++c) bv[c] = xa4[(5 * tj + c) * 11 + ch];
#pragma unroll
        for (int r = 0; r < 5; ++r)
#pragma unroll
            for (int c = 0; c < 5; ++c)
                dot[r][c] = fmaf(av[r].x, bv[c].x, fmaf(av[r].y, bv[c].y,
                              fmaf(av[r].z, bv[c].z, fmaf(av[r].w, bv[c].w, dot[r][c]))));
    }
    float* out = cd + (size_t)b * 6400;
#pragma unroll
    for (int r = 0; r < 5; ++r) {
        int n_ = 5 * ti + r;
        float sn = sq[n_];
#pragma unroll
        for (int c = 0; c < 5; ++c) {
            int m = 5 * tj + c;
            float d2 = sn + sq[m] - 2.f * dot[r][c];
            out[n_ * 80 + m] = sqrtf(fmaxf(d2, 0.f));
        }
    }
}

// ---------------- fused pull+combine (scaled input): dest = di*(Hs[row] + sum Hs[s]) + b
template <int D>
__global__ __launch_bounds__(256) void k_pcomb_s(const int* __restrict__ rs, const int* __restrict__ deg,
                                                 const int* __restrict__ srcs, const float* __restrict__ dinv,
                                                 const float* __restrict__ Hs, const float* __restrict__ b,
                                                 float* __restrict__ dest, int n)
{
    const int wid = (blockIdx.x * blockDim.x + threadIdx.x) >> 6;
    const int lane = threadIdx.x & 63;
    if (wid >= n) return;
    const float di = dinv[wid];
    const int e0 = rs[wid];
    const int d = deg[wid];
    float acc = (lane < D) ? Hs[(size_t)wid * D + lane] : 0.f;
    int e = 0;
    for (; e + 8 <= d; e += 8) {
        int s0 = srcs[e0 + e + 0], s1 = srcs[e0 + e + 1], s2 = srcs[e0 + e + 2], s3 = srcs[e0 + e + 3];
        int s4 = srcs[e0 + e + 4], s5 = srcs[e0 + e + 5], s6 = srcs[e0 + e + 6], s7 = srcs[e0 + e + 7];
        float h0 = 0.f, h1 = 0.f, h2 = 0.f, h3 = 0.f, h4 = 0.f, h5 = 0.f, h6 = 0.f, h7 = 0.f;
        if (lane < D) {
            h0 = Hs[(size_t)s0 * D + lane]; h1 = Hs[(size_t)s1 * D + lane];
            h2 = Hs[(size_t)s2 * D + lane]; h3 = Hs[(size_t)s3 * D + lane];
            h4 = Hs[(size_t)s4 * D + lane]; h5 = Hs[(size_t)s5 * D + lane];
            h6 = Hs[(size_t)s6 * D + lane]; h7 = Hs[(size_t)s7 * D + lane];
        }
        acc += ((h0 + h1) + (h2 + h3)) + ((h4 + h5) + (h6 + h7));
    }
    for (; e + 4 <= d; e += 4) {
        int s0 = srcs[e0 + e + 0], s1 = srcs[e0 + e + 1], s2 = srcs[e0 + e + 2], s3 = srcs[e0 + e + 3];
        float h0 = 0.f, h1 = 0.f, h2 = 0.f, h3 = 0.f;
        if (lane < D) {
            h0 = Hs[(size_t)s0 * D + lane]; h1 = Hs[(size_t)s1 * D + lane];
            h2 = Hs[(size_t)s2 * D + lane]; h3 = Hs[(size_t)s3 * D + lane];
        }
        acc += (h0 + h1) + (h2 + h3);
    }
    for (; e < d; ++e) {
        int s = srcs[e0 + e];
        if (lane < D) acc += Hs[(size_t)s * D + lane];
    }
    if (lane < D) dest[(size_t)wid * D + lane] = fmaf(di, acc, b[lane]);
}

// D=1 scaled pull+combine: thread per row
__global__ void k_pcomb1_s(const int* __restrict__ rs, const int* __restrict__ deg,
                           const int* __restrict__ srcs, const float* __restrict__ dinv,
                           const float* __restrict__ Hs, const float* __restrict__ b,
                           float* __restrict__ dest, int n)
{
    int r = blockIdx.x * blockDim.x + threadIdx.x;
    if (r >= n) return;
    int e0 = rs[r], d = deg[r];
    float acc = Hs[r];
    int e = 0;
    for (; e + 8 <= d; e += 8) {
        acc += ((Hs[srcs[e0 + e + 0]] + Hs[srcs[e0 + e + 1]]) + (Hs[srcs[e0 + e + 2]] + Hs[srcs[e0 + e + 3]]))
             + ((Hs[srcs[e0 + e + 4]] + Hs[srcs[e0 + e + 5]]) + (Hs[srcs[e0 + e + 6]] + Hs[srcs[e0 + e + 7]]));
    }
    for (; e + 4 <= d; e += 4) {
        acc += (Hs[srcs[e0 + e + 0]] + Hs[srcs[e0 + e + 1]]) + (Hs[srcs[e0 + e + 2]] + Hs[srcs[e0 + e + 3]]);
    }
    for (; e < d; ++e) acc += Hs[srcs[e0 + e]];
    dest[r] = fmaf(dinv[r], acc, b[0]);
}

// ---------------- alpha / yh: per-batch kernel regression ----------------
__global__ __launch_bounds__(256) void k_alpha(const float* __restrict__ X1,  // n1 x 34 (g1 out)
                                               const float* __restrict__ X,   // n1 x 35 (y col)
                                               float* __restrict__ X2,        // n2 x 35
                                               float* __restrict__ Xs2,       // n2 x 35 scaled
                                               const float* __restrict__ dinv2,
                                               const float* __restrict__ theta,
                                               const float* __restrict__ A,
                                               const float* __restrict__ scale)
{
    const int b = blockIdx.x;
    const int t = threadIdx.x;
    const int p = t & 63;
    const int w = t >> 6;
    __shared__ float th[34 * 34];
    __shared__ float xpS[64 * 35];
    __shared__ float xfS[16 * 34];
    __shared__ float UfS[16 * 34];
    __shared__ float upPart[4][64];
    __shared__ float upS[64];
    __shared__ float yS[64];

    for (int i = t; i < 34 * 34; i += 256) th[i] = theta[i];
    for (int i = t; i < 64 * 34; i += 256) {
        int r = i / 34, o = i - 34 * r;
        xpS[r * 35 + o] = X1[(size_t)(b * 64 + r) * 34 + o];
    }
    for (int i = t; i < 16 * 34; i += 256) {
        int q = i / 34, o = i - 34 * q;
        xfS[i] = X2[(size_t)(b * 16 + q) * 35 + o];
    }
    if (t < 64) yS[t] = X[(size_t)(b * 64 + t) * 35 + 34];
    __syncthreads();

    for (int i = t; i < 16 * 34; i += 256) {
        int q = i / 34, o = i - 34 * q;
        float a = 0.f;
#pragma unroll
        for (int O = 0; O < 34; ++O) a = fmaf(th[o * 34 + O], xfS[q * 34 + O], a);
        UfS[i] = a;
    }
    {
        const int o0 = w * 9;
        const int o1 = (o0 + 9 < 34) ? o0 + 9 : 34;
        float a = 0.f;
        for (int o = o0; o < o1; ++o) {
            float s2 = 0.f;
#pragma unroll
            for (int O = 0; O < 34; ++O) s2 = fmaf(th[o * 34 + O], xpS[p * 35 + O], s2);
            a = fmaf(xpS[p * 35 + o], s2, a);
        }
        upPart[w][p] = a;
    }
    __syncthreads();
    if (t < 64) upS[t] = upPart[0][t] + upPart[1][t] + upPart[2][t] + upPart[3][t];
    __syncthreads();

    const float sc = scale[0];
    const float up = upS[p];
    const float y = yS[p];
#pragma unroll
    for (int i = 0; i < 4; ++i) {
        const int q = w + 4 * i;
        float g = 0.f;
#pragma unroll
        for (int o = 0; o < 34; ++o) g = fmaf(UfS[q * 34 + o], xpS[p * 35 + o], g);
        float a = sc * (up - 2.f * g);
        if (A[(PASTN + q) * NN + p] == 0.f) a = -INFINITY;
        float mx = a;
#pragma unroll
        for (int off = 32; off > 0; off >>= 1) mx = fmaxf(mx, __shfl_xor(mx, off));
        float e = expf(a - mx);
        float s = e;
#pragma unroll
        for (int off = 32; off > 0; off >>= 1) s += __shfl_xor(s, off);
        float c = (e / s) * y;
#pragma unroll
        for (int off = 32; off > 0; off >>= 1) c += __shfl_xor(c, off);
        if (p == 0) {
            size_t ridx = (size_t)(b * 16 + q);
            X2[ridx * 35 + 34] = c;
            Xs2[ridx * 35 + 34] = c * dinv2[ridx];
        }
    }
}

extern "C" void kernel_launch(void* const* d_in, const int* in_sizes, int n_in,
                              void* d_out, int out_size, void* d_ws, size_t ws_size,
                              hipStream_t stream)
{
    const int* x1_cat = (const int*)d_in[0];
    const float* x1_num = (const float*)d_in[1];
    const int* x2_cat = (const int*)d_in[2];
    const float* x2_num = (const float*)d_in[3];
    const int* e1 = (const int*)d_in[4];
    const int* e2 = (const int*)d_in[5];
    const float* emb0 = (const float*)d_in[6];
    const float* emb1 = (const float*)d_in[7];
    const float* emb2 = (const float*)d_in[8];
    const float* pW1 = (const float*)d_in[9];
    const float* pb1 = (const float*)d_in[10];
    const float* pW2 = (const float*)d_in[11];
    const float* pb2 = (const float*)d_in[12];
    const float* pW3 = (const float*)d_in[13];
    const float* pb3 = (const float*)d_in[14];
    const float* g1W1 = (const float*)d_in[15];
    const float* g1b1 = (const float*)d_in[16];
    const float* g1W2 = (const float*)d_in[17];
    const float* g1b2 = (const float*)d_in[18];
    const float* g2W1 = (const float*)d_in[19];
    const float* g2b1 = (const float*)d_in[20];
    const float* g2W2 = (const float*)d_in[21];
    const float* g2b2 = (const float*)d_in[22];
    const float* kerW = (const float*)d_in[23];
    const float* smoothing = (const float*)d_in[24];
    const float* M = (const float*)d_in[25];

    const int n1 = in_sizes[0] / 3;
    const int n2 = in_sizes[2] / 3;
    const int E1 = in_sizes[4] / 2;
    const int E2 = in_sizes[5] / 2;
    const int SBc = n2 / FUTN;

    float* w = (float*)d_ws;
    size_t off = 0;
    float* scale = w + off; off += 16;
    float* theta = w + off; off += 1184;
    float* Aws = w + off; off += 6400;
    float* X = w + off; off += (size_t)n1 * 35;
    float* Xs1 = w + off; off += (size_t)n1 * 35;
    float* X2 = w + off; off += (size_t)n2 * 35;
    float* Xs2 = w + off; off += (size_t)n2 * 35;
    float* dinv1 = w + off; off += (size_t)n1;
    float* dinv2 = w + off; off += (size_t)n2;
    float* B3 = w + off; off += (size_t)n1 * 34;
    float* B4 = w + off; off += (size_t)n1 * 34;
    off = (off + 3) & ~(size_t)3;  // 16B align for bf16 fragment arrays
    unsigned short* W1fh = (unsigned short*)(w + off); off += 4096;   // 8192 halves
    unsigned short* W1fl = (unsigned short*)(w + off); off += 4096;
    unsigned short* W2fh = (unsigned short*)(w + off); off += 8192;   // 16384 halves
    unsigned short* W2fl = (unsigned short*)(w + off); off += 8192;
    unsigned short* W3fh = (unsigned short*)(w + off); off += 4096;   // 8192 halves
    unsigned short* W3fl = (unsigned short*)(w + off); off += 4096;
    int* iw = (int*)(w + off);
    size_t ioff = 0;
    int* degi1 = iw + ioff; ioff += n1;
    int* degi2 = iw + ioff; ioff += n2;
    int* rs1 = iw + ioff; ioff += n1;
    int* cur1 = iw + ioff; ioff += n1;
    int* srcs1 = iw + ioff; ioff += E1;
    int* rs2 = iw + ioff; ioff += n2;
    int* cur2 = iw + ioff; ioff += n2;
    int* srcs2 = iw + ioff; ioff += E2;
    int* bsumA = iw + ioff; ioff += 1024;
    int* bsumB = iw + ioff; ioff += 1024;

    float* out_f = (float*)d_out;
    float* cd_f = out_f + (size_t)SBc * FUTN;
    float* A_out = cd_f + (size_t)SBc * NN * NN;

    auto cdiv = [](long long a, long long b) { return (unsigned)((a + b - 1) / b); };

    // ---- init: setup + wconv + degree count (one dispatch) ----
    hipMemsetAsync(degi1, 0, ((size_t)n1 + n2) * 4, stream);
    const int nbe1 = cdiv(E1, 256), nbe2 = cdiv(E2, 256);
    k_init<<<129 + nbe1 + nbe2, 256, 0, stream>>>(M, kerW, smoothing, Aws, A_out, theta, scale,
                                                  pW1, pW2, pW3, W1fh, W1fl, W2fh, W2fl, W3fh, W3fl,
                                                  e1 + E1, e2 + E2, degi1, degi2, E1, E2, nbe1);

    // ---- scans ----
    const int nb1 = cdiv(n1, SCHUNK), nb2 = cdiv(n2, SCHUNK);
    k_scan_reduce2<<<nb1 + nb2, 256, 0, stream>>>(degi1, degi2, bsumA, bsumB, n1, n2, nb1);
    k_scan_mid2<<<2, 1024, 0, stream>>>(bsumA, bsumB, nb1, nb2);
    k_scan_final2<<<nb1 + nb2, 256, 0, stream>>>(degi1, degi2, bsumA, bsumB, rs1, rs2, cur1, cur2,
                                                 dinv1, dinv2, n1, n2, nb1);

    // ---- fill + pre MLP merged (latency-bound fill overlaps compute-bound MLP) ----
    const int npre = n1 / PR + n2 / PR;
    const int nfill = nbe1 + nbe2;
    k_fillpre<<<npre + nfill, 256, 0, stream>>>(e1, e1 + E1, e2, e2 + E2, cur1, cur2, srcs1, srcs2,
                                                E1, E2, nbe1, nfill,
                                                x1_cat, x1_num, x2_cat, x2_num, emb0, emb1, emb2,
                                                W1fh, W1fl, pb1, W2fh, W2fl, pb2, W3fh, W3fl, pb3,
                                                dinv1, dinv2, X, Xs1, X2, Xs2, n1 / PR, npre);

    // ---- g1: fused pull(35)+gemm(35->64)+relu+gemm(64->34)*di -> B3 ----
    k_gcn_f<35, 34><<<n1 / 4, 256, 0, stream>>>(rs1, degi1, srcs1, dinv1, Xs1, g1W1, g1b1, g1W2, B3, n1);
    k_pcomb_s<34><<<cdiv(n1, 4), 256, 0, stream>>>(rs1, degi1, srcs1, dinv1, B3, g1b2, B4, n1);

    // ---- alpha / yh -> X2 col 34 (+ scaled copy) ----
    k_alpha<<<SBc, 256, 0, stream>>>(B4, X, X2, Xs2, dinv2, theta, Aws, scale);

    // ---- g2 fused GCN + pairwise distances (one dispatch) ----
    k_g2cd<<<n2 / 4 + SBc, 256, 0, stream>>>(rs2, degi2, srcs2, dinv2, Xs2, g2W1, g2b1, g2W2, B3,
                                             n2 / 4, X, X2, cd_f);

    // ---- final pull+combine -> out ----
    k_pcomb1_s<<<cdiv(n2, 256), 256, 0, stream>>>(rs2, degi2, srcs2, dinv2, B3, g2b2, out_f, n2);
}